// Round 12
// baseline (2358.215 us; speedup 1.0000x reference)
//
#include <hip/hip_runtime.h>

// ---- problem dims ----
#define NN 20000
#define NE 640000
#define FF 128
#define H1 64
#define H2 32
#define RR 65
#define BQ 4096
#define NR (NN*RR)

#define DBLK 64               // dsts per block
#define NBLK 313              // ceil(20000/64)
#define NB (NBLK*RR)          // 20345 bins
#define NBPAD 20480
#define GCAP 512              // groups per block cap (avg ~190)
#define H1P 68                // padded LDS row (bank spread)
#define H2P 36

typedef __attribute__((ext_vector_type(8))) short bhalf8;   // 8 bf16 (4 VGPRs)
typedef __attribute__((ext_vector_type(4))) float f32x4;
#define MFMA16(a, b, c) __builtin_amdgcn_mfma_f32_16x16x32_bf16(a, b, c, 0, 0, 0)

__device__ __forceinline__ unsigned short f2bf(float f) {
  unsigned int u = __float_as_uint(f);
  unsigned int r = (u + 0x7fffu + ((u >> 16) & 1u)) >> 16;   // RNE
  return (unsigned short)r;
}
__device__ __forceinline__ float bf2f(unsigned short u) {
  return __uint_as_float((unsigned)u << 16);
}

// ===================== histogram: (dst,rel) cnt + (dstblock64,rel) bin cnt =========
__global__ __launch_bounds__(256) void k_hist(
    const int* __restrict__ ei, const int* __restrict__ etA, const int* __restrict__ etB,
    int* __restrict__ cntA, int* __restrict__ cntB,
    int* __restrict__ binCntA, int* __restrict__ binCntB) {
  int e = blockIdx.x * blockDim.x + threadIdx.x;
  if (e >= NE) return;
  int d = ei[NE + e];
  int ta = etA[e], tb = etB[e];
  atomicAdd(&cntA[(size_t)d * RR + ta], 1);
  atomicAdd(&cntB[(size_t)d * RR + tb], 1);
  atomicAdd(&binCntA[(d >> 6) * RR + ta], 1);
  atomicAdd(&binCntB[(d >> 6) * RR + tb], 1);
}

// ===================== exclusive scan over 20345 bins (both streams, 1 block) ======
__global__ __launch_bounds__(256) void k_prefixB(
    const int* __restrict__ cA, int* __restrict__ sA, int* __restrict__ uA,
    const int* __restrict__ cB, int* __restrict__ sB, int* __restrict__ uB) {
  __shared__ int ps[256];
  __shared__ int pb[257];
  int t = threadIdx.x;
  int c0 = t * 80;
  int c1 = (c0 + 80 < NB) ? (c0 + 80) : NB;
  {
    int s = 0;
    for (int i = c0; i < c1; ++i) s += cA[i];
    ps[t] = s;
    __syncthreads();
    if (t == 0) { int a = 0; for (int i = 0; i < 256; ++i) { pb[i] = a; a += ps[i]; } }
    __syncthreads();
    int run = pb[t];
    for (int i = c0; i < c1; ++i) { sA[i] = run; uA[i] = run; run += cA[i]; }
    __syncthreads();
  }
  {
    int s = 0;
    for (int i = c0; i < c1; ++i) s += cB[i];
    ps[t] = s;
    __syncthreads();
    if (t == 0) { int a = 0; for (int i = 0; i < 256; ++i) { pb[i] = a; a += ps[i]; } }
    __syncthreads();
    int run = pb[t];
    for (int i = c0; i < c1; ++i) { sB[i] = run; uB[i] = run; run += cB[i]; }
  }
}

// ===================== scatter edges into bins with packed meta =====================
// m = src | dstLocal<<20 ; iv = 1/cnt(dst,rel)
__global__ __launch_bounds__(256) void k_scatter2(
    const int* __restrict__ ei, const int* __restrict__ etA, const int* __restrict__ etB,
    const int* __restrict__ cntA, const int* __restrict__ cntB,
    int* __restrict__ binCurA, int* __restrict__ binCurB,
    int* __restrict__ mA, float* __restrict__ ivA,
    int* __restrict__ mB, float* __restrict__ ivB) {
  int e = blockIdx.x * blockDim.x + threadIdx.x;
  if (e >= NE) return;
  int s = ei[e], d = ei[NE + e];
  int mm = s | ((d & (DBLK - 1)) << 20);
  {
    int t = etA[e];
    int p = atomicAdd(&binCurA[(d >> 6) * RR + t], 1);
    mA[p] = mm;
    ivA[p] = 1.0f / (float)cntA[(size_t)d * RR + t];
  }
  {
    int t = etB[e];
    int p = atomicAdd(&binCurB[(d >> 6) * RR + t], 1);
    mB[p] = mm;
    ivB[p] = 1.0f / (float)cntB[(size_t)d * RR + t];
  }
}

// ===================== flat padded 16-edge group list per block =====================
// grpMeta = rel | lim<<8 (lim = edges in this group, <=16); grpBase = edge offset.
__global__ __launch_bounds__(128) void k_groups(
    const int* __restrict__ binStart, const int* __restrict__ binCnt,
    int* __restrict__ grpBase, int* __restrict__ grpMeta, int* __restrict__ grpN) {
  __shared__ int ngS[RR], gsS[RR];
  int b = blockIdx.x, t = threadIdx.x;
  if (t < RR) ngS[t] = (binCnt[b * RR + t] + 15) >> 4;
  __syncthreads();
  if (t == 0) {
    int a = 0;
    for (int i = 0; i < RR; ++i) { gsS[i] = a; a += ngS[i]; }
    grpN[b] = (a < GCAP) ? a : GCAP;
  }
  __syncthreads();
  if (t < RR) {
    int g = gsS[t];
    int bin = b * RR + t;
    int bs = binStart[bin];
    int c = binCnt[bin];
    while (c > 0 && g < GCAP) {
      int lim = (c < 16) ? c : 16;
      grpBase[b * GCAP + g] = bs;
      grpMeta[b * GCAP + g] = t | (lim << 8);
      ++g; bs += 16; c -= 16;
    }
  }
}

// ===================== fp32 -> bf16 conversion for x_o and x_a ====================
__global__ __launch_bounds__(256) void k_cvt2(const float4* __restrict__ inA,
                                              const float4* __restrict__ inB,
                                              uint4* __restrict__ outA,
                                              uint4* __restrict__ outB, int n8) {
  int i = blockIdx.x * blockDim.x + threadIdx.x;
  if (i >= 2 * n8) return;
  const float4* in = (i < n8) ? inA : inB;
  uint4* out = (i < n8) ? outA : outB;
  int j = (i < n8) ? i : i - n8;
  float4 a = in[2 * j], b = in[2 * j + 1];
  uint4 o;
  o.x = (unsigned)f2bf(a.x) | ((unsigned)f2bf(a.y) << 16);
  o.y = (unsigned)f2bf(a.z) | ((unsigned)f2bf(a.w) << 16);
  o.z = (unsigned)f2bf(b.x) | ((unsigned)f2bf(b.y) << 16);
  o.w = (unsigned)f2bf(b.z) | ((unsigned)f2bf(b.w) << 16);
  out[j] = o;
}

// ===================== W1 -> bf16 B-fragments =====================
__global__ __launch_bounds__(256) void k_wprep1(const float* __restrict__ W,
                                                unsigned short* __restrict__ Wf) {
  int r = blockIdx.x;
  int lane = threadIdx.x & 63, w = threadIdx.x >> 6;
#pragma unroll
  for (int s4 = 0; s4 < 4; ++s4) {
    int slot = w * 4 + s4;
    int ks = slot >> 2, n = slot & 3;
    int krow = ks * 32 + ((lane >> 4) << 3);
    int colo = n * 16 + (lane & 15);
    unsigned short* o = Wf + (((size_t)r * 16 + slot) * 64 + lane) * 8;
#pragma unroll
    for (int j = 0; j < 8; ++j)
      o[j] = f2bf(W[((size_t)r * FF + krow + j) * H1 + colo]);
  }
}

// ===================== W2 -> bf16 B-fragments =====================
__global__ __launch_bounds__(256) void k_wprep2(const float* __restrict__ W,
                                                unsigned short* __restrict__ Wf) {
  int r = blockIdx.x;
  int lane = threadIdx.x & 63, slot = threadIdx.x >> 6;
  int ks = slot >> 1, n = slot & 1;
  int krow = ks * 32 + ((lane >> 4) << 3);
  int colo = n * 16 + (lane & 15);
  unsigned short* o = Wf + (((size_t)r * 4 + slot) * 64 + lane) * 8;
#pragma unroll
  for (int j = 0; j < 8; ++j)
    o[j] = f2bf(W[((size_t)r * H1 + krow + j) * H2 + colo]);
}

// ===================== layer-1 root terms -> bf16 =====================
__global__ __launch_bounds__(256) void k_root1(
    const float* __restrict__ xo, const float* __restrict__ xa,
    const float* __restrict__ rt, const float* __restrict__ b,
    unsigned short* __restrict__ rO, unsigned short* __restrict__ rA) {
  int lane = threadIdx.x & 63;
  int n = (blockIdx.x * blockDim.x + threadIdx.x) >> 6;
  if (n >= NN) return;
  const float4* xo4 = (const float4*)(xo + (size_t)n * FF);
  const float4* xa4 = (const float4*)(xa + (size_t)n * FF);
  float so = b[lane], sa = so;
#pragma unroll
  for (int j = 0; j < FF / 4; ++j) {
    float vo[4], va[4];
    *(float4*)vo = xo4[j];
    *(float4*)va = xa4[j];
#pragma unroll
    for (int t = 0; t < 4; ++t) {
      float wv = rt[(4 * j + t) * H1 + lane];
      so = fmaf(vo[t], wv, so);
      sa = fmaf(va[t], wv, sa);
    }
  }
  rO[(size_t)n * H1 + lane] = f2bf(so);
  rA[(size_t)n * H1 + lane] = f2bf(sa);
}

// ===================== layer-1 edge GEMM + LDS fp32 aggregation (flat groups) ======
// Waves take contiguous group chunks (rel monotone -> W reload ~9x/wave);
// 1-deep pipeline on grpMeta->edgeMeta chain; scatter = LDS atomicAdd (r11-proven);
// epilogue fuses root + relu + bf16 store.
template <int NIN>
__global__ __launch_bounds__(512, 2) void k_edgeF1(
    const int* __restrict__ mP, const float* __restrict__ ivP,
    const int* __restrict__ grpBase, const int* __restrict__ grpMeta,
    const int* __restrict__ grpN,
    const unsigned short* __restrict__ Wf,
    const unsigned short* __restrict__ xA16, const unsigned short* __restrict__ xB16,
    const unsigned short* __restrict__ root0, const unsigned short* __restrict__ root1,
    unsigned short* __restrict__ y0, unsigned short* __restrict__ y1) {
  __shared__ float yT[NIN][DBLK][H1P];
  const int b = blockIdx.x;
  const int tid = threadIdx.x;
  {
    float4* p = (float4*)yT;
    for (int i = tid; i < NIN * DBLK * H1P / 4; i += 512) p[i] = float4{0.f, 0.f, 0.f, 0.f};
  }
  __syncthreads();
  const int lane = tid & 63;
  const int wv = tid >> 6;
  const int cg = lane >> 4;
  const int col = lane & 15;
  const int row0 = cg << 2;
  const int NG = grpN[b];
  const int g0 = (NG * wv) >> 3;
  const int g1 = (NG * (wv + 1)) >> 3;

  if (g0 < g1) {
    const int* gB = grpBase + b * GCAP;
    const int* gM = grpMeta + b * GCAP;
    int gbC = gB[g0], gmC = gM[g0];
    int gn1 = (g0 + 1 < g1) ? (g0 + 1) : (g1 - 1);
    int gbN = gB[gn1], gmN = gM[gn1];
    int offC = gbC + ((col < (gmC >> 8)) ? col : 0);
    int mC = mP[offC];
    float ivC = (col < (gmC >> 8)) ? ivP[offC] : 0.f;
    int relC = -1;
    bhalf8 wb[16];

    for (int g = g0; g < g1; ++g) {
      const int gn2 = (g + 2 < g1) ? (g + 2) : (g1 - 1);
      const int gbN2 = gB[gn2], gmN2 = gM[gn2];
      const int offN = gbN + ((col < (gmN >> 8)) ? col : 0);
      const int mN = mP[offN];
      const float ivN = (col < (gmN >> 8)) ? ivP[offN] : 0.f;

      const int rel = gmC & 0xFF;
      if (rel != relC) {
        relC = rel;
        const bhalf8* wf = (const bhalf8*)Wf + ((size_t)rel * 16) * 64 + lane;
#pragma unroll
        for (int s = 0; s < 16; ++s) wb[s] = wf[(size_t)s * 64];
      }
      const int src = mC & 0xFFFFF;
      const int dl = ((unsigned)mC) >> 20;
      const int dl0 = __shfl(dl, row0),     dl1 = __shfl(dl, row0 + 1),
                dl2 = __shfl(dl, row0 + 2), dl3 = __shfl(dl, row0 + 3);
      const float i0 = __shfl(ivC, row0),     i1 = __shfl(ivC, row0 + 1),
                  i2 = __shfl(ivC, row0 + 2), i3 = __shfl(ivC, row0 + 3);
#pragma unroll
      for (int in = 0; in < NIN; ++in) {
        const unsigned short* xp = (in == 0) ? xA16 : xB16;
        const bhalf8* xr = (const bhalf8*)xp + ((size_t)src << 4);
        bhalf8 a0 = xr[cg], a1 = xr[4 + cg], a2 = xr[8 + cg], a3 = xr[12 + cg];
        f32x4 c0 = {0.f,0.f,0.f,0.f}, c1 = c0, c2 = c0, c3 = c0;
        c0 = MFMA16(a0, wb[0], c0);  c1 = MFMA16(a0, wb[1], c1);
        c2 = MFMA16(a0, wb[2], c2);  c3 = MFMA16(a0, wb[3], c3);
        c0 = MFMA16(a1, wb[4], c0);  c1 = MFMA16(a1, wb[5], c1);
        c2 = MFMA16(a1, wb[6], c2);  c3 = MFMA16(a1, wb[7], c3);
        c0 = MFMA16(a2, wb[8], c0);  c1 = MFMA16(a2, wb[9], c1);
        c2 = MFMA16(a2, wb[10], c2); c3 = MFMA16(a2, wb[11], c3);
        c0 = MFMA16(a3, wb[12], c0); c1 = MFMA16(a3, wb[13], c1);
        c2 = MFMA16(a3, wb[14], c2); c3 = MFMA16(a3, wb[15], c3);
        const f32x4 cc[4] = {c0, c1, c2, c3};
#pragma unroll
        for (int n = 0; n < 4; ++n) {
          atomicAdd(&yT[in][dl0][n * 16 + col], cc[n][0] * i0);
          atomicAdd(&yT[in][dl1][n * 16 + col], cc[n][1] * i1);
          atomicAdd(&yT[in][dl2][n * 16 + col], cc[n][2] * i2);
          atomicAdd(&yT[in][dl3][n * 16 + col], cc[n][3] * i3);
        }
      }
      gbC = gbN; gmC = gmN; mC = mN; ivC = ivN;
      gbN = gbN2; gmN = gmN2;
    }
  }
  __syncthreads();
  const int dBase = b * DBLK;
  for (int i = tid; i < DBLK * H1; i += 512) {
    int dl = i >> 6, c = i & 63;
    int d = dBase + dl;
    if (d < NN) {
      size_t o = (size_t)d * H1 + c;
      float v0 = bf2f(root0[o]) + yT[0][dl][c];
      y0[o] = f2bf(fmaxf(v0, 0.f));
      if constexpr (NIN == 2) {
        float v1 = bf2f(root1[o]) + yT[1][dl][c];
        y1[o] = f2bf(fmaxf(v1, 0.f));
      }
    }
  }
}

// ===================== layer-2 root terms (bf16 in/out), 3 fused =====================
__global__ __launch_bounds__(256) void k_root2x3(
    const unsigned short* __restrict__ x1o, const unsigned short* __restrict__ x1a,
    const unsigned short* __restrict__ x1aa,
    const float* __restrict__ rt, const float* __restrict__ b,
    unsigned short* __restrict__ y0, unsigned short* __restrict__ y1,
    unsigned short* __restrict__ y2) {
  int i = blockIdx.x * blockDim.x + threadIdx.x;
  if (i >= NN * H2) return;
  int o = i & (H2 - 1);
  int n = i >> 5;
  const uint2* p0 = (const uint2*)(x1o + (size_t)n * H1);
  const uint2* p1 = (const uint2*)(x1a + (size_t)n * H1);
  const uint2* p2 = (const uint2*)(x1aa + (size_t)n * H1);
  float s0 = b[o], s1 = s0, s2 = s0;
#pragma unroll
  for (int j = 0; j < 16; ++j) {
    uint2 u0 = p0[j], u1 = p1[j], u2 = p2[j];
#pragma unroll
    for (int t = 0; t < 4; ++t) {
      unsigned w0 = (t < 2) ? u0.x : u0.y;
      unsigned w1 = (t < 2) ? u1.x : u1.y;
      unsigned w2 = (t < 2) ? u2.x : u2.y;
      int sh = (t & 1) * 16;
      float wv = rt[(4 * j + t) * H2 + o];
      s0 = fmaf(bf2f((unsigned short)(w0 >> sh)), wv, s0);
      s1 = fmaf(bf2f((unsigned short)(w1 >> sh)), wv, s1);
      s2 = fmaf(bf2f((unsigned short)(w2 >> sh)), wv, s2);
    }
  }
  y0[i] = f2bf(s0); y1[i] = f2bf(s1); y2[i] = f2bf(s2);
}

// ===================== layer-2 edge GEMM + LDS aggregation (flat groups) ===========
template <int NIN>
__global__ __launch_bounds__(512, 2) void k_edgeF2(
    const int* __restrict__ mP, const float* __restrict__ ivP,
    const int* __restrict__ grpBase, const int* __restrict__ grpMeta,
    const int* __restrict__ grpN,
    const unsigned short* __restrict__ Wf,
    const unsigned short* __restrict__ xA16, const unsigned short* __restrict__ xB16,
    const unsigned short* __restrict__ root0, const unsigned short* __restrict__ root1,
    unsigned short* __restrict__ y0, unsigned short* __restrict__ y1,
    float* __restrict__ f32out) {
  __shared__ float yT[NIN][DBLK][H2P];
  const int b = blockIdx.x;
  const int tid = threadIdx.x;
  {
    float4* p = (float4*)yT;
    for (int i = tid; i < NIN * DBLK * H2P / 4; i += 512) p[i] = float4{0.f, 0.f, 0.f, 0.f};
  }
  __syncthreads();
  const int lane = tid & 63;
  const int wv = tid >> 6;
  const int cg = lane >> 4;
  const int col = lane & 15;
  const int row0 = cg << 2;
  const int NG = grpN[b];
  const int g0 = (NG * wv) >> 3;
  const int g1 = (NG * (wv + 1)) >> 3;

  if (g0 < g1) {
    const int* gB = grpBase + b * GCAP;
    const int* gM = grpMeta + b * GCAP;
    int gbC = gB[g0], gmC = gM[g0];
    int gn1 = (g0 + 1 < g1) ? (g0 + 1) : (g1 - 1);
    int gbN = gB[gn1], gmN = gM[gn1];
    int offC = gbC + ((col < (gmC >> 8)) ? col : 0);
    int mC = mP[offC];
    float ivC = (col < (gmC >> 8)) ? ivP[offC] : 0.f;
    int relC = -1;
    bhalf8 wb[4];

    for (int g = g0; g < g1; ++g) {
      const int gn2 = (g + 2 < g1) ? (g + 2) : (g1 - 1);
      const int gbN2 = gB[gn2], gmN2 = gM[gn2];
      const int offN = gbN + ((col < (gmN >> 8)) ? col : 0);
      const int mN = mP[offN];
      const float ivN = (col < (gmN >> 8)) ? ivP[offN] : 0.f;

      const int rel = gmC & 0xFF;
      if (rel != relC) {
        relC = rel;
        const bhalf8* wf = (const bhalf8*)Wf + ((size_t)rel * 4) * 64 + lane;
#pragma unroll
        for (int s = 0; s < 4; ++s) wb[s] = wf[(size_t)s * 64];
      }
      const int src = mC & 0xFFFFF;
      const int dl = ((unsigned)mC) >> 20;
      const int dl0 = __shfl(dl, row0),     dl1 = __shfl(dl, row0 + 1),
                dl2 = __shfl(dl, row0 + 2), dl3 = __shfl(dl, row0 + 3);
      const float i0 = __shfl(ivC, row0),     i1 = __shfl(ivC, row0 + 1),
                  i2 = __shfl(ivC, row0 + 2), i3 = __shfl(ivC, row0 + 3);
#pragma unroll
      for (int in = 0; in < NIN; ++in) {
        const unsigned short* xp = (in == 0) ? xA16 : xB16;
        const bhalf8* xr = (const bhalf8*)xp + ((size_t)src << 3);
        bhalf8 a0 = xr[cg], a1 = xr[4 + cg];
        f32x4 c0 = {0.f,0.f,0.f,0.f}, c1 = c0;
        c0 = MFMA16(a0, wb[0], c0); c1 = MFMA16(a0, wb[1], c1);
        c0 = MFMA16(a1, wb[2], c0); c1 = MFMA16(a1, wb[3], c1);
        const f32x4 cc[2] = {c0, c1};
#pragma unroll
        for (int n = 0; n < 2; ++n) {
          atomicAdd(&yT[in][dl0][n * 16 + col], cc[n][0] * i0);
          atomicAdd(&yT[in][dl1][n * 16 + col], cc[n][1] * i1);
          atomicAdd(&yT[in][dl2][n * 16 + col], cc[n][2] * i2);
          atomicAdd(&yT[in][dl3][n * 16 + col], cc[n][3] * i3);
        }
      }
      gbC = gbN; gmC = gmN; mC = mN; ivC = ivN;
      gbN = gbN2; gmN = gmN2;
    }
  }
  __syncthreads();
  const int dBase = b * DBLK;
  for (int i = tid; i < DBLK * H2; i += 512) {
    int dl = i >> 5, c = i & 31;
    int d = dBase + dl;
    if (d < NN) {
      size_t o = (size_t)d * H2 + c;
      float v0 = bf2f(root0[o]) + yT[0][dl][c];
      y0[o] = f2bf(v0);
      if (f32out) f32out[o] = v0;
      if constexpr (NIN == 2) {
        float v1 = bf2f(root1[o]) + yT[1][dl][c];
        y1[o] = f2bf(v1);
      }
    }
  }
}

// ===================== column sum of x2_o (fp32) -> hacc[32] =====================
__global__ __launch_bounds__(256) void k_colsum(const float* __restrict__ x2o,
                                                float* __restrict__ hacc) {
  int tid = threadIdx.x;
  int col = tid & 31;
  int rgrp = blockIdx.x * (blockDim.x >> 5) + (tid >> 5);
  int nth = gridDim.x * (blockDim.x >> 5);
  float s = 0.f;
  for (int n = rgrp; n < NN; n += nth) s += x2o[(size_t)n * H2 + col];
  unsafeAtomicAdd(&hacc[col], s);
}

// ===================== h_os = sigmoid(mean); v = disc_w @ h_os =====================
__global__ __launch_bounds__(64) void k_disc(const float* __restrict__ hacc,
                                             const float* __restrict__ dw,
                                             float* __restrict__ vout) {
  __shared__ float hos[H2];
  int t = threadIdx.x;
  if (t < H2) hos[t] = 1.0f / (1.0f + expf(-hacc[t] / (float)NN));
  __syncthreads();
  if (t < H2) {
    float s = 0.f;
#pragma unroll
    for (int k = 0; k < H2; ++k) s = fmaf(dw[t * H2 + k], hos[k], s);
    vout[t] = s;
  }
}

// ===================== ret_os / ret_os_a (bf16 x2 inputs) =====================
__global__ __launch_bounds__(256) void k_ret(
    const unsigned short* __restrict__ x2o, const unsigned short* __restrict__ x2oa,
    const unsigned short* __restrict__ x2oaa,
    const float* __restrict__ v, const float* __restrict__ db,
    float* __restrict__ ros, float* __restrict__ rosa) {
  int n = blockIdx.x * blockDim.x + threadIdx.x;
  if (n >= NN) return;
  const uint2* a2 = (const uint2*)(x2o + (size_t)n * H2);
  const uint2* b2 = (const uint2*)(x2oa + (size_t)n * H2);
  const uint2* c2 = (const uint2*)(x2oaa + (size_t)n * H2);
  const float4* v4 = (const float4*)v;
  float r0 = 0.f, r1 = 0.f, r2 = 0.f;
#pragma unroll
  for (int j = 0; j < 8; ++j) {
    uint2 ua = a2[j], ub = b2[j], uc = c2[j];
    float4 vv = v4[j];
    r0 += bf2f((unsigned short)ua.x) * vv.x + bf2f((unsigned short)(ua.x >> 16)) * vv.y
        + bf2f((unsigned short)ua.y) * vv.z + bf2f((unsigned short)(ua.y >> 16)) * vv.w;
    r1 += bf2f((unsigned short)ub.x) * vv.x + bf2f((unsigned short)(ub.x >> 16)) * vv.y
        + bf2f((unsigned short)ub.y) * vv.z + bf2f((unsigned short)(ub.y >> 16)) * vv.w;
    r2 += bf2f((unsigned short)uc.x) * vv.x + bf2f((unsigned short)(uc.x >> 16)) * vv.y
        + bf2f((unsigned short)uc.y) * vv.z + bf2f((unsigned short)(uc.y >> 16)) * vv.w;
  }
  float bb = db[0];
  ros[n * 2] = r0 + bb;  ros[n * 2 + 1] = r1 + bb;
  rosa[n * 2] = r0 + bb; rosa[n * 2 + 1] = r2 + bb;
}

// ===================== classifier (x1o bf16, x2o fp32) =====================
__global__ __launch_bounds__(128) void k_cls(
    const int* __restrict__ idx, const unsigned short* __restrict__ x1o,
    const float* __restrict__ x2o,
    const float* __restrict__ attt, const float* __restrict__ cw, const float* __restrict__ cb,
    float* __restrict__ lg) {
  int b = blockIdx.x;
  int r = threadIdx.x;
  if (r >= RR) return;
  int i1 = idx[b], i2 = idx[BQ + b];
  float a0 = attt[0], a1 = attt[1];
  float acc = cb[r];
  const uint2* q1 = (const uint2*)(x1o + (size_t)i1 * H1);
  const float4* q2 = (const float4*)(x2o + (size_t)i1 * H2);
  const uint2* q3 = (const uint2*)(x1o + (size_t)i2 * H1);
  const float4* q4 = (const float4*)(x2o + (size_t)i2 * H2);
#pragma unroll
  for (int j = 0; j < 16; ++j) {
    uint2 u = q1[j];
    float v0 = bf2f((unsigned short)u.x), v1 = bf2f((unsigned short)(u.x >> 16));
    float v2 = bf2f((unsigned short)u.y), v3 = bf2f((unsigned short)(u.y >> 16));
    acc = fmaf(a0 * v0, cw[(4 * j) * RR + r], acc);
    acc = fmaf(a0 * v1, cw[(4 * j + 1) * RR + r], acc);
    acc = fmaf(a0 * v2, cw[(4 * j + 2) * RR + r], acc);
    acc = fmaf(a0 * v3, cw[(4 * j + 3) * RR + r], acc);
  }
#pragma unroll
  for (int j = 0; j < H2 / 4; ++j) {
    float v[4]; *(float4*)v = q2[j];
#pragma unroll
    for (int t = 0; t < 4; ++t) acc = fmaf(a1 * v[t], cw[(H1 + 4 * j + t) * RR + r], acc);
  }
#pragma unroll
  for (int j = 0; j < 16; ++j) {
    uint2 u = q3[j];
    float v0 = bf2f((unsigned short)u.x), v1 = bf2f((unsigned short)(u.x >> 16));
    float v2 = bf2f((unsigned short)u.y), v3 = bf2f((unsigned short)(u.y >> 16));
    acc = fmaf(a0 * v0, cw[(96 + 4 * j) * RR + r], acc);
    acc = fmaf(a0 * v1, cw[(96 + 4 * j + 1) * RR + r], acc);
    acc = fmaf(a0 * v2, cw[(96 + 4 * j + 2) * RR + r], acc);
    acc = fmaf(a0 * v3, cw[(96 + 4 * j + 3) * RR + r], acc);
  }
#pragma unroll
  for (int j = 0; j < H2 / 4; ++j) {
    float v[4]; *(float4*)v = q4[j];
#pragma unroll
    for (int t = 0; t < 4; ++t) acc = fmaf(a1 * v[t], cw[(96 + H1 + 4 * j + t) * RR + r], acc);
  }
  lg[(size_t)b * RR + r] = acc;
}

// ===================== launch =====================
extern "C" void kernel_launch(void* const* d_in, const int* in_sizes, int n_in,
                              void* d_out, int out_size, void* d_ws, size_t ws_size,
                              hipStream_t stream) {
  const float* x_o  = (const float*)d_in[0];
  const float* x_a  = (const float*)d_in[1];
  const int*   ei   = (const int*)d_in[2];
  const int*   etA  = (const int*)d_in[3];
  const int*   etB  = (const int*)d_in[4];
  const int*   idx  = (const int*)d_in[5];
  const float* W1   = (const float*)d_in[6];
  const float* rt1  = (const float*)d_in[7];
  const float* b1   = (const float*)d_in[8];
  const float* W2   = (const float*)d_in[9];
  const float* rt2  = (const float*)d_in[10];
  const float* b2   = (const float*)d_in[11];
  const float* attt = (const float*)d_in[12];
  const float* dw   = (const float*)d_in[13];
  const float* db   = (const float*)d_in[14];
  const float* cw   = (const float*)d_in[15];
  const float* cb   = (const float*)d_in[16];

  const size_t NRp = 1300224;
  int* wsI      = (int*)d_ws;
  int* cntA     = wsI;                       // NRp
  int* cntB     = cntA + NRp;                // NRp
  int* binCntA  = cntB + NRp;                // NBPAD
  int* binCntB  = binCntA + NBPAD;           // NBPAD
  float* hacc   = (float*)(binCntB + NBPAD); // 32
  float* vbuf   = hacc + 32;                 // 32
  // --- end of memset region ---
  int* binStartA = (int*)(vbuf + 32);        // NBPAD
  int* binCurA   = binStartA + NBPAD;
  int* binStartB = binCurA + NBPAD;
  int* binCurB   = binStartB + NBPAD;
  int* grpBaseA  = binCurB + NBPAD;          // NBLK*GCAP
  int* grpMetaA  = grpBaseA + NBLK * GCAP;
  int* grpNA     = grpMetaA + NBLK * GCAP;   // 320
  int* grpBaseB  = grpNA + 320;
  int* grpMetaB  = grpBaseB + NBLK * GCAP;
  int* grpNB     = grpMetaB + NBLK * GCAP;   // 320
  int* mA        = grpNB + 320;              // NE
  int* mB        = mA + NE;                  // NE
  float* ivA     = (float*)(mB + NE);        // NE
  float* ivB     = ivA + NE;                 // NE
  // bf16 region
  unsigned short* xo16    = (unsigned short*)(ivB + NE);   // NN*FF
  unsigned short* xa16    = xo16 + (size_t)NN * FF;
  unsigned short* x1o16   = xa16 + (size_t)NN * FF;        // NN*H1 x3
  unsigned short* x1a16   = x1o16 + (size_t)NN * H1;
  unsigned short* x1aa16  = x1a16 + (size_t)NN * H1;
  unsigned short* x2ob    = x1aa16 + (size_t)NN * H1;      // NN*H2 x3
  unsigned short* x2oab   = x2ob + (size_t)NN * H2;
  unsigned short* x2oaab  = x2oab + (size_t)NN * H2;
  unsigned short* rootO16 = x2oaab + (size_t)NN * H2;      // NN*H1 x2
  unsigned short* rootA16 = rootO16 + (size_t)NN * H1;
  unsigned short* r2o16   = rootA16 + (size_t)NN * H1;     // NN*H2 x3
  unsigned short* r2a16   = r2o16 + (size_t)NN * H2;
  unsigned short* r2aa16  = r2a16 + (size_t)NN * H2;
  unsigned short* W1f     = r2aa16 + (size_t)NN * H2;      // RR*16*64*8
  unsigned short* W2f     = W1f + (size_t)RR * 16 * 64 * 8;

  float* outF   = (float*)d_out;
  float* o_log  = outF;
  float* o_ros  = outF + (size_t)BQ * RR;
  float* o_rosa = o_ros + (size_t)NN * 2;
  float* o_x2o  = o_rosa + (size_t)NN * 2;

  hipMemsetAsync(wsI, 0, (2 * NRp + 2 * NBPAD + 64) * sizeof(int), stream);

  // prep (independent of hist chain)
  k_cvt2<<<(2 * NN * FF / 8 + 255) / 256, 256, 0, stream>>>(
      (const float4*)x_o, (const float4*)x_a, (uint4*)xo16, (uint4*)xa16, NN * FF / 8);
  k_wprep1<<<RR, 256, 0, stream>>>(W1, W1f);
  k_wprep2<<<RR, 256, 0, stream>>>(W2, W2f);
  k_root1<<<(NN * H1) / 256, 256, 0, stream>>>(x_o, x_a, rt1, b1, rootO16, rootA16);

  k_hist<<<(NE + 255) / 256, 256, 0, stream>>>(ei, etA, etB, cntA, cntB, binCntA, binCntB);
  k_prefixB<<<1, 256, 0, stream>>>(binCntA, binStartA, binCurA, binCntB, binStartB, binCurB);
  k_scatter2<<<(NE + 255) / 256, 256, 0, stream>>>(ei, etA, etB, cntA, cntB,
                                                   binCurA, binCurB, mA, ivA, mB, ivB);
  k_groups<<<NBLK, 128, 0, stream>>>(binStartA, binCntA, grpBaseA, grpMetaA, grpNA);
  k_groups<<<NBLK, 128, 0, stream>>>(binStartB, binCntB, grpBaseB, grpMetaB, grpNB);

  k_edgeF1<2><<<NBLK, 512, 0, stream>>>(mA, ivA, grpBaseA, grpMetaA, grpNA, W1f,
                                        xo16, xa16, rootO16, rootA16, x1o16, x1a16);
  k_edgeF1<1><<<NBLK, 512, 0, stream>>>(mB, ivB, grpBaseB, grpMetaB, grpNB, W1f,
                                        xo16, nullptr, rootO16, nullptr, x1aa16, nullptr);

  k_root2x3<<<(NN * H2 + 255) / 256, 256, 0, stream>>>(x1o16, x1a16, x1aa16, rt2, b2,
                                                       r2o16, r2a16, r2aa16);
  k_edgeF2<2><<<NBLK, 512, 0, stream>>>(mA, ivA, grpBaseA, grpMetaA, grpNA, W2f,
                                        x1o16, x1a16, r2o16, r2a16, x2ob, x2oab, o_x2o);
  k_edgeF2<1><<<NBLK, 512, 0, stream>>>(mB, ivB, grpBaseB, grpMetaB, grpNB, W2f,
                                        x1aa16, nullptr, r2aa16, nullptr, x2oaab, nullptr,
                                        nullptr);

  k_colsum<<<128, 256, 0, stream>>>(o_x2o, hacc);
  k_disc<<<1, 64, 0, stream>>>(hacc, dw, vbuf);
  k_ret<<<(NN + 255) / 256, 256, 0, stream>>>(x2ob, x2oab, x2oaab, vbuf, db, o_ros, o_rosa);
  k_cls<<<BQ, 128, 0, stream>>>(idx, x1o16, o_x2o, attt, cw, cb, o_log);
}

// Round 13
// 2356.468 us; speedup vs baseline: 1.0007x; 1.0007x over previous
//
#include <hip/hip_runtime.h>

// ---- problem dims ----
#define NN 20000
#define NE 640000
#define FF 128
#define H1 64
#define H2 32
#define RR 65
#define BQ 4096
#define NR (NN*RR)

#define DBLK 64               // dsts per block
#define NBLK 313              // ceil(20000/64)
#define NB (NBLK*RR)          // 20345 bins
#define NBPAD 20480
#define GCAP 512              // groups per block cap (avg ~190)
#define H1P 68                // padded LDS row (bank spread)
#define H2P 36

typedef __attribute__((ext_vector_type(8))) short bhalf8;   // 8 bf16 (4 VGPRs)
typedef __attribute__((ext_vector_type(4))) float f32x4;
#define MFMA16(a, b, c) __builtin_amdgcn_mfma_f32_16x16x32_bf16(a, b, c, 0, 0, 0)

__device__ __forceinline__ unsigned short f2bf(float f) {
  unsigned int u = __float_as_uint(f);
  unsigned int r = (u + 0x7fffu + ((u >> 16) & 1u)) >> 16;   // RNE
  return (unsigned short)r;
}
__device__ __forceinline__ float bf2f(unsigned short u) {
  return __uint_as_float((unsigned)u << 16);
}

// ===================== histogram: (dst,rel) cnt + (dstblock64,rel) bin cnt =========
__global__ __launch_bounds__(256) void k_hist(
    const int* __restrict__ ei, const int* __restrict__ etA, const int* __restrict__ etB,
    int* __restrict__ cntA, int* __restrict__ cntB,
    int* __restrict__ binCntA, int* __restrict__ binCntB) {
  int e = blockIdx.x * blockDim.x + threadIdx.x;
  if (e >= NE) return;
  int d = ei[NE + e];
  int ta = etA[e], tb = etB[e];
  atomicAdd(&cntA[(size_t)d * RR + ta], 1);
  atomicAdd(&cntB[(size_t)d * RR + tb], 1);
  atomicAdd(&binCntA[(d >> 6) * RR + ta], 1);
  atomicAdd(&binCntB[(d >> 6) * RR + tb], 1);
}

// ===================== exclusive scan over 20345 bins (both streams, 1 block) ======
__global__ __launch_bounds__(256) void k_prefixB(
    const int* __restrict__ cA, int* __restrict__ sA, int* __restrict__ uA,
    const int* __restrict__ cB, int* __restrict__ sB, int* __restrict__ uB) {
  __shared__ int ps[256];
  __shared__ int pb[257];
  int t = threadIdx.x;
  int c0 = t * 80;
  int c1 = (c0 + 80 < NB) ? (c0 + 80) : NB;
  {
    int s = 0;
    for (int i = c0; i < c1; ++i) s += cA[i];
    ps[t] = s;
    __syncthreads();
    if (t == 0) { int a = 0; for (int i = 0; i < 256; ++i) { pb[i] = a; a += ps[i]; } }
    __syncthreads();
    int run = pb[t];
    for (int i = c0; i < c1; ++i) { sA[i] = run; uA[i] = run; run += cA[i]; }
    __syncthreads();
  }
  {
    int s = 0;
    for (int i = c0; i < c1; ++i) s += cB[i];
    ps[t] = s;
    __syncthreads();
    if (t == 0) { int a = 0; for (int i = 0; i < 256; ++i) { pb[i] = a; a += ps[i]; } }
    __syncthreads();
    int run = pb[t];
    for (int i = c0; i < c1; ++i) { sB[i] = run; uB[i] = run; run += cB[i]; }
  }
}

// ===================== scatter edges into bins with packed meta =====================
// m = src | dstLocal<<20 ; iv = 1/cnt(dst,rel)
__global__ __launch_bounds__(256) void k_scatter2(
    const int* __restrict__ ei, const int* __restrict__ etA, const int* __restrict__ etB,
    const int* __restrict__ cntA, const int* __restrict__ cntB,
    int* __restrict__ binCurA, int* __restrict__ binCurB,
    int* __restrict__ mA, float* __restrict__ ivA,
    int* __restrict__ mB, float* __restrict__ ivB) {
  int e = blockIdx.x * blockDim.x + threadIdx.x;
  if (e >= NE) return;
  int s = ei[e], d = ei[NE + e];
  int mm = s | ((d & (DBLK - 1)) << 20);
  {
    int t = etA[e];
    int p = atomicAdd(&binCurA[(d >> 6) * RR + t], 1);
    mA[p] = mm;
    ivA[p] = 1.0f / (float)cntA[(size_t)d * RR + t];
  }
  {
    int t = etB[e];
    int p = atomicAdd(&binCurB[(d >> 6) * RR + t], 1);
    mB[p] = mm;
    ivB[p] = 1.0f / (float)cntB[(size_t)d * RR + t];
  }
}

// ===================== flat padded 16-edge group list per block =====================
// grpMeta = rel | lim<<8 (lim = edges in this group, <=16); grpBase = edge offset.
__global__ __launch_bounds__(128) void k_groups(
    const int* __restrict__ binStart, const int* __restrict__ binCnt,
    int* __restrict__ grpBase, int* __restrict__ grpMeta, int* __restrict__ grpN) {
  __shared__ int ngS[RR], gsS[RR];
  int b = blockIdx.x, t = threadIdx.x;
  if (t < RR) ngS[t] = (binCnt[b * RR + t] + 15) >> 4;
  __syncthreads();
  if (t == 0) {
    int a = 0;
    for (int i = 0; i < RR; ++i) { gsS[i] = a; a += ngS[i]; }
    grpN[b] = (a < GCAP) ? a : GCAP;
  }
  __syncthreads();
  if (t < RR) {
    int g = gsS[t];
    int bin = b * RR + t;
    int bs = binStart[bin];
    int c = binCnt[bin];
    while (c > 0 && g < GCAP) {
      int lim = (c < 16) ? c : 16;
      grpBase[b * GCAP + g] = bs;
      grpMeta[b * GCAP + g] = t | (lim << 8);
      ++g; bs += 16; c -= 16;
    }
  }
}

// ===================== fp32 -> bf16 conversion for x_o and x_a ====================
__global__ __launch_bounds__(256) void k_cvt2(const float4* __restrict__ inA,
                                              const float4* __restrict__ inB,
                                              uint4* __restrict__ outA,
                                              uint4* __restrict__ outB, int n8) {
  int i = blockIdx.x * blockDim.x + threadIdx.x;
  if (i >= 2 * n8) return;
  const float4* in = (i < n8) ? inA : inB;
  uint4* out = (i < n8) ? outA : outB;
  int j = (i < n8) ? i : i - n8;
  float4 a = in[2 * j], b = in[2 * j + 1];
  uint4 o;
  o.x = (unsigned)f2bf(a.x) | ((unsigned)f2bf(a.y) << 16);
  o.y = (unsigned)f2bf(a.z) | ((unsigned)f2bf(a.w) << 16);
  o.z = (unsigned)f2bf(b.x) | ((unsigned)f2bf(b.y) << 16);
  o.w = (unsigned)f2bf(b.z) | ((unsigned)f2bf(b.w) << 16);
  out[j] = o;
}

// ===================== W1 -> bf16 B-fragments =====================
__global__ __launch_bounds__(256) void k_wprep1(const float* __restrict__ W,
                                                unsigned short* __restrict__ Wf) {
  int r = blockIdx.x;
  int lane = threadIdx.x & 63, w = threadIdx.x >> 6;
#pragma unroll
  for (int s4 = 0; s4 < 4; ++s4) {
    int slot = w * 4 + s4;
    int ks = slot >> 2, n = slot & 3;
    int krow = ks * 32 + ((lane >> 4) << 3);
    int colo = n * 16 + (lane & 15);
    unsigned short* o = Wf + (((size_t)r * 16 + slot) * 64 + lane) * 8;
#pragma unroll
    for (int j = 0; j < 8; ++j)
      o[j] = f2bf(W[((size_t)r * FF + krow + j) * H1 + colo]);
  }
}

// ===================== W2 -> bf16 B-fragments =====================
__global__ __launch_bounds__(256) void k_wprep2(const float* __restrict__ W,
                                                unsigned short* __restrict__ Wf) {
  int r = blockIdx.x;
  int lane = threadIdx.x & 63, slot = threadIdx.x >> 6;
  int ks = slot >> 1, n = slot & 1;
  int krow = ks * 32 + ((lane >> 4) << 3);
  int colo = n * 16 + (lane & 15);
  unsigned short* o = Wf + (((size_t)r * 4 + slot) * 64 + lane) * 8;
#pragma unroll
  for (int j = 0; j < 8; ++j)
    o[j] = f2bf(W[((size_t)r * H1 + krow + j) * H2 + colo]);
}

// ===================== layer-1 root terms -> bf16 =====================
__global__ __launch_bounds__(256) void k_root1(
    const float* __restrict__ xo, const float* __restrict__ xa,
    const float* __restrict__ rt, const float* __restrict__ b,
    unsigned short* __restrict__ rO, unsigned short* __restrict__ rA) {
  int lane = threadIdx.x & 63;
  int n = (blockIdx.x * blockDim.x + threadIdx.x) >> 6;
  if (n >= NN) return;
  const float4* xo4 = (const float4*)(xo + (size_t)n * FF);
  const float4* xa4 = (const float4*)(xa + (size_t)n * FF);
  float so = b[lane], sa = so;
#pragma unroll
  for (int j = 0; j < FF / 4; ++j) {
    float vo[4], va[4];
    *(float4*)vo = xo4[j];
    *(float4*)va = xa4[j];
#pragma unroll
    for (int t = 0; t < 4; ++t) {
      float wv = rt[(4 * j + t) * H1 + lane];
      so = fmaf(vo[t], wv, so);
      sa = fmaf(va[t], wv, sa);
    }
  }
  rO[(size_t)n * H1 + lane] = f2bf(so);
  rA[(size_t)n * H1 + lane] = f2bf(sa);
}

// ===================== layer-1 edge GEMM + LDS fp32 aggregation (flat groups) ======
// r13 FIX: unsafeAtomicAdd on the LDS tile -> native no-return ds_add_f32.
// (plain atomicAdd on LDS f32 = CAS retry loop with serializing lgkmcnt waits —
//  the ~25x stall of r11/r12: 32 atomics/group x ~130cy round-trip each.)
template <int NIN>
__global__ __launch_bounds__(512, 2) void k_edgeF1(
    const int* __restrict__ mP, const float* __restrict__ ivP,
    const int* __restrict__ grpBase, const int* __restrict__ grpMeta,
    const int* __restrict__ grpN,
    const unsigned short* __restrict__ Wf,
    const unsigned short* __restrict__ xA16, const unsigned short* __restrict__ xB16,
    const unsigned short* __restrict__ root0, const unsigned short* __restrict__ root1,
    unsigned short* __restrict__ y0, unsigned short* __restrict__ y1) {
  __shared__ float yT[NIN][DBLK][H1P];
  const int b = blockIdx.x;
  const int tid = threadIdx.x;
  {
    float4* p = (float4*)yT;
    for (int i = tid; i < NIN * DBLK * H1P / 4; i += 512) p[i] = float4{0.f, 0.f, 0.f, 0.f};
  }
  __syncthreads();
  const int lane = tid & 63;
  const int wv = tid >> 6;
  const int cg = lane >> 4;
  const int col = lane & 15;
  const int row0 = cg << 2;
  const int NG = grpN[b];
  const int g0 = (NG * wv) >> 3;
  const int g1 = (NG * (wv + 1)) >> 3;

  if (g0 < g1) {
    const int* gB = grpBase + b * GCAP;
    const int* gM = grpMeta + b * GCAP;
    int gbC = gB[g0], gmC = gM[g0];
    int gn1 = (g0 + 1 < g1) ? (g0 + 1) : (g1 - 1);
    int gbN = gB[gn1], gmN = gM[gn1];
    int offC = gbC + ((col < (gmC >> 8)) ? col : 0);
    int mC = mP[offC];
    float ivC = (col < (gmC >> 8)) ? ivP[offC] : 0.f;
    int relC = -1;
    bhalf8 wb[16];

    for (int g = g0; g < g1; ++g) {
      const int gn2 = (g + 2 < g1) ? (g + 2) : (g1 - 1);
      const int gbN2 = gB[gn2], gmN2 = gM[gn2];
      const int offN = gbN + ((col < (gmN >> 8)) ? col : 0);
      const int mN = mP[offN];
      const float ivN = (col < (gmN >> 8)) ? ivP[offN] : 0.f;

      const int rel = gmC & 0xFF;
      if (rel != relC) {
        relC = rel;
        const bhalf8* wf = (const bhalf8*)Wf + ((size_t)rel * 16) * 64 + lane;
#pragma unroll
        for (int s = 0; s < 16; ++s) wb[s] = wf[(size_t)s * 64];
      }
      const int src = mC & 0xFFFFF;
      const int dl = ((unsigned)mC) >> 20;
      const int dl0 = __shfl(dl, row0),     dl1 = __shfl(dl, row0 + 1),
                dl2 = __shfl(dl, row0 + 2), dl3 = __shfl(dl, row0 + 3);
      const float i0 = __shfl(ivC, row0),     i1 = __shfl(ivC, row0 + 1),
                  i2 = __shfl(ivC, row0 + 2), i3 = __shfl(ivC, row0 + 3);
#pragma unroll
      for (int in = 0; in < NIN; ++in) {
        const unsigned short* xp = (in == 0) ? xA16 : xB16;
        const bhalf8* xr = (const bhalf8*)xp + ((size_t)src << 4);
        bhalf8 a0 = xr[cg], a1 = xr[4 + cg], a2 = xr[8 + cg], a3 = xr[12 + cg];
        f32x4 c0 = {0.f,0.f,0.f,0.f}, c1 = c0, c2 = c0, c3 = c0;
        c0 = MFMA16(a0, wb[0], c0);  c1 = MFMA16(a0, wb[1], c1);
        c2 = MFMA16(a0, wb[2], c2);  c3 = MFMA16(a0, wb[3], c3);
        c0 = MFMA16(a1, wb[4], c0);  c1 = MFMA16(a1, wb[5], c1);
        c2 = MFMA16(a1, wb[6], c2);  c3 = MFMA16(a1, wb[7], c3);
        c0 = MFMA16(a2, wb[8], c0);  c1 = MFMA16(a2, wb[9], c1);
        c2 = MFMA16(a2, wb[10], c2); c3 = MFMA16(a2, wb[11], c3);
        c0 = MFMA16(a3, wb[12], c0); c1 = MFMA16(a3, wb[13], c1);
        c2 = MFMA16(a3, wb[14], c2); c3 = MFMA16(a3, wb[15], c3);
        const f32x4 cc[4] = {c0, c1, c2, c3};
#pragma unroll
        for (int n = 0; n < 4; ++n) {
          unsafeAtomicAdd(&yT[in][dl0][n * 16 + col], cc[n][0] * i0);
          unsafeAtomicAdd(&yT[in][dl1][n * 16 + col], cc[n][1] * i1);
          unsafeAtomicAdd(&yT[in][dl2][n * 16 + col], cc[n][2] * i2);
          unsafeAtomicAdd(&yT[in][dl3][n * 16 + col], cc[n][3] * i3);
        }
      }
      gbC = gbN; gmC = gmN; mC = mN; ivC = ivN;
      gbN = gbN2; gmN = gmN2;
    }
  }
  __syncthreads();
  const int dBase = b * DBLK;
  for (int i = tid; i < DBLK * H1; i += 512) {
    int dl = i >> 6, c = i & 63;
    int d = dBase + dl;
    if (d < NN) {
      size_t o = (size_t)d * H1 + c;
      float v0 = bf2f(root0[o]) + yT[0][dl][c];
      y0[o] = f2bf(fmaxf(v0, 0.f));
      if constexpr (NIN == 2) {
        float v1 = bf2f(root1[o]) + yT[1][dl][c];
        y1[o] = f2bf(fmaxf(v1, 0.f));
      }
    }
  }
}

// ===================== layer-2 root terms (bf16 in/out), 3 fused =====================
__global__ __launch_bounds__(256) void k_root2x3(
    const unsigned short* __restrict__ x1o, const unsigned short* __restrict__ x1a,
    const unsigned short* __restrict__ x1aa,
    const float* __restrict__ rt, const float* __restrict__ b,
    unsigned short* __restrict__ y0, unsigned short* __restrict__ y1,
    unsigned short* __restrict__ y2) {
  int i = blockIdx.x * blockDim.x + threadIdx.x;
  if (i >= NN * H2) return;
  int o = i & (H2 - 1);
  int n = i >> 5;
  const uint2* p0 = (const uint2*)(x1o + (size_t)n * H1);
  const uint2* p1 = (const uint2*)(x1a + (size_t)n * H1);
  const uint2* p2 = (const uint2*)(x1aa + (size_t)n * H1);
  float s0 = b[o], s1 = s0, s2 = s0;
#pragma unroll
  for (int j = 0; j < 16; ++j) {
    uint2 u0 = p0[j], u1 = p1[j], u2 = p2[j];
#pragma unroll
    for (int t = 0; t < 4; ++t) {
      unsigned w0 = (t < 2) ? u0.x : u0.y;
      unsigned w1 = (t < 2) ? u1.x : u1.y;
      unsigned w2 = (t < 2) ? u2.x : u2.y;
      int sh = (t & 1) * 16;
      float wv = rt[(4 * j + t) * H2 + o];
      s0 = fmaf(bf2f((unsigned short)(w0 >> sh)), wv, s0);
      s1 = fmaf(bf2f((unsigned short)(w1 >> sh)), wv, s1);
      s2 = fmaf(bf2f((unsigned short)(w2 >> sh)), wv, s2);
    }
  }
  y0[i] = f2bf(s0); y1[i] = f2bf(s1); y2[i] = f2bf(s2);
}

// ===================== layer-2 edge GEMM + LDS aggregation (flat groups) ===========
template <int NIN>
__global__ __launch_bounds__(512, 2) void k_edgeF2(
    const int* __restrict__ mP, const float* __restrict__ ivP,
    const int* __restrict__ grpBase, const int* __restrict__ grpMeta,
    const int* __restrict__ grpN,
    const unsigned short* __restrict__ Wf,
    const unsigned short* __restrict__ xA16, const unsigned short* __restrict__ xB16,
    const unsigned short* __restrict__ root0, const unsigned short* __restrict__ root1,
    unsigned short* __restrict__ y0, unsigned short* __restrict__ y1,
    float* __restrict__ f32out) {
  __shared__ float yT[NIN][DBLK][H2P];
  const int b = blockIdx.x;
  const int tid = threadIdx.x;
  {
    float4* p = (float4*)yT;
    for (int i = tid; i < NIN * DBLK * H2P / 4; i += 512) p[i] = float4{0.f, 0.f, 0.f, 0.f};
  }
  __syncthreads();
  const int lane = tid & 63;
  const int wv = tid >> 6;
  const int cg = lane >> 4;
  const int col = lane & 15;
  const int row0 = cg << 2;
  const int NG = grpN[b];
  const int g0 = (NG * wv) >> 3;
  const int g1 = (NG * (wv + 1)) >> 3;

  if (g0 < g1) {
    const int* gB = grpBase + b * GCAP;
    const int* gM = grpMeta + b * GCAP;
    int gbC = gB[g0], gmC = gM[g0];
    int gn1 = (g0 + 1 < g1) ? (g0 + 1) : (g1 - 1);
    int gbN = gB[gn1], gmN = gM[gn1];
    int offC = gbC + ((col < (gmC >> 8)) ? col : 0);
    int mC = mP[offC];
    float ivC = (col < (gmC >> 8)) ? ivP[offC] : 0.f;
    int relC = -1;
    bhalf8 wb[4];

    for (int g = g0; g < g1; ++g) {
      const int gn2 = (g + 2 < g1) ? (g + 2) : (g1 - 1);
      const int gbN2 = gB[gn2], gmN2 = gM[gn2];
      const int offN = gbN + ((col < (gmN >> 8)) ? col : 0);
      const int mN = mP[offN];
      const float ivN = (col < (gmN >> 8)) ? ivP[offN] : 0.f;

      const int rel = gmC & 0xFF;
      if (rel != relC) {
        relC = rel;
        const bhalf8* wf = (const bhalf8*)Wf + ((size_t)rel * 4) * 64 + lane;
#pragma unroll
        for (int s = 0; s < 4; ++s) wb[s] = wf[(size_t)s * 64];
      }
      const int src = mC & 0xFFFFF;
      const int dl = ((unsigned)mC) >> 20;
      const int dl0 = __shfl(dl, row0),     dl1 = __shfl(dl, row0 + 1),
                dl2 = __shfl(dl, row0 + 2), dl3 = __shfl(dl, row0 + 3);
      const float i0 = __shfl(ivC, row0),     i1 = __shfl(ivC, row0 + 1),
                  i2 = __shfl(ivC, row0 + 2), i3 = __shfl(ivC, row0 + 3);
#pragma unroll
      for (int in = 0; in < NIN; ++in) {
        const unsigned short* xp = (in == 0) ? xA16 : xB16;
        const bhalf8* xr = (const bhalf8*)xp + ((size_t)src << 3);
        bhalf8 a0 = xr[cg], a1 = xr[4 + cg];
        f32x4 c0 = {0.f,0.f,0.f,0.f}, c1 = c0;
        c0 = MFMA16(a0, wb[0], c0); c1 = MFMA16(a0, wb[1], c1);
        c0 = MFMA16(a1, wb[2], c0); c1 = MFMA16(a1, wb[3], c1);
        const f32x4 cc[2] = {c0, c1};
#pragma unroll
        for (int n = 0; n < 2; ++n) {
          unsafeAtomicAdd(&yT[in][dl0][n * 16 + col], cc[n][0] * i0);
          unsafeAtomicAdd(&yT[in][dl1][n * 16 + col], cc[n][1] * i1);
          unsafeAtomicAdd(&yT[in][dl2][n * 16 + col], cc[n][2] * i2);
          unsafeAtomicAdd(&yT[in][dl3][n * 16 + col], cc[n][3] * i3);
        }
      }
      gbC = gbN; gmC = gmN; mC = mN; ivC = ivN;
      gbN = gbN2; gmN = gmN2;
    }
  }
  __syncthreads();
  const int dBase = b * DBLK;
  for (int i = tid; i < DBLK * H2; i += 512) {
    int dl = i >> 5, c = i & 31;
    int d = dBase + dl;
    if (d < NN) {
      size_t o = (size_t)d * H2 + c;
      float v0 = bf2f(root0[o]) + yT[0][dl][c];
      y0[o] = f2bf(v0);
      if (f32out) f32out[o] = v0;
      if constexpr (NIN == 2) {
        float v1 = bf2f(root1[o]) + yT[1][dl][c];
        y1[o] = f2bf(v1);
      }
    }
  }
}

// ===================== column sum of x2_o (fp32) -> hacc[32] =====================
__global__ __launch_bounds__(256) void k_colsum(const float* __restrict__ x2o,
                                                float* __restrict__ hacc) {
  int tid = threadIdx.x;
  int col = tid & 31;
  int rgrp = blockIdx.x * (blockDim.x >> 5) + (tid >> 5);
  int nth = gridDim.x * (blockDim.x >> 5);
  float s = 0.f;
  for (int n = rgrp; n < NN; n += nth) s += x2o[(size_t)n * H2 + col];
  unsafeAtomicAdd(&hacc[col], s);
}

// ===================== h_os = sigmoid(mean); v = disc_w @ h_os =====================
__global__ __launch_bounds__(64) void k_disc(const float* __restrict__ hacc,
                                             const float* __restrict__ dw,
                                             float* __restrict__ vout) {
  __shared__ float hos[H2];
  int t = threadIdx.x;
  if (t < H2) hos[t] = 1.0f / (1.0f + expf(-hacc[t] / (float)NN));
  __syncthreads();
  if (t < H2) {
    float s = 0.f;
#pragma unroll
    for (int k = 0; k < H2; ++k) s = fmaf(dw[t * H2 + k], hos[k], s);
    vout[t] = s;
  }
}

// ===================== ret_os / ret_os_a (bf16 x2 inputs) =====================
__global__ __launch_bounds__(256) void k_ret(
    const unsigned short* __restrict__ x2o, const unsigned short* __restrict__ x2oa,
    const unsigned short* __restrict__ x2oaa,
    const float* __restrict__ v, const float* __restrict__ db,
    float* __restrict__ ros, float* __restrict__ rosa) {
  int n = blockIdx.x * blockDim.x + threadIdx.x;
  if (n >= NN) return;
  const uint2* a2 = (const uint2*)(x2o + (size_t)n * H2);
  const uint2* b2 = (const uint2*)(x2oa + (size_t)n * H2);
  const uint2* c2 = (const uint2*)(x2oaa + (size_t)n * H2);
  const float4* v4 = (const float4*)v;
  float r0 = 0.f, r1 = 0.f, r2 = 0.f;
#pragma unroll
  for (int j = 0; j < 8; ++j) {
    uint2 ua = a2[j], ub = b2[j], uc = c2[j];
    float4 vv = v4[j];
    r0 += bf2f((unsigned short)ua.x) * vv.x + bf2f((unsigned short)(ua.x >> 16)) * vv.y
        + bf2f((unsigned short)ua.y) * vv.z + bf2f((unsigned short)(ua.y >> 16)) * vv.w;
    r1 += bf2f((unsigned short)ub.x) * vv.x + bf2f((unsigned short)(ub.x >> 16)) * vv.y
        + bf2f((unsigned short)ub.y) * vv.z + bf2f((unsigned short)(ub.y >> 16)) * vv.w;
    r2 += bf2f((unsigned short)uc.x) * vv.x + bf2f((unsigned short)(uc.x >> 16)) * vv.y
        + bf2f((unsigned short)uc.y) * vv.z + bf2f((unsigned short)(uc.y >> 16)) * vv.w;
  }
  float bb = db[0];
  ros[n * 2] = r0 + bb;  ros[n * 2 + 1] = r1 + bb;
  rosa[n * 2] = r0 + bb; rosa[n * 2 + 1] = r2 + bb;
}

// ===================== classifier (x1o bf16, x2o fp32) =====================
__global__ __launch_bounds__(128) void k_cls(
    const int* __restrict__ idx, const unsigned short* __restrict__ x1o,
    const float* __restrict__ x2o,
    const float* __restrict__ attt, const float* __restrict__ cw, const float* __restrict__ cb,
    float* __restrict__ lg) {
  int b = blockIdx.x;
  int r = threadIdx.x;
  if (r >= RR) return;
  int i1 = idx[b], i2 = idx[BQ + b];
  float a0 = attt[0], a1 = attt[1];
  float acc = cb[r];
  const uint2* q1 = (const uint2*)(x1o + (size_t)i1 * H1);
  const float4* q2 = (const float4*)(x2o + (size_t)i1 * H2);
  const uint2* q3 = (const uint2*)(x1o + (size_t)i2 * H1);
  const float4* q4 = (const float4*)(x2o + (size_t)i2 * H2);
#pragma unroll
  for (int j = 0; j < 16; ++j) {
    uint2 u = q1[j];
    float v0 = bf2f((unsigned short)u.x), v1 = bf2f((unsigned short)(u.x >> 16));
    float v2 = bf2f((unsigned short)u.y), v3 = bf2f((unsigned short)(u.y >> 16));
    acc = fmaf(a0 * v0, cw[(4 * j) * RR + r], acc);
    acc = fmaf(a0 * v1, cw[(4 * j + 1) * RR + r], acc);
    acc = fmaf(a0 * v2, cw[(4 * j + 2) * RR + r], acc);
    acc = fmaf(a0 * v3, cw[(4 * j + 3) * RR + r], acc);
  }
#pragma unroll
  for (int j = 0; j < H2 / 4; ++j) {
    float v[4]; *(float4*)v = q2[j];
#pragma unroll
    for (int t = 0; t < 4; ++t) acc = fmaf(a1 * v[t], cw[(H1 + 4 * j + t) * RR + r], acc);
  }
#pragma unroll
  for (int j = 0; j < 16; ++j) {
    uint2 u = q3[j];
    float v0 = bf2f((unsigned short)u.x), v1 = bf2f((unsigned short)(u.x >> 16));
    float v2 = bf2f((unsigned short)u.y), v3 = bf2f((unsigned short)(u.y >> 16));
    acc = fmaf(a0 * v0, cw[(96 + 4 * j) * RR + r], acc);
    acc = fmaf(a0 * v1, cw[(96 + 4 * j + 1) * RR + r], acc);
    acc = fmaf(a0 * v2, cw[(96 + 4 * j + 2) * RR + r], acc);
    acc = fmaf(a0 * v3, cw[(96 + 4 * j + 3) * RR + r], acc);
  }
#pragma unroll
  for (int j = 0; j < H2 / 4; ++j) {
    float v[4]; *(float4*)v = q4[j];
#pragma unroll
    for (int t = 0; t < 4; ++t) acc = fmaf(a1 * v[t], cw[(96 + H1 + 4 * j + t) * RR + r], acc);
  }
  lg[(size_t)b * RR + r] = acc;
}

// ===================== launch =====================
extern "C" void kernel_launch(void* const* d_in, const int* in_sizes, int n_in,
                              void* d_out, int out_size, void* d_ws, size_t ws_size,
                              hipStream_t stream) {
  const float* x_o  = (const float*)d_in[0];
  const float* x_a  = (const float*)d_in[1];
  const int*   ei   = (const int*)d_in[2];
  const int*   etA  = (const int*)d_in[3];
  const int*   etB  = (const int*)d_in[4];
  const int*   idx  = (const int*)d_in[5];
  const float* W1   = (const float*)d_in[6];
  const float* rt1  = (const float*)d_in[7];
  const float* b1   = (const float*)d_in[8];
  const float* W2   = (const float*)d_in[9];
  const float* rt2  = (const float*)d_in[10];
  const float* b2   = (const float*)d_in[11];
  const float* attt = (const float*)d_in[12];
  const float* dw   = (const float*)d_in[13];
  const float* db   = (const float*)d_in[14];
  const float* cw   = (const float*)d_in[15];
  const float* cb   = (const float*)d_in[16];

  const size_t NRp = 1300224;
  int* wsI      = (int*)d_ws;
  int* cntA     = wsI;                       // NRp
  int* cntB     = cntA + NRp;                // NRp
  int* binCntA  = cntB + NRp;                // NBPAD
  int* binCntB  = binCntA + NBPAD;           // NBPAD
  float* hacc   = (float*)(binCntB + NBPAD); // 32
  float* vbuf   = hacc + 32;                 // 32
  // --- end of memset region ---
  int* binStartA = (int*)(vbuf + 32);        // NBPAD
  int* binCurA   = binStartA + NBPAD;
  int* binStartB = binCurA + NBPAD;
  int* binCurB   = binStartB + NBPAD;
  int* grpBaseA  = binCurB + NBPAD;          // NBLK*GCAP
  int* grpMetaA  = grpBaseA + NBLK * GCAP;
  int* grpNA     = grpMetaA + NBLK * GCAP;   // 320
  int* grpBaseB  = grpNA + 320;
  int* grpMetaB  = grpBaseB + NBLK * GCAP;
  int* grpNB     = grpMetaB + NBLK * GCAP;   // 320
  int* mA        = grpNB + 320;              // NE
  int* mB        = mA + NE;                  // NE
  float* ivA     = (float*)(mB + NE);        // NE
  float* ivB     = ivA + NE;                 // NE
  // bf16 region
  unsigned short* xo16    = (unsigned short*)(ivB + NE);   // NN*FF
  unsigned short* xa16    = xo16 + (size_t)NN * FF;
  unsigned short* x1o16   = xa16 + (size_t)NN * FF;        // NN*H1 x3
  unsigned short* x1a16   = x1o16 + (size_t)NN * H1;
  unsigned short* x1aa16  = x1a16 + (size_t)NN * H1;
  unsigned short* x2ob    = x1aa16 + (size_t)NN * H1;      // NN*H2 x3
  unsigned short* x2oab   = x2ob + (size_t)NN * H2;
  unsigned short* x2oaab  = x2oab + (size_t)NN * H2;
  unsigned short* rootO16 = x2oaab + (size_t)NN * H2;      // NN*H1 x2
  unsigned short* rootA16 = rootO16 + (size_t)NN * H1;
  unsigned short* r2o16   = rootA16 + (size_t)NN * H1;     // NN*H2 x3
  unsigned short* r2a16   = r2o16 + (size_t)NN * H2;
  unsigned short* r2aa16  = r2a16 + (size_t)NN * H2;
  unsigned short* W1f     = r2aa16 + (size_t)NN * H2;      // RR*16*64*8
  unsigned short* W2f     = W1f + (size_t)RR * 16 * 64 * 8;

  float* outF   = (float*)d_out;
  float* o_log  = outF;
  float* o_ros  = outF + (size_t)BQ * RR;
  float* o_rosa = o_ros + (size_t)NN * 2;
  float* o_x2o  = o_rosa + (size_t)NN * 2;

  hipMemsetAsync(wsI, 0, (2 * NRp + 2 * NBPAD + 64) * sizeof(int), stream);

  // prep (independent of hist chain)
  k_cvt2<<<(2 * NN * FF / 8 + 255) / 256, 256, 0, stream>>>(
      (const float4*)x_o, (const float4*)x_a, (uint4*)xo16, (uint4*)xa16, NN * FF / 8);
  k_wprep1<<<RR, 256, 0, stream>>>(W1, W1f);
  k_wprep2<<<RR, 256, 0, stream>>>(W2, W2f);
  k_root1<<<(NN * H1) / 256, 256, 0, stream>>>(x_o, x_a, rt1, b1, rootO16, rootA16);

  k_hist<<<(NE + 255) / 256, 256, 0, stream>>>(ei, etA, etB, cntA, cntB, binCntA, binCntB);
  k_prefixB<<<1, 256, 0, stream>>>(binCntA, binStartA, binCurA, binCntB, binStartB, binCurB);
  k_scatter2<<<(NE + 255) / 256, 256, 0, stream>>>(ei, etA, etB, cntA, cntB,
                                                   binCurA, binCurB, mA, ivA, mB, ivB);
  k_groups<<<NBLK, 128, 0, stream>>>(binStartA, binCntA, grpBaseA, grpMetaA, grpNA);
  k_groups<<<NBLK, 128, 0, stream>>>(binStartB, binCntB, grpBaseB, grpMetaB, grpNB);

  k_edgeF1<2><<<NBLK, 512, 0, stream>>>(mA, ivA, grpBaseA, grpMetaA, grpNA, W1f,
                                        xo16, xa16, rootO16, rootA16, x1o16, x1a16);
  k_edgeF1<1><<<NBLK, 512, 0, stream>>>(mB, ivB, grpBaseB, grpMetaB, grpNB, W1f,
                                        xo16, nullptr, rootO16, nullptr, x1aa16, nullptr);

  k_root2x3<<<(NN * H2 + 255) / 256, 256, 0, stream>>>(x1o16, x1a16, x1aa16, rt2, b2,
                                                       r2o16, r2a16, r2aa16);
  k_edgeF2<2><<<NBLK, 512, 0, stream>>>(mA, ivA, grpBaseA, grpMetaA, grpNA, W2f,
                                        x1o16, x1a16, r2o16, r2a16, x2ob, x2oab, o_x2o);
  k_edgeF2<1><<<NBLK, 512, 0, stream>>>(mB, ivB, grpBaseB, grpMetaB, grpNB, W2f,
                                        x1aa16, nullptr, r2aa16, nullptr, x2oaab, nullptr,
                                        nullptr);

  k_colsum<<<128, 256, 0, stream>>>(o_x2o, hacc);
  k_disc<<<1, 64, 0, stream>>>(hacc, dw, vbuf);
  k_ret<<<(NN + 255) / 256, 256, 0, stream>>>(x2ob, x2oab, x2oaab, vbuf, db, o_ros, o_rosa);
  k_cls<<<BQ, 128, 0, stream>>>(idx, x1o16, o_x2o, attt, cw, cb, o_log);
}

// Round 14
// 1007.748 us; speedup vs baseline: 2.3401x; 2.3384x over previous
//
#include <hip/hip_runtime.h>

// ---- problem dims ----
#define NN 20000
#define NE 640000
#define FF 128
#define H1 64
#define H2 32
#define RR 65
#define BQ 4096
#define NR (NN*RR)

// ---- small scratch block offsets (ints within sm[1024]) ----
#define SM_HIST_A 0
#define SM_START_A 128
#define SM_CUR_A 256
#define SM_HIST_B 384
#define SM_START_B 512
#define SM_CUR_B 640
#define SM_HACC 768   // 32 floats
#define SM_V 832      // 32 floats

#define CPB1 32
#define CPB2 32

typedef __attribute__((ext_vector_type(8))) short bhalf8;   // 8 bf16 (4 VGPRs)
typedef __attribute__((ext_vector_type(4))) float f32x4;
#define MFMA16(a, b, c) __builtin_amdgcn_mfma_f32_16x16x32_bf16(a, b, c, 0, 0, 0)

__device__ __forceinline__ unsigned short f2bf(float f) {
  unsigned int u = __float_as_uint(f);
  unsigned int r = (u + 0x7fffu + ((u >> 16) & 1u)) >> 16;   // RNE
  return (unsigned short)r;
}
__device__ __forceinline__ float bf2f(unsigned short u) {
  return __uint_as_float((unsigned)u << 16);
}
// packed bf16x2 atomic add (2 values per memory-side RMW op)
__device__ __forceinline__ void atomPK(unsigned short* p, unsigned v) {
  asm volatile("global_atomic_pk_add_bf16 %0, %1, off"
               :: "v"((unsigned long long)p), "v"(v) : "memory");
}

// ===================== histogram =====================
__global__ __launch_bounds__(256) void k_hist(
    const int* __restrict__ ei, const int* __restrict__ etA, const int* __restrict__ etB,
    int* __restrict__ cntA, int* __restrict__ cntB, int* __restrict__ sm) {
  __shared__ int lh[2 * RR];
  int tid = threadIdx.x;
  for (int i = tid; i < 2 * RR; i += blockDim.x) lh[i] = 0;
  __syncthreads();
  int e = blockIdx.x * blockDim.x + tid;
  if (e < NE) {
    int dst = ei[NE + e];
    int ta = etA[e], tb = etB[e];
    atomicAdd(&cntA[dst * RR + ta], 1);
    atomicAdd(&cntB[dst * RR + tb], 1);
    atomicAdd(&lh[ta], 1);
    atomicAdd(&lh[RR + tb], 1);
  }
  __syncthreads();
  for (int i = tid; i < 2 * RR; i += blockDim.x) {
    int c = lh[i];
    if (c) atomicAdd(&sm[(i < RR) ? (SM_HIST_A + i) : (SM_HIST_B + (i - RR))], c);
  }
}

// ===================== exclusive prefix over 65 bins =====================
__global__ __launch_bounds__(128) void k_prefix(int* __restrict__ sm) {
  int w = threadIdx.x >> 6;
  if ((threadIdx.x & 63) == 0 && w < 2) {
    int hb = w ? SM_HIST_B : SM_HIST_A;
    int sb = w ? SM_START_B : SM_START_A;
    int cb = w ? SM_CUR_B : SM_CUR_A;
    int h[RR];
#pragma unroll
    for (int r = 0; r < RR; ++r) h[r] = sm[hb + r];
    int s = 0;
#pragma unroll
    for (int r = 0; r < RR; ++r) { sm[sb + r] = s; sm[cb + r] = s; s += h[r]; }
  }
}

// ===================== counting-sort scatter =====================
__global__ __launch_bounds__(256) void k_scatter(
    const int* __restrict__ etA, const int* __restrict__ etB,
    int* __restrict__ sm, int* __restrict__ ordA, int* __restrict__ ordB) {
  __shared__ int lhA[RR], lbA[RR], lhB[RR], lbB[RR];
  int tid = threadIdx.x;
  for (int i = tid; i < RR; i += blockDim.x) { lhA[i] = 0; lhB[i] = 0; }
  __syncthreads();
  int e = blockIdx.x * blockDim.x + tid;
  int ta = 0, tb = 0, ra = 0, rb = 0;
  bool valid = (e < NE);
  if (valid) {
    ta = etA[e]; tb = etB[e];
    ra = atomicAdd(&lhA[ta], 1);
    rb = atomicAdd(&lhB[tb], 1);
  }
  __syncthreads();
  for (int i = tid; i < RR; i += blockDim.x) {
    if (lhA[i]) lbA[i] = atomicAdd(&sm[SM_CUR_A + i], lhA[i]);
    if (lhB[i]) lbB[i] = atomicAdd(&sm[SM_CUR_B + i], lhB[i]);
  }
  __syncthreads();
  if (valid) { ordA[lbA[ta] + ra] = e; ordB[lbB[tb] + rb] = e; }
}

// ===================== flatten per-position edge meta (inv computed inline) ========
__global__ __launch_bounds__(256) void k_emeta(
    const int* __restrict__ ei, const int* __restrict__ ordA, const int* __restrict__ ordB,
    const int* __restrict__ cntA, const int* __restrict__ cntB,
    const int* __restrict__ etA, const int* __restrict__ etB,
    int2* __restrict__ sdA, float* __restrict__ ivA,
    int2* __restrict__ sdB, float* __restrict__ ivB) {
  int p = blockIdx.x * blockDim.x + threadIdx.x;
  if (p >= NE) return;
  {
    int e = ordA[p]; int s = ei[e], d = ei[NE + e]; int t = etA[e];
    sdA[p] = make_int2(s, d);
    ivA[p] = 1.0f / (float)cntA[(size_t)d * RR + t];
  }
  {
    int e = ordB[p]; int s = ei[e], d = ei[NE + e]; int t = etB[e];
    sdB[p] = make_int2(s, d);
    ivB[p] = 1.0f / (float)cntB[(size_t)d * RR + t];
  }
}

// ===================== fp32 -> bf16 conversion for x_o and x_a in one pass ==========
__global__ __launch_bounds__(256) void k_cvt2(const float4* __restrict__ inA,
                                              const float4* __restrict__ inB,
                                              uint4* __restrict__ outA,
                                              uint4* __restrict__ outB, int n8) {
  int i = blockIdx.x * blockDim.x + threadIdx.x;
  if (i >= 2 * n8) return;
  const float4* in = (i < n8) ? inA : inB;
  uint4* out = (i < n8) ? outA : outB;
  int j = (i < n8) ? i : i - n8;
  float4 a = in[2 * j], b = in[2 * j + 1];
  uint4 o;
  o.x = (unsigned)f2bf(a.x) | ((unsigned)f2bf(a.y) << 16);
  o.y = (unsigned)f2bf(a.z) | ((unsigned)f2bf(a.w) << 16);
  o.z = (unsigned)f2bf(b.x) | ((unsigned)f2bf(b.y) << 16);
  o.w = (unsigned)f2bf(b.z) | ((unsigned)f2bf(b.w) << 16);
  out[j] = o;
}

// ===================== in-place bf16 relu over contiguous x1 buffers ===============
__global__ __launch_bounds__(256) void k_relu16(uint4* __restrict__ a, int n4) {
  int i = blockIdx.x * blockDim.x + threadIdx.x;
  if (i >= n4) return;
  uint4 u = a[i];
  unsigned* w = (unsigned*)&u;
#pragma unroll
  for (int t = 0; t < 4; ++t) {
    unsigned lo = (w[t] & 0x8000u) ? 0u : (w[t] & 0xFFFFu);
    unsigned hi = (w[t] & 0x80000000u) ? 0u : (w[t] & 0xFFFF0000u);
    w[t] = lo | hi;
  }
  a[i] = u;
}

// ===================== W1 -> bf16 B-fragments =====================
__global__ __launch_bounds__(256) void k_wprep1(const float* __restrict__ W,
                                                unsigned short* __restrict__ Wf) {
  int r = blockIdx.x;
  int lane = threadIdx.x & 63, w = threadIdx.x >> 6;
#pragma unroll
  for (int s4 = 0; s4 < 4; ++s4) {
    int slot = w * 4 + s4;
    int ks = slot >> 2, n = slot & 3;
    int krow = ks * 32 + ((lane >> 4) << 3);
    int colo = n * 16 + (lane & 15);
    unsigned short* o = Wf + (((size_t)r * 16 + slot) * 64 + lane) * 8;
#pragma unroll
    for (int j = 0; j < 8; ++j)
      o[j] = f2bf(W[((size_t)r * FF + krow + j) * H1 + colo]);
  }
}

// ===================== W2 -> bf16 B-fragments (K=64, N=32 -> 4 slots/rel) ==========
__global__ __launch_bounds__(256) void k_wprep2(const float* __restrict__ W,
                                                unsigned short* __restrict__ Wf) {
  int r = blockIdx.x;
  int lane = threadIdx.x & 63, slot = threadIdx.x >> 6;
  int ks = slot >> 1, n = slot & 1;
  int krow = ks * 32 + ((lane >> 4) << 3);
  int colo = n * 16 + (lane & 15);
  unsigned short* o = Wf + (((size_t)r * 4 + slot) * 64 + lane) * 8;
#pragma unroll
  for (int j = 0; j < 8; ++j)
    o[j] = f2bf(W[((size_t)r * H1 + krow + j) * H2 + colo]);
}

// ===================== layer-1 root term -> bf16 accumulators =====================
__global__ __launch_bounds__(256) void k_root1(
    const float* __restrict__ xo, const float* __restrict__ xa,
    const float* __restrict__ rt, const float* __restrict__ b,
    unsigned short* __restrict__ yo, unsigned short* __restrict__ yaa,
    unsigned short* __restrict__ ya) {
  int lane = threadIdx.x & 63;
  int n = (blockIdx.x * blockDim.x + threadIdx.x) >> 6;
  if (n >= NN) return;
  const float4* xo4 = (const float4*)(xo + (size_t)n * FF);
  const float4* xa4 = (const float4*)(xa + (size_t)n * FF);
  float so = b[lane], sa = so;
#pragma unroll
  for (int j = 0; j < FF / 4; ++j) {
    float vo[4], va[4];
    *(float4*)vo = xo4[j];
    *(float4*)va = xa4[j];
#pragma unroll
    for (int t = 0; t < 4; ++t) {
      float wv = rt[(4 * j + t) * H1 + lane];
      so = fmaf(vo[t], wv, so);
      sa = fmaf(va[t], wv, sa);
    }
  }
  yo[(size_t)n * H1 + lane] = f2bf(so);
  yaa[(size_t)n * H1 + lane] = f2bf(so);
  ya[(size_t)n * H1 + lane] = f2bf(sa);
}

// ---- meta loader (single-level) ----
#define LM(G, SD, IV)                                       \
  {                                                         \
    const int base_ = s0 + ((G) << 4);                      \
    const int lim_ = cnt - ((G) << 4);                      \
    const int off_ = base_ + ((col < lim_) ? col : 0);      \
    SD = sdp[off_];                                         \
    IV = (col < lim_) ? invp[off_] : 0.f;                   \
  }

// ===================== layer-1 edge GEMM via MFMA, pk-bf16 scatter =================
// r14: in-register x DOUBLE-BUFFER — next group's 16-row gather issues BEFORE this
// group's MFMA+scatter (addresses ready from the meta prefetch), hiding the ~500cy
// gather latency that r13's occupancy analysis showed to be the binding wall.
// Explicit named regs (no runtime-indexed arrays -> no scratch); bounds (256,2)
// gives a 256-VGPR cap so the ~100-reg live set cannot spill.
template <int NIN>
__global__ __launch_bounds__(256, 2) void k_edge1m(
    const int2* __restrict__ sdp, const float* __restrict__ invp,
    const int* __restrict__ sm, int startOff, int histOff,
    const unsigned short* __restrict__ Wf,
    const unsigned short* __restrict__ x16A, const unsigned short* __restrict__ x16B,
    unsigned short* __restrict__ yA, unsigned short* __restrict__ yB) {
  const int r = blockIdx.x / CPB1;
  const int lane = threadIdx.x & 63;
  bhalf8 wb[16];
  {
    const bhalf8* wf = (const bhalf8*)Wf + ((size_t)r * 16) * 64 + lane;
#pragma unroll
    for (int s = 0; s < 16; ++s) wb[s] = wf[(size_t)s * 64];
  }
  const int wvid = (blockIdx.x - r * CPB1) * 4 + (threadIdx.x >> 6);
  const int stride = CPB1 * 4;
  const int s0 = sm[startOff + r];
  const int cnt = sm[histOff + r];
  const int ngroups = (cnt + 15) >> 4;
  if (wvid >= ngroups) return;
  const int cg = lane >> 4;
  const int col = lane & 15;
  const int row0 = cg << 2;

  int2 sdC, sdN; float ivC, ivN;
  LM(wvid, sdC, ivC);
  {
    const int gn = wvid + stride;
    if (gn < ngroups) { LM(gn, sdN, ivN); } else { sdN = sdC; ivN = ivC; }
  }
  bhalf8 cA0, cA1, cA2, cA3, cB0, cB1, cB2, cB3;
  {
    const bhalf8* xr = (const bhalf8*)x16A + ((size_t)sdC.x << 4);
    cA0 = xr[cg]; cA1 = xr[4 + cg]; cA2 = xr[8 + cg]; cA3 = xr[12 + cg];
    if constexpr (NIN == 2) {
      const bhalf8* xb = (const bhalf8*)x16B + ((size_t)sdC.x << 4);
      cB0 = xb[cg]; cB1 = xb[4 + cg]; cB2 = xb[8 + cg]; cB3 = xb[12 + cg];
    }
  }

  for (int G = wvid; G < ngroups; G += stride) {
    // 1) issue NEXT group's x-gather (latency hides under this group's compute)
    bhalf8 nA0, nA1, nA2, nA3, nB0, nB1, nB2, nB3;
    {
      const bhalf8* xr = (const bhalf8*)x16A + ((size_t)sdN.x << 4);
      nA0 = xr[cg]; nA1 = xr[4 + cg]; nA2 = xr[8 + cg]; nA3 = xr[12 + cg];
      if constexpr (NIN == 2) {
        const bhalf8* xb = (const bhalf8*)x16B + ((size_t)sdN.x << 4);
        nB0 = xb[cg]; nB1 = xb[4 + cg]; nB2 = xb[8 + cg]; nB3 = xb[12 + cg];
      }
    }
    // 2) prefetch meta two groups ahead
    int2 sdN2 = sdN; float ivN2 = ivN;
    {
      const int g2 = G + 2 * stride;
      if (g2 < ngroups) LM(g2, sdN2, ivN2);
    }
    // 3) compute current group
    const int dstv = sdC.y;
    const int d0 = __shfl(dstv, row0),     d1 = __shfl(dstv, row0 + 1),
              d2 = __shfl(dstv, row0 + 2), d3 = __shfl(dstv, row0 + 3);
    const float i0 = __shfl(ivC, row0),     i1 = __shfl(ivC, row0 + 1),
                i2 = __shfl(ivC, row0 + 2), i3 = __shfl(ivC, row0 + 3);

#define SCAT1(Y, CCN, NOFF)                                                     \
    {                                                                           \
      float v0 = (CCN)[0] * i0, v1 = (CCN)[1] * i1,                             \
            v2 = (CCN)[2] * i2, v3 = (CCN)[3] * i3;                             \
      float p0 = __shfl_xor(v0, 1), p1 = __shfl_xor(v1, 1),                     \
            p2 = __shfl_xor(v2, 1), p3 = __shfl_xor(v3, 1);                     \
      if (!(lane & 1)) {                                                        \
        atomPK(Y + (size_t)d0 * H1 + (NOFF) + col, (unsigned)f2bf(v0) | ((unsigned)f2bf(p0) << 16)); \
        atomPK(Y + (size_t)d1 * H1 + (NOFF) + col, (unsigned)f2bf(v1) | ((unsigned)f2bf(p1) << 16)); \
        atomPK(Y + (size_t)d2 * H1 + (NOFF) + col, (unsigned)f2bf(v2) | ((unsigned)f2bf(p2) << 16)); \
        atomPK(Y + (size_t)d3 * H1 + (NOFF) + col, (unsigned)f2bf(v3) | ((unsigned)f2bf(p3) << 16)); \
      }                                                                         \
    }

    {
      f32x4 c0 = {0.f,0.f,0.f,0.f}, c1 = c0, c2 = c0, c3 = c0;
      c0 = MFMA16(cA0, wb[0], c0);  c1 = MFMA16(cA0, wb[1], c1);
      c2 = MFMA16(cA0, wb[2], c2);  c3 = MFMA16(cA0, wb[3], c3);
      c0 = MFMA16(cA1, wb[4], c0);  c1 = MFMA16(cA1, wb[5], c1);
      c2 = MFMA16(cA1, wb[6], c2);  c3 = MFMA16(cA1, wb[7], c3);
      c0 = MFMA16(cA2, wb[8], c0);  c1 = MFMA16(cA2, wb[9], c1);
      c2 = MFMA16(cA2, wb[10], c2); c3 = MFMA16(cA2, wb[11], c3);
      c0 = MFMA16(cA3, wb[12], c0); c1 = MFMA16(cA3, wb[13], c1);
      c2 = MFMA16(cA3, wb[14], c2); c3 = MFMA16(cA3, wb[15], c3);
      SCAT1(yA, c0, 0); SCAT1(yA, c1, 16); SCAT1(yA, c2, 32); SCAT1(yA, c3, 48);
    }
    if constexpr (NIN == 2) {
      f32x4 c0 = {0.f,0.f,0.f,0.f}, c1 = c0, c2 = c0, c3 = c0;
      c0 = MFMA16(cB0, wb[0], c0);  c1 = MFMA16(cB0, wb[1], c1);
      c2 = MFMA16(cB0, wb[2], c2);  c3 = MFMA16(cB0, wb[3], c3);
      c0 = MFMA16(cB1, wb[4], c0);  c1 = MFMA16(cB1, wb[5], c1);
      c2 = MFMA16(cB1, wb[6], c2);  c3 = MFMA16(cB1, wb[7], c3);
      c0 = MFMA16(cB2, wb[8], c0);  c1 = MFMA16(cB2, wb[9], c1);
      c2 = MFMA16(cB2, wb[10], c2); c3 = MFMA16(cB2, wb[11], c3);
      c0 = MFMA16(cB3, wb[12], c0); c1 = MFMA16(cB3, wb[13], c1);
      c2 = MFMA16(cB3, wb[14], c2); c3 = MFMA16(cB3, wb[15], c3);
      SCAT1(yB, c0, 0); SCAT1(yB, c1, 16); SCAT1(yB, c2, 32); SCAT1(yB, c3, 48);
    }
#undef SCAT1
    // 4) rotate buffers
    cA0 = nA0; cA1 = nA1; cA2 = nA2; cA3 = nA3;
    if constexpr (NIN == 2) { cB0 = nB0; cB1 = nB1; cB2 = nB2; cB3 = nB3; }
    sdC = sdN; ivC = ivN; sdN = sdN2; ivN = ivN2;
  }
}

// ===================== layer-2 root term (bf16 in, bf16 out), 3 passes fused =======
__global__ __launch_bounds__(256) void k_root2x3(
    const unsigned short* __restrict__ x1o, const unsigned short* __restrict__ x1a,
    const unsigned short* __restrict__ x1aa,
    const float* __restrict__ rt, const float* __restrict__ b,
    unsigned short* __restrict__ y0, unsigned short* __restrict__ y1,
    unsigned short* __restrict__ y2) {
  int i = blockIdx.x * blockDim.x + threadIdx.x;
  if (i >= NN * H2) return;
  int o = i & (H2 - 1);
  int n = i >> 5;
  const uint2* p0 = (const uint2*)(x1o + (size_t)n * H1);
  const uint2* p1 = (const uint2*)(x1a + (size_t)n * H1);
  const uint2* p2 = (const uint2*)(x1aa + (size_t)n * H1);
  float s0 = b[o], s1 = s0, s2 = s0;
#pragma unroll
  for (int j = 0; j < 16; ++j) {
    uint2 u0 = p0[j], u1 = p1[j], u2 = p2[j];
#pragma unroll
    for (int t = 0; t < 4; ++t) {
      unsigned w0 = (t < 2) ? u0.x : u0.y;
      unsigned w1 = (t < 2) ? u1.x : u1.y;
      unsigned w2 = (t < 2) ? u2.x : u2.y;
      int sh = (t & 1) * 16;
      float wv = rt[(4 * j + t) * H2 + o];
      s0 = fmaf(bf2f((unsigned short)(w0 >> sh)), wv, s0);
      s1 = fmaf(bf2f((unsigned short)(w1 >> sh)), wv, s1);
      s2 = fmaf(bf2f((unsigned short)(w2 >> sh)), wv, s2);
    }
  }
  y0[i] = f2bf(s0); y1[i] = f2bf(s1); y2[i] = f2bf(s2);
}

// ===================== layer-2 edge GEMM via MFMA, pk-bf16 scatter + x dbuf ========
template <int NIN>
__global__ __launch_bounds__(256, 2) void k_edge2m(
    const int2* __restrict__ sdp, const float* __restrict__ invp,
    const int* __restrict__ sm, int startOff, int histOff,
    const unsigned short* __restrict__ Wf,
    const unsigned short* __restrict__ x16A, const unsigned short* __restrict__ x16B,
    unsigned short* __restrict__ yA, unsigned short* __restrict__ yB) {
  const int r = blockIdx.x / CPB2;
  const int lane = threadIdx.x & 63;
  bhalf8 wb[4];
  {
    const bhalf8* wf = (const bhalf8*)Wf + ((size_t)r * 4) * 64 + lane;
#pragma unroll
    for (int s = 0; s < 4; ++s) wb[s] = wf[(size_t)s * 64];
  }
  const int wvid = (blockIdx.x - r * CPB2) * 4 + (threadIdx.x >> 6);
  const int stride = CPB2 * 4;
  const int s0 = sm[startOff + r];
  const int cnt = sm[histOff + r];
  const int ngroups = (cnt + 15) >> 4;
  if (wvid >= ngroups) return;
  const int cg = lane >> 4;
  const int col = lane & 15;
  const int row0 = cg << 2;

  int2 sdC, sdN; float ivC, ivN;
  LM(wvid, sdC, ivC);
  {
    const int gn = wvid + stride;
    if (gn < ngroups) { LM(gn, sdN, ivN); } else { sdN = sdC; ivN = ivC; }
  }
  bhalf8 cA0, cA1, cB0, cB1;
  {
    const bhalf8* xr = (const bhalf8*)x16A + ((size_t)sdC.x << 3);
    cA0 = xr[cg]; cA1 = xr[4 + cg];
    if constexpr (NIN == 2) {
      const bhalf8* xb = (const bhalf8*)x16B + ((size_t)sdC.x << 3);
      cB0 = xb[cg]; cB1 = xb[4 + cg];
    }
  }

  for (int G = wvid; G < ngroups; G += stride) {
    bhalf8 nA0, nA1, nB0, nB1;
    {
      const bhalf8* xr = (const bhalf8*)x16A + ((size_t)sdN.x << 3);
      nA0 = xr[cg]; nA1 = xr[4 + cg];
      if constexpr (NIN == 2) {
        const bhalf8* xb = (const bhalf8*)x16B + ((size_t)sdN.x << 3);
        nB0 = xb[cg]; nB1 = xb[4 + cg];
      }
    }
    int2 sdN2 = sdN; float ivN2 = ivN;
    {
      const int g2 = G + 2 * stride;
      if (g2 < ngroups) LM(g2, sdN2, ivN2);
    }
    const int dstv = sdC.y;
    const int d0 = __shfl(dstv, row0),     d1 = __shfl(dstv, row0 + 1),
              d2 = __shfl(dstv, row0 + 2), d3 = __shfl(dstv, row0 + 3);
    const float i0 = __shfl(ivC, row0),     i1 = __shfl(ivC, row0 + 1),
                i2 = __shfl(ivC, row0 + 2), i3 = __shfl(ivC, row0 + 3);

#define SCAT2(Y, CCN, NOFF)                                                     \
    {                                                                           \
      float v0 = (CCN)[0] * i0, v1 = (CCN)[1] * i1,                             \
            v2 = (CCN)[2] * i2, v3 = (CCN)[3] * i3;                             \
      float p0 = __shfl_xor(v0, 1), p1 = __shfl_xor(v1, 1),                     \
            p2 = __shfl_xor(v2, 1), p3 = __shfl_xor(v3, 1);                     \
      if (!(lane & 1)) {                                                        \
        atomPK(Y + (size_t)d0 * H2 + (NOFF) + col, (unsigned)f2bf(v0) | ((unsigned)f2bf(p0) << 16)); \
        atomPK(Y + (size_t)d1 * H2 + (NOFF) + col, (unsigned)f2bf(v1) | ((unsigned)f2bf(p1) << 16)); \
        atomPK(Y + (size_t)d2 * H2 + (NOFF) + col, (unsigned)f2bf(v2) | ((unsigned)f2bf(p2) << 16)); \
        atomPK(Y + (size_t)d3 * H2 + (NOFF) + col, (unsigned)f2bf(v3) | ((unsigned)f2bf(p3) << 16)); \
      }                                                                         \
    }

    {
      f32x4 c0 = {0.f,0.f,0.f,0.f}, c1 = c0;
      c0 = MFMA16(cA0, wb[0], c0); c1 = MFMA16(cA0, wb[1], c1);
      c0 = MFMA16(cA1, wb[2], c0); c1 = MFMA16(cA1, wb[3], c1);
      SCAT2(yA, c0, 0); SCAT2(yA, c1, 16);
    }
    if constexpr (NIN == 2) {
      f32x4 c0 = {0.f,0.f,0.f,0.f}, c1 = c0;
      c0 = MFMA16(cB0, wb[0], c0); c1 = MFMA16(cB0, wb[1], c1);
      c0 = MFMA16(cB1, wb[2], c0); c1 = MFMA16(cB1, wb[3], c1);
      SCAT2(yB, c0, 0); SCAT2(yB, c1, 16);
    }
#undef SCAT2
    cA0 = nA0; cA1 = nA1;
    if constexpr (NIN == 2) { cB0 = nB0; cB1 = nB1; }
    sdC = sdN; ivC = ivN; sdN = sdN2; ivN = ivN2;
  }
}

// ===================== x2_o bf16 -> fp32 into d_out =====================
__global__ __launch_bounds__(256) void k_fin(const uint4* __restrict__ xb,
                                             float4* __restrict__ out, int n8) {
  int i = blockIdx.x * blockDim.x + threadIdx.x;
  if (i >= n8) return;
  uint4 u = xb[i];
  float4 a, b;
  a.x = bf2f((unsigned short)u.x); a.y = bf2f((unsigned short)(u.x >> 16));
  a.z = bf2f((unsigned short)u.y); a.w = bf2f((unsigned short)(u.y >> 16));
  b.x = bf2f((unsigned short)u.z); b.y = bf2f((unsigned short)(u.z >> 16));
  b.z = bf2f((unsigned short)u.w); b.w = bf2f((unsigned short)(u.w >> 16));
  out[2 * i] = a; out[2 * i + 1] = b;
}

// ===================== column sum of x2_o (fp32) -> hacc[32] =====================
__global__ __launch_bounds__(256) void k_colsum(const float* __restrict__ x2o,
                                                float* __restrict__ hacc) {
  int tid = threadIdx.x;
  int col = tid & 31;
  int rgrp = blockIdx.x * (blockDim.x >> 5) + (tid >> 5);
  int nth = gridDim.x * (blockDim.x >> 5);
  float s = 0.f;
  for (int n = rgrp; n < NN; n += nth) s += x2o[(size_t)n * H2 + col];
  unsafeAtomicAdd(&hacc[col], s);
}

// ===================== h_os = sigmoid(mean); v = disc_w @ h_os =====================
__global__ __launch_bounds__(64) void k_disc(const float* __restrict__ hacc,
                                             const float* __restrict__ dw,
                                             float* __restrict__ vout) {
  __shared__ float hos[H2];
  int t = threadIdx.x;
  if (t < H2) hos[t] = 1.0f / (1.0f + expf(-hacc[t] / (float)NN));
  __syncthreads();
  if (t < H2) {
    float s = 0.f;
#pragma unroll
    for (int k = 0; k < H2; ++k) s = fmaf(dw[t * H2 + k], hos[k], s);
    vout[t] = s;
  }
}

// ===================== ret_os / ret_os_a (bf16 x2 inputs) =====================
__global__ __launch_bounds__(256) void k_ret(
    const unsigned short* __restrict__ x2o, const unsigned short* __restrict__ x2oa,
    const unsigned short* __restrict__ x2oaa,
    const float* __restrict__ v, const float* __restrict__ db,
    float* __restrict__ ros, float* __restrict__ rosa) {
  int n = blockIdx.x * blockDim.x + threadIdx.x;
  if (n >= NN) return;
  const uint2* a2 = (const uint2*)(x2o + (size_t)n * H2);
  const uint2* b2 = (const uint2*)(x2oa + (size_t)n * H2);
  const uint2* c2 = (const uint2*)(x2oaa + (size_t)n * H2);
  const float4* v4 = (const float4*)v;
  float r0 = 0.f, r1 = 0.f, r2 = 0.f;
#pragma unroll
  for (int j = 0; j < 8; ++j) {
    uint2 ua = a2[j], ub = b2[j], uc = c2[j];
    float4 vv = v4[j];
    r0 += bf2f((unsigned short)ua.x) * vv.x + bf2f((unsigned short)(ua.x >> 16)) * vv.y
        + bf2f((unsigned short)ua.y) * vv.z + bf2f((unsigned short)(ua.y >> 16)) * vv.w;
    r1 += bf2f((unsigned short)ub.x) * vv.x + bf2f((unsigned short)(ub.x >> 16)) * vv.y
        + bf2f((unsigned short)ub.y) * vv.z + bf2f((unsigned short)(ub.y >> 16)) * vv.w;
    r2 += bf2f((unsigned short)uc.x) * vv.x + bf2f((unsigned short)(uc.x >> 16)) * vv.y
        + bf2f((unsigned short)uc.y) * vv.z + bf2f((unsigned short)(uc.y >> 16)) * vv.w;
  }
  float bb = db[0];
  ros[n * 2] = r0 + bb;  ros[n * 2 + 1] = r1 + bb;
  rosa[n * 2] = r0 + bb; rosa[n * 2 + 1] = r2 + bb;
}

// ===================== classifier (x1o bf16, x2o fp32) =====================
__global__ __launch_bounds__(128) void k_cls(
    const int* __restrict__ idx, const unsigned short* __restrict__ x1o,
    const float* __restrict__ x2o,
    const float* __restrict__ attt, const float* __restrict__ cw, const float* __restrict__ cb,
    float* __restrict__ lg) {
  int b = blockIdx.x;
  int r = threadIdx.x;
  if (r >= RR) return;
  int i1 = idx[b], i2 = idx[BQ + b];
  float a0 = attt[0], a1 = attt[1];
  float acc = cb[r];
  const uint2* q1 = (const uint2*)(x1o + (size_t)i1 * H1);
  const float4* q2 = (const float4*)(x2o + (size_t)i1 * H2);
  const uint2* q3 = (const uint2*)(x1o + (size_t)i2 * H1);
  const float4* q4 = (const float4*)(x2o + (size_t)i2 * H2);
#pragma unroll
  for (int j = 0; j < 16; ++j) {
    uint2 u = q1[j];
    float v0 = bf2f((unsigned short)u.x), v1 = bf2f((unsigned short)(u.x >> 16));
    float v2 = bf2f((unsigned short)u.y), v3 = bf2f((unsigned short)(u.y >> 16));
    acc = fmaf(a0 * v0, cw[(4 * j) * RR + r], acc);
    acc = fmaf(a0 * v1, cw[(4 * j + 1) * RR + r], acc);
    acc = fmaf(a0 * v2, cw[(4 * j + 2) * RR + r], acc);
    acc = fmaf(a0 * v3, cw[(4 * j + 3) * RR + r], acc);
  }
#pragma unroll
  for (int j = 0; j < H2 / 4; ++j) {
    float v[4]; *(float4*)v = q2[j];
#pragma unroll
    for (int t = 0; t < 4; ++t) acc = fmaf(a1 * v[t], cw[(H1 + 4 * j + t) * RR + r], acc);
  }
#pragma unroll
  for (int j = 0; j < 16; ++j) {
    uint2 u = q3[j];
    float v0 = bf2f((unsigned short)u.x), v1 = bf2f((unsigned short)(u.x >> 16));
    float v2 = bf2f((unsigned short)u.y), v3 = bf2f((unsigned short)(u.y >> 16));
    acc = fmaf(a0 * v0, cw[(96 + 4 * j) * RR + r], acc);
    acc = fmaf(a0 * v1, cw[(96 + 4 * j + 1) * RR + r], acc);
    acc = fmaf(a0 * v2, cw[(96 + 4 * j + 2) * RR + r], acc);
    acc = fmaf(a0 * v3, cw[(96 + 4 * j + 3) * RR + r], acc);
  }
#pragma unroll
  for (int j = 0; j < H2 / 4; ++j) {
    float v[4]; *(float4*)v = q4[j];
#pragma unroll
    for (int t = 0; t < 4; ++t) acc = fmaf(a1 * v[t], cw[(96 + H1 + 4 * j + t) * RR + r], acc);
  }
  lg[(size_t)b * RR + r] = acc;
}

// ===================== launch =====================
extern "C" void kernel_launch(void* const* d_in, const int* in_sizes, int n_in,
                              void* d_out, int out_size, void* d_ws, size_t ws_size,
                              hipStream_t stream) {
  const float* x_o  = (const float*)d_in[0];
  const float* x_a  = (const float*)d_in[1];
  const int*   ei   = (const int*)d_in[2];
  const int*   etA  = (const int*)d_in[3];
  const int*   etB  = (const int*)d_in[4];
  const int*   idx  = (const int*)d_in[5];
  const float* W1   = (const float*)d_in[6];
  const float* rt1  = (const float*)d_in[7];
  const float* b1   = (const float*)d_in[8];
  const float* W2   = (const float*)d_in[9];
  const float* rt2  = (const float*)d_in[10];
  const float* b2   = (const float*)d_in[11];
  const float* attt = (const float*)d_in[12];
  const float* dw   = (const float*)d_in[13];
  const float* db   = (const float*)d_in[14];
  const float* cw   = (const float*)d_in[15];
  const float* cb   = (const float*)d_in[16];

  const size_t NRp = 1300224;
  int* wsI  = (int*)d_ws;
  int* cntA = wsI;                              // NRp ints
  int* cntB = wsI + NRp;                        // NRp ints
  int* sm   = wsI + 2 * NRp;                    // 1024
  int* ordA = sm + 1024;                        // NE
  int* ordB = ordA + NE;                        // NE
  int2*  sdA = (int2*)(ordB + NE);              // NE int2
  float* ivA = (float*)(sdA + NE);              // NE
  int2*  sdB = (int2*)(ivA + NE);               // NE int2
  float* ivB = (float*)(sdB + NE);              // NE
  // bf16 region
  unsigned short* x1o16  = (unsigned short*)(ivB + NE);      // NN*H1
  unsigned short* x1a16  = x1o16 + (size_t)NN * H1;
  unsigned short* x1aa16 = x1a16 + (size_t)NN * H1;
  unsigned short* x2ob   = x1aa16 + (size_t)NN * H1;         // NN*H2
  unsigned short* x2oab  = x2ob + (size_t)NN * H2;
  unsigned short* x2oaab = x2oab + (size_t)NN * H2;
  unsigned short* xo16   = x2oaab + (size_t)NN * H2;         // NN*FF
  unsigned short* xa16   = xo16 + (size_t)NN * FF;
  unsigned short* W1f    = xa16 + (size_t)NN * FF;           // RR*16*64*8
  unsigned short* W2f    = W1f + (size_t)RR * 16 * 64 * 8;   // RR*4*64*8
  float* smF   = (float*)sm;
  float* hacc  = smF + SM_HACC;
  float* vbuf  = smF + SM_V;

  float* outF   = (float*)d_out;
  float* o_log  = outF;
  float* o_ros  = outF + (size_t)BQ * RR;
  float* o_rosa = o_ros + (size_t)NN * 2;
  float* o_x2o  = o_rosa + (size_t)NN * 2;

  hipMemsetAsync(wsI, 0, (2 * NRp + 1024) * sizeof(int), stream);

  // prep: bf16 conversions + W fragment packing
  k_cvt2<<<(2 * NN * FF / 8 + 255) / 256, 256, 0, stream>>>(
      (const float4*)x_o, (const float4*)x_a, (uint4*)xo16, (uint4*)xa16, NN * FF / 8);
  k_wprep1<<<RR, 256, 0, stream>>>(W1, W1f);
  k_wprep2<<<RR, 256, 0, stream>>>(W2, W2f);

  k_hist<<<(NE + 255) / 256, 256, 0, stream>>>(ei, etA, etB, cntA, cntB, sm);
  k_prefix<<<1, 128, 0, stream>>>(sm);
  k_scatter<<<(NE + 255) / 256, 256, 0, stream>>>(etA, etB, sm, ordA, ordB);
  k_emeta<<<(NE + 255) / 256, 256, 0, stream>>>(ei, ordA, ordB, cntA, cntB,
                                                etA, etB, sdA, ivA, sdB, ivB);

  k_root1<<<(NN * H1) / 256, 256, 0, stream>>>(x_o, x_a, rt1, b1, x1o16, x1aa16, x1a16);
  k_edge1m<2><<<RR * CPB1, 256, 0, stream>>>(sdA, ivA, sm, SM_START_A, SM_HIST_A,
                                             W1f, xo16, xa16, x1o16, x1a16);
  k_edge1m<1><<<RR * CPB1, 256, 0, stream>>>(sdB, ivB, sm, SM_START_B, SM_HIST_B,
                                             W1f, xo16, nullptr, x1aa16, nullptr);
  k_relu16<<<(3 * NN * H1 / 8 + 255) / 256, 256, 0, stream>>>((uint4*)x1o16, 3 * NN * H1 / 8);

  k_root2x3<<<(NN * H2 + 255) / 256, 256, 0, stream>>>(x1o16, x1a16, x1aa16, rt2, b2,
                                                       x2ob, x2oab, x2oaab);
  k_edge2m<2><<<RR * CPB2, 256, 0, stream>>>(sdA, ivA, sm, SM_START_A, SM_HIST_A,
                                             W2f, x1o16, x1a16, x2ob, x2oab);
  k_edge2m<1><<<RR * CPB2, 256, 0, stream>>>(sdB, ivB, sm, SM_START_B, SM_HIST_B,
                                             W2f, x1aa16, nullptr, x2oaab, nullptr);

  k_fin<<<(NN * H2 / 8 + 255) / 256, 256, 0, stream>>>((const uint4*)x2ob,
                                                       (float4*)o_x2o, NN * H2 / 8);
  k_colsum<<<128, 256, 0, stream>>>(o_x2o, hacc);
  k_disc<<<1, 64, 0, stream>>>(hacc, dw, vbuf);
  k_ret<<<(NN + 255) / 256, 256, 0, stream>>>(x2ob, x2oab, x2oaab, vbuf, db, o_ros, o_rosa);
  k_cls<<<BQ, 128, 0, stream>>>(idx, x1o16, o_x2o, attt, cw, cb, o_log);
}

// Round 15
// 866.946 us; speedup vs baseline: 2.7201x; 1.1624x over previous
//
#include <hip/hip_runtime.h>

// ---- problem dims ----
#define NN 20000
#define NE 640000
#define FF 128
#define H1 64
#define H2 32
#define RR 65
#define BQ 4096
#define NR (NN*RR)
#define NDPAD 20480

// ---- small scratch block offsets (ints within sm[1024]) ----
#define SM_HIST_A 0
#define SM_START_A 128
#define SM_CUR_A 256
#define SM_HIST_B 384
#define SM_START_B 512
#define SM_CUR_B 640
#define SM_HACC 768   // 32 floats
#define SM_V 832      // 32 floats

#define CPB1 32
#define CPB2 32

typedef __attribute__((ext_vector_type(8))) short bhalf8;   // 8 bf16 (4 VGPRs)
typedef __attribute__((ext_vector_type(4))) float f32x4;
#define MFMA16(a, b, c) __builtin_amdgcn_mfma_f32_16x16x32_bf16(a, b, c, 0, 0, 0)

__device__ __forceinline__ unsigned short f2bf(float f) {
  unsigned int u = __float_as_uint(f);
  unsigned int r = (u + 0x7fffu + ((u >> 16) & 1u)) >> 16;   // RNE
  return (unsigned short)r;
}
__device__ __forceinline__ float bf2f(unsigned short u) {
  return __uint_as_float((unsigned)u << 16);
}
__device__ __forceinline__ void atomPK(unsigned short* p, unsigned v) {
  asm volatile("global_atomic_pk_add_bf16 %0, %1, off"
               :: "v"((unsigned long long)p), "v"(v) : "memory");
}

// ===================== histogram (+ per-dst counts for reduce tiers) ==============
__global__ __launch_bounds__(256) void k_hist(
    const int* __restrict__ ei, const int* __restrict__ etA, const int* __restrict__ etB,
    int* __restrict__ cntA, int* __restrict__ cntB, int* __restrict__ sm,
    int* __restrict__ cntD) {
  __shared__ int lh[2 * RR];
  int tid = threadIdx.x;
  for (int i = tid; i < 2 * RR; i += blockDim.x) lh[i] = 0;
  __syncthreads();
  int e = blockIdx.x * blockDim.x + tid;
  if (e < NE) {
    int dst = ei[NE + e];
    int ta = etA[e], tb = etB[e];
    atomicAdd(&cntA[dst * RR + ta], 1);
    atomicAdd(&cntB[dst * RR + tb], 1);
    atomicAdd(&cntD[dst], 1);
    atomicAdd(&lh[ta], 1);
    atomicAdd(&lh[RR + tb], 1);
  }
  __syncthreads();
  for (int i = tid; i < 2 * RR; i += blockDim.x) {
    int c = lh[i];
    if (c) atomicAdd(&sm[(i < RR) ? (SM_HIST_A + i) : (SM_HIST_B + (i - RR))], c);
  }
}

// ===================== exclusive prefix over 65 bins =====================
__global__ __launch_bounds__(128) void k_prefix(int* __restrict__ sm) {
  int w = threadIdx.x >> 6;
  if ((threadIdx.x & 63) == 0 && w < 2) {
    int hb = w ? SM_HIST_B : SM_HIST_A;
    int sb = w ? SM_START_B : SM_START_A;
    int cb = w ? SM_CUR_B : SM_CUR_A;
    int h[RR];
#pragma unroll
    for (int r = 0; r < RR; ++r) h[r] = sm[hb + r];
    int s = 0;
#pragma unroll
    for (int r = 0; r < RR; ++r) { sm[sb + r] = s; sm[cb + r] = s; s += h[r]; }
  }
}

// ===================== exclusive prefix over 20000 dst bins (1 block) ==============
__global__ __launch_bounds__(256) void k_prefixD(
    const int* __restrict__ cntD, int* __restrict__ startD,
    int* __restrict__ curA, int* __restrict__ curB) {
  __shared__ int psum[256];
  __shared__ int pbase[257];
  int t = threadIdx.x;
  int c0 = t * 80;
  int c1 = (c0 + 80 < NN) ? (c0 + 80) : NN;
  int s = 0;
  for (int i = c0; i < c1; ++i) s += cntD[i];
  psum[t] = s;
  __syncthreads();
  if (t == 0) {
    int a = 0;
    for (int i = 0; i < 256; ++i) { pbase[i] = a; a += psum[i]; }
    pbase[256] = a;
  }
  __syncthreads();
  int run = pbase[t];
  for (int i = c0; i < c1; ++i) {
    startD[i] = run; curA[i] = run; curB[i] = run;
    run += cntD[i];
  }
  if (t == 255) startD[NN] = pbase[256];
}

// ===================== counting-sort scatter =====================
__global__ __launch_bounds__(256) void k_scatter(
    const int* __restrict__ etA, const int* __restrict__ etB,
    int* __restrict__ sm, int* __restrict__ ordA, int* __restrict__ ordB) {
  __shared__ int lhA[RR], lbA[RR], lhB[RR], lbB[RR];
  int tid = threadIdx.x;
  for (int i = tid; i < RR; i += blockDim.x) { lhA[i] = 0; lhB[i] = 0; }
  __syncthreads();
  int e = blockIdx.x * blockDim.x + tid;
  int ta = 0, tb = 0, ra = 0, rb = 0;
  bool valid = (e < NE);
  if (valid) {
    ta = etA[e]; tb = etB[e];
    ra = atomicAdd(&lhA[ta], 1);
    rb = atomicAdd(&lhB[tb], 1);
  }
  __syncthreads();
  for (int i = tid; i < RR; i += blockDim.x) {
    if (lhA[i]) lbA[i] = atomicAdd(&sm[SM_CUR_A + i], lhA[i]);
    if (lhB[i]) lbB[i] = atomicAdd(&sm[SM_CUR_B + i], lhB[i]);
  }
  __syncthreads();
  if (valid) { ordA[lbA[ta] + ra] = e; ordB[lbB[tb] + rb] = e; }
}

// ===================== flatten per-position edge meta =====================
__global__ __launch_bounds__(256) void k_emeta(
    const int* __restrict__ ei, const int* __restrict__ ordA, const int* __restrict__ ordB,
    const int* __restrict__ cntA, const int* __restrict__ cntB,
    const int* __restrict__ etA, const int* __restrict__ etB,
    int2* __restrict__ sdA, float* __restrict__ ivA,
    int2* __restrict__ sdB, float* __restrict__ ivB) {
  int p = blockIdx.x * blockDim.x + threadIdx.x;
  if (p >= NE) return;
  {
    int e = ordA[p]; int s = ei[e], d = ei[NE + e]; int t = etA[e];
    sdA[p] = make_int2(s, d);
    ivA[p] = 1.0f / (float)cntA[(size_t)d * RR + t];
  }
  {
    int e = ordB[p]; int s = ei[e], d = ei[NE + e]; int t = etB[e];
    sdB[p] = make_int2(s, d);
    ivB[p] = 1.0f / (float)cntB[(size_t)d * RR + t];
  }
}

// ===================== dst-major position lists =====================
__global__ __launch_bounds__(256) void k_scatterD(
    const int2* __restrict__ sdA, const int2* __restrict__ sdB,
    int* __restrict__ curA, int* __restrict__ curB,
    int* __restrict__ posA, int* __restrict__ posB) {
  int p = blockIdx.x * blockDim.x + threadIdx.x;
  if (p >= NE) return;
  posA[atomicAdd(&curA[sdA[p].y], 1)] = p;
  posB[atomicAdd(&curB[sdB[p].y], 1)] = p;
}

// ===================== fp32 -> bf16 conversion for x_o and x_a =====================
__global__ __launch_bounds__(256) void k_cvt2(const float4* __restrict__ inA,
                                              const float4* __restrict__ inB,
                                              uint4* __restrict__ outA,
                                              uint4* __restrict__ outB, int n8) {
  int i = blockIdx.x * blockDim.x + threadIdx.x;
  if (i >= 2 * n8) return;
  const float4* in = (i < n8) ? inA : inB;
  uint4* out = (i < n8) ? outA : outB;
  int j = (i < n8) ? i : i - n8;
  float4 a = in[2 * j], b = in[2 * j + 1];
  uint4 o;
  o.x = (unsigned)f2bf(a.x) | ((unsigned)f2bf(a.y) << 16);
  o.y = (unsigned)f2bf(a.z) | ((unsigned)f2bf(a.w) << 16);
  o.z = (unsigned)f2bf(b.x) | ((unsigned)f2bf(b.y) << 16);
  o.w = (unsigned)f2bf(b.z) | ((unsigned)f2bf(b.w) << 16);
  out[j] = o;
}

// ===================== in-place bf16 relu (atomic tier only) =====================
__global__ __launch_bounds__(256) void k_relu16(uint4* __restrict__ a, int n4) {
  int i = blockIdx.x * blockDim.x + threadIdx.x;
  if (i >= n4) return;
  uint4 u = a[i];
  unsigned* w = (unsigned*)&u;
#pragma unroll
  for (int t = 0; t < 4; ++t) {
    unsigned lo = (w[t] & 0x8000u) ? 0u : (w[t] & 0xFFFFu);
    unsigned hi = (w[t] & 0x80000000u) ? 0u : (w[t] & 0xFFFF0000u);
    w[t] = lo | hi;
  }
  a[i] = u;
}

// ===================== W1 -> bf16 B-fragments =====================
__global__ __launch_bounds__(256) void k_wprep1(const float* __restrict__ W,
                                                unsigned short* __restrict__ Wf) {
  int r = blockIdx.x;
  int lane = threadIdx.x & 63, w = threadIdx.x >> 6;
#pragma unroll
  for (int s4 = 0; s4 < 4; ++s4) {
    int slot = w * 4 + s4;
    int ks = slot >> 2, n = slot & 3;
    int krow = ks * 32 + ((lane >> 4) << 3);
    int colo = n * 16 + (lane & 15);
    unsigned short* o = Wf + (((size_t)r * 16 + slot) * 64 + lane) * 8;
#pragma unroll
    for (int j = 0; j < 8; ++j)
      o[j] = f2bf(W[((size_t)r * FF + krow + j) * H1 + colo]);
  }
}

// ===================== W2 -> bf16 B-fragments =====================
__global__ __launch_bounds__(256) void k_wprep2(const float* __restrict__ W,
                                                unsigned short* __restrict__ Wf) {
  int r = blockIdx.x;
  int lane = threadIdx.x & 63, slot = threadIdx.x >> 6;
  int ks = slot >> 1, n = slot & 1;
  int krow = ks * 32 + ((lane >> 4) << 3);
  int colo = n * 16 + (lane & 15);
  unsigned short* o = Wf + (((size_t)r * 4 + slot) * 64 + lane) * 8;
#pragma unroll
  for (int j = 0; j < 8; ++j)
    o[j] = f2bf(W[((size_t)r * H1 + krow + j) * H2 + colo]);
}

// ===================== layer-1 root term -> bf16 =====================
__global__ __launch_bounds__(256) void k_root1(
    const float* __restrict__ xo, const float* __restrict__ xa,
    const float* __restrict__ rt, const float* __restrict__ b,
    unsigned short* __restrict__ yo, unsigned short* __restrict__ yaa,
    unsigned short* __restrict__ ya) {
  int lane = threadIdx.x & 63;
  int n = (blockIdx.x * blockDim.x + threadIdx.x) >> 6;
  if (n >= NN) return;
  const float4* xo4 = (const float4*)(xo + (size_t)n * FF);
  const float4* xa4 = (const float4*)(xa + (size_t)n * FF);
  float so = b[lane], sa = so;
#pragma unroll
  for (int j = 0; j < FF / 4; ++j) {
    float vo[4], va[4];
    *(float4*)vo = xo4[j];
    *(float4*)va = xa4[j];
#pragma unroll
    for (int t = 0; t < 4; ++t) {
      float wv = rt[(4 * j + t) * H1 + lane];
      so = fmaf(vo[t], wv, so);
      sa = fmaf(va[t], wv, sa);
    }
  }
  yo[(size_t)n * H1 + lane] = f2bf(so);
  yaa[(size_t)n * H1 + lane] = f2bf(so);
  ya[(size_t)n * H1 + lane] = f2bf(sa);
}

// ---- meta loader ----
#define LM(G, SD, IV)                                       \
  {                                                         \
    const int base_ = s0 + ((G) << 4);                      \
    const int lim_ = cnt - ((G) << 4);                      \
    const int off_ = base_ + ((col < lim_) ? col : 0);      \
    SD = sdp[off_];                                         \
    IV = (col < lim_) ? invp[off_] : 0.f;                   \
  }

// ===================== MFMA bodies (shared) =====================
#define MFMA_BODY1(A0, A1, A2, A3)                                  \
  f32x4 c0 = {0.f,0.f,0.f,0.f}, c1 = c0, c2 = c0, c3 = c0;          \
  c0 = MFMA16(A0, wb[0], c0);  c1 = MFMA16(A0, wb[1], c1);          \
  c2 = MFMA16(A0, wb[2], c2);  c3 = MFMA16(A0, wb[3], c3);          \
  c0 = MFMA16(A1, wb[4], c0);  c1 = MFMA16(A1, wb[5], c1);          \
  c2 = MFMA16(A1, wb[6], c2);  c3 = MFMA16(A1, wb[7], c3);          \
  c0 = MFMA16(A2, wb[8], c0);  c1 = MFMA16(A2, wb[9], c1);          \
  c2 = MFMA16(A2, wb[10], c2); c3 = MFMA16(A2, wb[11], c3);         \
  c0 = MFMA16(A3, wb[12], c0); c1 = MFMA16(A3, wb[13], c1);         \
  c2 = MFMA16(A3, wb[14], c2); c3 = MFMA16(A3, wb[15], c3);

// ===================== layer-1 edge GEMM, ATOMIC scatter (fallback tier) ===========
template <int NIN>
__global__ __launch_bounds__(256, 2) void k_edge1m(
    const int2* __restrict__ sdp, const float* __restrict__ invp,
    const int* __restrict__ sm, int startOff, int histOff,
    const unsigned short* __restrict__ Wf,
    const unsigned short* __restrict__ x16A, const unsigned short* __restrict__ x16B,
    unsigned short* __restrict__ yA, unsigned short* __restrict__ yB) {
  const int r = blockIdx.x / CPB1;
  const int lane = threadIdx.x & 63;
  bhalf8 wb[16];
  {
    const bhalf8* wf = (const bhalf8*)Wf + ((size_t)r * 16) * 64 + lane;
#pragma unroll
    for (int s = 0; s < 16; ++s) wb[s] = wf[(size_t)s * 64];
  }
  const int wvid = (blockIdx.x - r * CPB1) * 4 + (threadIdx.x >> 6);
  const int stride = CPB1 * 4;
  const int s0 = sm[startOff + r];
  const int cnt = sm[histOff + r];
  const int ngroups = (cnt + 15) >> 4;
  if (wvid >= ngroups) return;
  const int cg = lane >> 4;
  const int col = lane & 15;
  const int row0 = cg << 2;

  int2 sdC; float ivC;
  LM(wvid, sdC, ivC);
  for (int G = wvid; G < ngroups; G += stride) {
    int2 sdN = sdC; float ivN = ivC;
    if (G + stride < ngroups) LM(G + stride, sdN, ivN);
    const int src = sdC.x;
    const int dstv = sdC.y;
    const int d0 = __shfl(dstv, row0),     d1 = __shfl(dstv, row0 + 1),
              d2 = __shfl(dstv, row0 + 2), d3 = __shfl(dstv, row0 + 3);
    const float i0 = __shfl(ivC, row0),     i1 = __shfl(ivC, row0 + 1),
                i2 = __shfl(ivC, row0 + 2), i3 = __shfl(ivC, row0 + 3);
#define SCAT1(Y, CCN, NOFF)                                                     \
    {                                                                           \
      float v0 = (CCN)[0] * i0, v1 = (CCN)[1] * i1,                             \
            v2 = (CCN)[2] * i2, v3 = (CCN)[3] * i3;                             \
      float p0 = __shfl_xor(v0, 1), p1 = __shfl_xor(v1, 1),                     \
            p2 = __shfl_xor(v2, 1), p3 = __shfl_xor(v3, 1);                     \
      if (!(lane & 1)) {                                                        \
        atomPK(Y + (size_t)d0 * H1 + (NOFF) + col, (unsigned)f2bf(v0) | ((unsigned)f2bf(p0) << 16)); \
        atomPK(Y + (size_t)d1 * H1 + (NOFF) + col, (unsigned)f2bf(v1) | ((unsigned)f2bf(p1) << 16)); \
        atomPK(Y + (size_t)d2 * H1 + (NOFF) + col, (unsigned)f2bf(v2) | ((unsigned)f2bf(p2) << 16)); \
        atomPK(Y + (size_t)d3 * H1 + (NOFF) + col, (unsigned)f2bf(v3) | ((unsigned)f2bf(p3) << 16)); \
      }                                                                         \
    }
    {
      const bhalf8* xr = (const bhalf8*)x16A + ((size_t)src << 4);
      bhalf8 a0 = xr[cg], a1 = xr[4 + cg], a2 = xr[8 + cg], a3 = xr[12 + cg];
      MFMA_BODY1(a0, a1, a2, a3)
      SCAT1(yA, c0, 0); SCAT1(yA, c1, 16); SCAT1(yA, c2, 32); SCAT1(yA, c3, 48);
    }
    if constexpr (NIN == 2) {
      const bhalf8* xr = (const bhalf8*)x16B + ((size_t)src << 4);
      bhalf8 a0 = xr[cg], a1 = xr[4 + cg], a2 = xr[8 + cg], a3 = xr[12 + cg];
      MFMA_BODY1(a0, a1, a2, a3)
      SCAT1(yB, c0, 0); SCAT1(yB, c1, 16); SCAT1(yB, c2, 32); SCAT1(yB, c3, 48);
    }
#undef SCAT1
    sdC = sdN; ivC = ivN;
  }
}

// ===================== layer-1 edge GEMM, per-edge row STORES (reduce tier) ========
template <int NIN>
__global__ __launch_bounds__(256, 2) void k_edge1s(
    const int2* __restrict__ sdp, const float* __restrict__ invp,
    const int* __restrict__ sm, int startOff, int histOff,
    const unsigned short* __restrict__ Wf,
    const unsigned short* __restrict__ x16A, const unsigned short* __restrict__ x16B,
    unsigned short* __restrict__ tA, unsigned short* __restrict__ tB) {
  const int r = blockIdx.x / CPB1;
  const int lane = threadIdx.x & 63;
  bhalf8 wb[16];
  {
    const bhalf8* wf = (const bhalf8*)Wf + ((size_t)r * 16) * 64 + lane;
#pragma unroll
    for (int s = 0; s < 16; ++s) wb[s] = wf[(size_t)s * 64];
  }
  const int wvid = (blockIdx.x - r * CPB1) * 4 + (threadIdx.x >> 6);
  const int stride = CPB1 * 4;
  const int s0 = sm[startOff + r];
  const int cnt = sm[histOff + r];
  const int ngroups = (cnt + 15) >> 4;
  if (wvid >= ngroups) return;
  const int cg = lane >> 4;
  const int col = lane & 15;
  const int row0 = cg << 2;

  int2 sdC; float ivC;
  LM(wvid, sdC, ivC);
  for (int G = wvid; G < ngroups; G += stride) {
    int2 sdN = sdC; float ivN = ivC;
    if (G + stride < ngroups) LM(G + stride, sdN, ivN);
    const int src = sdC.x;
    const int base = s0 + (G << 4);
    const int lim = cnt - (G << 4);
    const float i0 = __shfl(ivC, row0),     i1 = __shfl(ivC, row0 + 1),
                i2 = __shfl(ivC, row0 + 2), i3 = __shfl(ivC, row0 + 3);
#define STOR1(T, CCN, NOFF)                                                     \
    {                                                                           \
      float v0 = (CCN)[0] * i0, v1 = (CCN)[1] * i1,                             \
            v2 = (CCN)[2] * i2, v3 = (CCN)[3] * i3;                             \
      float p0 = __shfl_xor(v0, 1), p1 = __shfl_xor(v1, 1),                     \
            p2 = __shfl_xor(v2, 1), p3 = __shfl_xor(v3, 1);                     \
      if (!(lane & 1)) {                                                        \
        if (row0 + 0 < lim) *(unsigned*)(T + (size_t)(base + row0 + 0) * H1 + (NOFF) + col) = (unsigned)f2bf(v0) | ((unsigned)f2bf(p0) << 16); \
        if (row0 + 1 < lim) *(unsigned*)(T + (size_t)(base + row0 + 1) * H1 + (NOFF) + col) = (unsigned)f2bf(v1) | ((unsigned)f2bf(p1) << 16); \
        if (row0 + 2 < lim) *(unsigned*)(T + (size_t)(base + row0 + 2) * H1 + (NOFF) + col) = (unsigned)f2bf(v2) | ((unsigned)f2bf(p2) << 16); \
        if (row0 + 3 < lim) *(unsigned*)(T + (size_t)(base + row0 + 3) * H1 + (NOFF) + col) = (unsigned)f2bf(v3) | ((unsigned)f2bf(p3) << 16); \
      }                                                                         \
    }
    {
      const bhalf8* xr = (const bhalf8*)x16A + ((size_t)src << 4);
      bhalf8 a0 = xr[cg], a1 = xr[4 + cg], a2 = xr[8 + cg], a3 = xr[12 + cg];
      MFMA_BODY1(a0, a1, a2, a3)
      STOR1(tA, c0, 0); STOR1(tA, c1, 16); STOR1(tA, c2, 32); STOR1(tA, c3, 48);
    }
    if constexpr (NIN == 2) {
      const bhalf8* xr = (const bhalf8*)x16B + ((size_t)src << 4);
      bhalf8 a0 = xr[cg], a1 = xr[4 + cg], a2 = xr[8 + cg], a3 = xr[12 + cg];
      MFMA_BODY1(a0, a1, a2, a3)
      STOR1(tB, c0, 0); STOR1(tB, c1, 16); STOR1(tB, c2, 32); STOR1(tB, c3, 48);
    }
#undef STOR1
    sdC = sdN; ivC = ivN;
  }
}

// ===================== layer-1 segmented reduce + root + relu =====================
template <int NT>
__global__ __launch_bounds__(256) void k_reduce1(
    const int* __restrict__ startD, const int* __restrict__ pos,
    const unsigned short* __restrict__ t0, const unsigned short* __restrict__ t1,
    const unsigned short* __restrict__ r0, const unsigned short* __restrict__ r1,
    unsigned short* __restrict__ y0, unsigned short* __restrict__ y1) {
  int lane = threadIdx.x & 63;
  int d = (blockIdx.x * blockDim.x + threadIdx.x) >> 6;
  if (d >= NN) return;
  int e0 = startD[d], e1 = startD[d + 1];
  float a0 = 0.f, a1 = 0.f;
  int j = e0;
  for (; j + 4 <= e1; j += 4) {
    int p0 = pos[j], p1 = pos[j + 1], p2 = pos[j + 2], p3 = pos[j + 3];
    a0 += bf2f(t0[(size_t)p0 * H1 + lane]) + bf2f(t0[(size_t)p1 * H1 + lane])
        + bf2f(t0[(size_t)p2 * H1 + lane]) + bf2f(t0[(size_t)p3 * H1 + lane]);
    if constexpr (NT == 2)
      a1 += bf2f(t1[(size_t)p0 * H1 + lane]) + bf2f(t1[(size_t)p1 * H1 + lane])
          + bf2f(t1[(size_t)p2 * H1 + lane]) + bf2f(t1[(size_t)p3 * H1 + lane]);
  }
  for (; j < e1; ++j) {
    int p = pos[j];
    a0 += bf2f(t0[(size_t)p * H1 + lane]);
    if constexpr (NT == 2) a1 += bf2f(t1[(size_t)p * H1 + lane]);
  }
  size_t o = (size_t)d * H1 + lane;
  y0[o] = f2bf(fmaxf(bf2f(r0[o]) + a0, 0.f));
  if constexpr (NT == 2) y1[o] = f2bf(fmaxf(bf2f(r1[o]) + a1, 0.f));
}

// ===================== layer-2 root term, 3 fused (bf16 out) =====================
__global__ __launch_bounds__(256) void k_root2x3(
    const unsigned short* __restrict__ x1o, const unsigned short* __restrict__ x1a,
    const unsigned short* __restrict__ x1aa,
    const float* __restrict__ rt, const float* __restrict__ b,
    unsigned short* __restrict__ y0, unsigned short* __restrict__ y1,
    unsigned short* __restrict__ y2) {
  int i = blockIdx.x * blockDim.x + threadIdx.x;
  if (i >= NN * H2) return;
  int o = i & (H2 - 1);
  int n = i >> 5;
  const uint2* p0 = (const uint2*)(x1o + (size_t)n * H1);
  const uint2* p1 = (const uint2*)(x1a + (size_t)n * H1);
  const uint2* p2 = (const uint2*)(x1aa + (size_t)n * H1);
  float s0 = b[o], s1 = s0, s2 = s0;
#pragma unroll
  for (int j = 0; j < 16; ++j) {
    uint2 u0 = p0[j], u1 = p1[j], u2 = p2[j];
#pragma unroll
    for (int t = 0; t < 4; ++t) {
      unsigned w0 = (t < 2) ? u0.x : u0.y;
      unsigned w1 = (t < 2) ? u1.x : u1.y;
      unsigned w2 = (t < 2) ? u2.x : u2.y;
      int sh = (t & 1) * 16;
      float wv = rt[(4 * j + t) * H2 + o];
      s0 = fmaf(bf2f((unsigned short)(w0 >> sh)), wv, s0);
      s1 = fmaf(bf2f((unsigned short)(w1 >> sh)), wv, s1);
      s2 = fmaf(bf2f((unsigned short)(w2 >> sh)), wv, s2);
    }
  }
  y0[i] = f2bf(s0); y1[i] = f2bf(s1); y2[i] = f2bf(s2);
}

// ===================== layer-2 edge GEMM, ATOMIC (fallback) =====================
template <int NIN>
__global__ __launch_bounds__(256, 2) void k_edge2m(
    const int2* __restrict__ sdp, const float* __restrict__ invp,
    const int* __restrict__ sm, int startOff, int histOff,
    const unsigned short* __restrict__ Wf,
    const unsigned short* __restrict__ x16A, const unsigned short* __restrict__ x16B,
    unsigned short* __restrict__ yA, unsigned short* __restrict__ yB) {
  const int r = blockIdx.x / CPB2;
  const int lane = threadIdx.x & 63;
  bhalf8 wb[4];
  {
    const bhalf8* wf = (const bhalf8*)Wf + ((size_t)r * 4) * 64 + lane;
#pragma unroll
    for (int s = 0; s < 4; ++s) wb[s] = wf[(size_t)s * 64];
  }
  const int wvid = (blockIdx.x - r * CPB2) * 4 + (threadIdx.x >> 6);
  const int stride = CPB2 * 4;
  const int s0 = sm[startOff + r];
  const int cnt = sm[histOff + r];
  const int ngroups = (cnt + 15) >> 4;
  if (wvid >= ngroups) return;
  const int cg = lane >> 4;
  const int col = lane & 15;
  const int row0 = cg << 2;

  int2 sdC; float ivC;
  LM(wvid, sdC, ivC);
  for (int G = wvid; G < ngroups; G += stride) {
    int2 sdN = sdC; float ivN = ivC;
    if (G + stride < ngroups) LM(G + stride, sdN, ivN);
    const int src = sdC.x;
    const int dstv = sdC.y;
    const int d0 = __shfl(dstv, row0),     d1 = __shfl(dstv, row0 + 1),
              d2 = __shfl(dstv, row0 + 2), d3 = __shfl(dstv, row0 + 3);
    const float i0 = __shfl(ivC, row0),     i1 = __shfl(ivC, row0 + 1),
                i2 = __shfl(ivC, row0 + 2), i3 = __shfl(ivC, row0 + 3);
#define SCAT2(Y, CCN, NOFF)                                                     \
    {                                                                           \
      float v0 = (CCN)[0] * i0, v1 = (CCN)[1] * i1,                             \
            v2 = (CCN)[2] * i2, v3 = (CCN)[3] * i3;                             \
      float p0 = __shfl_xor(v0, 1), p1 = __shfl_xor(v1, 1),                     \
            p2 = __shfl_xor(v2, 1), p3 = __shfl_xor(v3, 1);                     \
      if (!(lane & 1)) {                                                        \
        atomPK(Y + (size_t)d0 * H2 + (NOFF) + col, (unsigned)f2bf(v0) | ((unsigned)f2bf(p0) << 16)); \
        atomPK(Y + (size_t)d1 * H2 + (NOFF) + col, (unsigned)f2bf(v1) | ((unsigned)f2bf(p1) << 16)); \
        atomPK(Y + (size_t)d2 * H2 + (NOFF) + col, (unsigned)f2bf(v2) | ((unsigned)f2bf(p2) << 16)); \
        atomPK(Y + (size_t)d3 * H2 + (NOFF) + col, (unsigned)f2bf(v3) | ((unsigned)f2bf(p3) << 16)); \
      }                                                                         \
    }
    {
      const bhalf8* xr = (const bhalf8*)x16A + ((size_t)src << 3);
      bhalf8 a0 = xr[cg], a1 = xr[4 + cg];
      f32x4 c0 = {0.f,0.f,0.f,0.f}, c1 = c0;
      c0 = MFMA16(a0, wb[0], c0); c1 = MFMA16(a0, wb[1], c1);
      c0 = MFMA16(a1, wb[2], c0); c1 = MFMA16(a1, wb[3], c1);
      SCAT2(yA, c0, 0); SCAT2(yA, c1, 16);
    }
    if constexpr (NIN == 2) {
      const bhalf8* xr = (const bhalf8*)x16B + ((size_t)src << 3);
      bhalf8 a0 = xr[cg], a1 = xr[4 + cg];
      f32x4 c0 = {0.f,0.f,0.f,0.f}, c1 = c0;
      c0 = MFMA16(a0, wb[0], c0); c1 = MFMA16(a0, wb[1], c1);
      c0 = MFMA16(a1, wb[2], c0); c1 = MFMA16(a1, wb[3], c1);
      SCAT2(yB, c0, 0); SCAT2(yB, c1, 16);
    }
#undef SCAT2
    sdC = sdN; ivC = ivN;
  }
}

// ===================== layer-2 edge GEMM, STORES (reduce tier) =====================
template <int NIN>
__global__ __launch_bounds__(256, 2) void k_edge2s(
    const int2* __restrict__ sdp, const float* __restrict__ invp,
    const int* __restrict__ sm, int startOff, int histOff,
    const unsigned short* __restrict__ Wf,
    const unsigned short* __restrict__ x16A, const unsigned short* __restrict__ x16B,
    unsigned short* __restrict__ tA, unsigned short* __restrict__ tB) {
  const int r = blockIdx.x / CPB2;
  const int lane = threadIdx.x & 63;
  bhalf8 wb[4];
  {
    const bhalf8* wf = (const bhalf8*)Wf + ((size_t)r * 4) * 64 + lane;
#pragma unroll
    for (int s = 0; s < 4; ++s) wb[s] = wf[(size_t)s * 64];
  }
  const int wvid = (blockIdx.x - r * CPB2) * 4 + (threadIdx.x >> 6);
  const int stride = CPB2 * 4;
  const int s0 = sm[startOff + r];
  const int cnt = sm[histOff + r];
  const int ngroups = (cnt + 15) >> 4;
  if (wvid >= ngroups) return;
  const int cg = lane >> 4;
  const int col = lane & 15;
  const int row0 = cg << 2;

  int2 sdC; float ivC;
  LM(wvid, sdC, ivC);
  for (int G = wvid; G < ngroups; G += stride) {
    int2 sdN = sdC; float ivN = ivC;
    if (G + stride < ngroups) LM(G + stride, sdN, ivN);
    const int src = sdC.x;
    const int base = s0 + (G << 4);
    const int lim = cnt - (G << 4);
    const float i0 = __shfl(ivC, row0),     i1 = __shfl(ivC, row0 + 1),
                i2 = __shfl(ivC, row0 + 2), i3 = __shfl(ivC, row0 + 3);
#define STOR2(T, CCN, NOFF)                                                     \
    {                                                                           \
      float v0 = (CCN)[0] * i0, v1 = (CCN)[1] * i1,                             \
            v2 = (CCN)[2] * i2, v3 = (CCN)[3] * i3;                             \
      float p0 = __shfl_xor(v0, 1), p1 = __shfl_xor(v1, 1),                     \
            p2 = __shfl_xor(v2, 1), p3 = __shfl_xor(v3, 1);                     \
      if (!(lane & 1)) {                                                        \
        if (row0 + 0 < lim) *(unsigned*)(T + (size_t)(base + row0 + 0) * H2 + (NOFF) + col) = (unsigned)f2bf(v0) | ((unsigned)f2bf(p0) << 16); \
        if (row0 + 1 < lim) *(unsigned*)(T + (size_t)(base + row0 + 1) * H2 + (NOFF) + col) = (unsigned)f2bf(v1) | ((unsigned)f2bf(p1) << 16); \
        if (row0 + 2 < lim) *(unsigned*)(T + (size_t)(base + row0 + 2) * H2 + (NOFF) + col) = (unsigned)f2bf(v2) | ((unsigned)f2bf(p2) << 16); \
        if (row0 + 3 < lim) *(unsigned*)(T + (size_t)(base + row0 + 3) * H2 + (NOFF) + col) = (unsigned)f2bf(v3) | ((unsigned)f2bf(p3) << 16); \
      }                                                                         \
    }
    {
      const bhalf8* xr = (const bhalf8*)x16A + ((size_t)src << 3);
      bhalf8 a0 = xr[cg], a1 = xr[4 + cg];
      f32x4 c0 = {0.f,0.f,0.f,0.f}, c1 = c0;
      c0 = MFMA16(a0, wb[0], c0); c1 = MFMA16(a0, wb[1], c1);
      c0 = MFMA16(a1, wb[2], c0); c1 = MFMA16(a1, wb[3], c1);
      STOR2(tA, c0, 0); STOR2(tA, c1, 16);
    }
    if constexpr (NIN == 2) {
      const bhalf8* xr = (const bhalf8*)x16B + ((size_t)src << 3);
      bhalf8 a0 = xr[cg], a1 = xr[4 + cg];
      f32x4 c0 = {0.f,0.f,0.f,0.f}, c1 = c0;
      c0 = MFMA16(a0, wb[0], c0); c1 = MFMA16(a0, wb[1], c1);
      c0 = MFMA16(a1, wb[2], c0); c1 = MFMA16(a1, wb[3], c1);
      STOR2(tB, c0, 0); STOR2(tB, c1, 16);
    }
#undef STOR2
    sdC = sdN; ivC = ivN;
  }
}

// ===================== layer-2 segmented reduce + root =====================
template <int NT>
__global__ __launch_bounds__(256) void k_reduce2(
    const int* __restrict__ startD, const int* __restrict__ pos,
    const unsigned short* __restrict__ t0, const unsigned short* __restrict__ t1,
    const unsigned short* __restrict__ r0, const unsigned short* __restrict__ r1,
    unsigned short* __restrict__ y0, unsigned short* __restrict__ y1,
    float* __restrict__ f32out) {
  int gt = blockIdx.x * blockDim.x + threadIdx.x;
  int d = gt >> 5;
  int colc = gt & 31;
  if (d >= NN) return;
  int e0 = startD[d], e1 = startD[d + 1];
  float a0 = 0.f, a1 = 0.f;
  int j = e0;
  for (; j + 4 <= e1; j += 4) {
    int p0 = pos[j], p1 = pos[j + 1], p2 = pos[j + 2], p3 = pos[j + 3];
    a0 += bf2f(t0[(size_t)p0 * H2 + colc]) + bf2f(t0[(size_t)p1 * H2 + colc])
        + bf2f(t0[(size_t)p2 * H2 + colc]) + bf2f(t0[(size_t)p3 * H2 + colc]);
    if constexpr (NT == 2)
      a1 += bf2f(t1[(size_t)p0 * H2 + colc]) + bf2f(t1[(size_t)p1 * H2 + colc])
          + bf2f(t1[(size_t)p2 * H2 + colc]) + bf2f(t1[(size_t)p3 * H2 + colc]);
  }
  for (; j < e1; ++j) {
    int p = pos[j];
    a0 += bf2f(t0[(size_t)p * H2 + colc]);
    if constexpr (NT == 2) a1 += bf2f(t1[(size_t)p * H2 + colc]);
  }
  size_t o = (size_t)d * H2 + colc;
  float v0 = bf2f(r0[o]) + a0;
  y0[o] = f2bf(v0);
  if (f32out) f32out[o] = v0;
  if constexpr (NT == 2) y1[o] = f2bf(bf2f(r1[o]) + a1);
}

// ===================== x2_o bf16 -> fp32 into d_out (atomic tier) ==================
__global__ __launch_bounds__(256) void k_fin(const uint4* __restrict__ xb,
                                             float4* __restrict__ out, int n8) {
  int i = blockIdx.x * blockDim.x + threadIdx.x;
  if (i >= n8) return;
  uint4 u = xb[i];
  float4 a, b;
  a.x = bf2f((unsigned short)u.x); a.y = bf2f((unsigned short)(u.x >> 16));
  a.z = bf2f((unsigned short)u.y); a.w = bf2f((unsigned short)(u.y >> 16));
  b.x = bf2f((unsigned short)u.z); b.y = bf2f((unsigned short)(u.z >> 16));
  b.z = bf2f((unsigned short)u.w); b.w = bf2f((unsigned short)(u.w >> 16));
  out[2 * i] = a; out[2 * i + 1] = b;
}

// ===================== column sum -> hacc[32] =====================
__global__ __launch_bounds__(256) void k_colsum(const float* __restrict__ x2o,
                                                float* __restrict__ hacc) {
  int tid = threadIdx.x;
  int col = tid & 31;
  int rgrp = blockIdx.x * (blockDim.x >> 5) + (tid >> 5);
  int nth = gridDim.x * (blockDim.x >> 5);
  float s = 0.f;
  for (int n = rgrp; n < NN; n += nth) s += x2o[(size_t)n * H2 + col];
  unsafeAtomicAdd(&hacc[col], s);
}

// ===================== h_os = sigmoid(mean); v = disc_w @ h_os =====================
__global__ __launch_bounds__(64) void k_disc(const float* __restrict__ hacc,
                                             const float* __restrict__ dw,
                                             float* __restrict__ vout) {
  __shared__ float hos[H2];
  int t = threadIdx.x;
  if (t < H2) hos[t] = 1.0f / (1.0f + expf(-hacc[t] / (float)NN));
  __syncthreads();
  if (t < H2) {
    float s = 0.f;
#pragma unroll
    for (int k = 0; k < H2; ++k) s = fmaf(dw[t * H2 + k], hos[k], s);
    vout[t] = s;
  }
}

// ===================== ret_os / ret_os_a =====================
__global__ __launch_bounds__(256) void k_ret(
    const unsigned short* __restrict__ x2o, const unsigned short* __restrict__ x2oa,
    const unsigned short* __restrict__ x2oaa,
    const float* __restrict__ v, const float* __restrict__ db,
    float* __restrict__ ros, float* __restrict__ rosa) {
  int n = blockIdx.x * blockDim.x + threadIdx.x;
  if (n >= NN) return;
  const uint2* a2 = (const uint2*)(x2o + (size_t)n * H2);
  const uint2* b2 = (const uint2*)(x2oa + (size_t)n * H2);
  const uint2* c2 = (const uint2*)(x2oaa + (size_t)n * H2);
  const float4* v4 = (const float4*)v;
  float r0 = 0.f, r1 = 0.f, r2 = 0.f;
#pragma unroll
  for (int j = 0; j < 8; ++j) {
    uint2 ua = a2[j], ub = b2[j], uc = c2[j];
    float4 vv = v4[j];
    r0 += bf2f((unsigned short)ua.x) * vv.x + bf2f((unsigned short)(ua.x >> 16)) * vv.y
        + bf2f((unsigned short)ua.y) * vv.z + bf2f((unsigned short)(ua.y >> 16)) * vv.w;
    r1 += bf2f((unsigned short)ub.x) * vv.x + bf2f((unsigned short)(ub.x >> 16)) * vv.y
        + bf2f((unsigned short)ub.y) * vv.z + bf2f((unsigned short)(ub.y >> 16)) * vv.w;
    r2 += bf2f((unsigned short)uc.x) * vv.x + bf2f((unsigned short)(uc.x >> 16)) * vv.y
        + bf2f((unsigned short)uc.y) * vv.z + bf2f((unsigned short)(uc.y >> 16)) * vv.w;
  }
  float bb = db[0];
  ros[n * 2] = r0 + bb;  ros[n * 2 + 1] = r1 + bb;
  rosa[n * 2] = r0 + bb; rosa[n * 2 + 1] = r2 + bb;
}

// ===================== classifier =====================
__global__ __launch_bounds__(128) void k_cls(
    const int* __restrict__ idx, const unsigned short* __restrict__ x1o,
    const float* __restrict__ x2o,
    const float* __restrict__ attt, const float* __restrict__ cw, const float* __restrict__ cb,
    float* __restrict__ lg) {
  int b = blockIdx.x;
  int r = threadIdx.x;
  if (r >= RR) return;
  int i1 = idx[b], i2 = idx[BQ + b];
  float a0 = attt[0], a1 = attt[1];
  float acc = cb[r];
  const uint2* q1 = (const uint2*)(x1o + (size_t)i1 * H1);
  const float4* q2 = (const float4*)(x2o + (size_t)i1 * H2);
  const uint2* q3 = (const uint2*)(x1o + (size_t)i2 * H1);
  const float4* q4 = (const float4*)(x2o + (size_t)i2 * H2);
#pragma unroll
  for (int j = 0; j < 16; ++j) {
    uint2 u = q1[j];
    float v0 = bf2f((unsigned short)u.x), v1 = bf2f((unsigned short)(u.x >> 16));
    float v2 = bf2f((unsigned short)u.y), v3 = bf2f((unsigned short)(u.y >> 16));
    acc = fmaf(a0 * v0, cw[(4 * j) * RR + r], acc);
    acc = fmaf(a0 * v1, cw[(4 * j + 1) * RR + r], acc);
    acc = fmaf(a0 * v2, cw[(4 * j + 2) * RR + r], acc);
    acc = fmaf(a0 * v3, cw[(4 * j + 3) * RR + r], acc);
  }
#pragma unroll
  for (int j = 0; j < H2 / 4; ++j) {
    float v[4]; *(float4*)v = q2[j];
#pragma unroll
    for (int t = 0; t < 4; ++t) acc = fmaf(a1 * v[t], cw[(H1 + 4 * j + t) * RR + r], acc);
  }
#pragma unroll
  for (int j = 0; j < 16; ++j) {
    uint2 u = q3[j];
    float v0 = bf2f((unsigned short)u.x), v1 = bf2f((unsigned short)(u.x >> 16));
    float v2 = bf2f((unsigned short)u.y), v3 = bf2f((unsigned short)(u.y >> 16));
    acc = fmaf(a0 * v0, cw[(96 + 4 * j) * RR + r], acc);
    acc = fmaf(a0 * v1, cw[(96 + 4 * j + 1) * RR + r], acc);
    acc = fmaf(a0 * v2, cw[(96 + 4 * j + 2) * RR + r], acc);
    acc = fmaf(a0 * v3, cw[(96 + 4 * j + 3) * RR + r], acc);
  }
#pragma unroll
  for (int j = 0; j < H2 / 4; ++j) {
    float v[4]; *(float4*)v = q4[j];
#pragma unroll
    for (int t = 0; t < 4; ++t) acc = fmaf(a1 * v[t], cw[(96 + H1 + 4 * j + t) * RR + r], acc);
  }
  lg[(size_t)b * RR + r] = acc;
}

// ===================== launch =====================
extern "C" void kernel_launch(void* const* d_in, const int* in_sizes, int n_in,
                              void* d_out, int out_size, void* d_ws, size_t ws_size,
                              hipStream_t stream) {
  const float* x_o  = (const float*)d_in[0];
  const float* x_a  = (const float*)d_in[1];
  const int*   ei   = (const int*)d_in[2];
  const int*   etA  = (const int*)d_in[3];
  const int*   etB  = (const int*)d_in[4];
  const int*   idx  = (const int*)d_in[5];
  const float* W1   = (const float*)d_in[6];
  const float* rt1  = (const float*)d_in[7];
  const float* b1   = (const float*)d_in[8];
  const float* W2   = (const float*)d_in[9];
  const float* rt2  = (const float*)d_in[10];
  const float* b2   = (const float*)d_in[11];
  const float* attt = (const float*)d_in[12];
  const float* dw   = (const float*)d_in[13];
  const float* db   = (const float*)d_in[14];
  const float* cw   = (const float*)d_in[15];
  const float* cb   = (const float*)d_in[16];

  const size_t NRp = 1300224;
  int* wsI    = (int*)d_ws;
  int* cntA   = wsI;                            // NRp
  int* cntB   = cntA + NRp;                     // NRp
  int* sm     = cntB + NRp;                     // 1024
  int* cntD   = sm + 1024;                      // NDPAD (memset'd)
  int* startD = cntD + NDPAD;                   // NDPAD
  int* curA   = startD + NDPAD;                 // NDPAD
  int* curB   = curA + NDPAD;                   // NDPAD
  int* ordA   = curB + NDPAD;                   // NE
  int* ordB   = ordA + NE;                      // NE
  int* posA   = ordB + NE;                      // NE
  int* posB   = posA + NE;                      // NE
  int2*  sdA  = (int2*)(posB + NE);             // NE int2
  float* ivA  = (float*)(sdA + NE);             // NE
  int2*  sdB  = (int2*)(ivA + NE);              // NE int2
  float* ivB  = (float*)(sdB + NE);             // NE
  // bf16 region
  unsigned short* x1o16   = (unsigned short*)(ivB + NE);   // NN*H1 x3
  unsigned short* x1a16   = x1o16 + (size_t)NN * H1;
  unsigned short* x1aa16  = x1a16 + (size_t)NN * H1;
  unsigned short* x2ob    = x1aa16 + (size_t)NN * H1;      // NN*H2 x3
  unsigned short* x2oab   = x2ob + (size_t)NN * H2;
  unsigned short* x2oaab  = x2oab + (size_t)NN * H2;
  unsigned short* xo16    = x2oaab + (size_t)NN * H2;      // NN*FF x2
  unsigned short* xa16    = xo16 + (size_t)NN * FF;
  unsigned short* W1f     = xa16 + (size_t)NN * FF;        // RR*16*64*8
  unsigned short* W2f     = W1f + (size_t)RR * 16 * 64 * 8;
  unsigned short* rootO16 = W2f + (size_t)RR * 4 * 64 * 8; // NN*H1 x2
  unsigned short* rootA16 = rootO16 + (size_t)NN * H1;
  unsigned short* r2o16   = rootA16 + (size_t)NN * H1;     // NN*H2 x3
  unsigned short* r2a16   = r2o16 + (size_t)NN * H2;
  unsigned short* r2aa16  = r2a16 + (size_t)NN * H2;
  unsigned short* t0      = r2aa16 + (size_t)NN * H2;      // t region start
  unsigned short* t1      = t0 + (size_t)NE * H1;
  unsigned short* tc1     = t0 + (size_t)NE * H2;          // layer-2 second tensor

  const size_t ofsT = (size_t)((char*)t0 - (char*)d_ws);
  const size_t needFull = ofsT + (size_t)2 * NE * H1 * 2 + 256;   // tA0+tA1
  const size_t needMid  = ofsT + (size_t)2 * NE * H2 * 2 + 256;   // tC0+tC1
  const bool fullT = ws_size >= needFull;
  const bool midT  = fullT || ws_size >= needMid;   // layer-2 reduce available

  float* smF  = (float*)sm;
  float* hacc = smF + SM_HACC;
  float* vbuf = smF + SM_V;

  float* outF   = (float*)d_out;
  float* o_log  = outF;
  float* o_ros  = outF + (size_t)BQ * RR;
  float* o_rosa = o_ros + (size_t)NN * 2;
  float* o_x2o  = o_rosa + (size_t)NN * 2;

  hipMemsetAsync(wsI, 0, (2 * NRp + 1024 + NDPAD) * sizeof(int), stream);

  // prep
  k_cvt2<<<(2 * NN * FF / 8 + 255) / 256, 256, 0, stream>>>(
      (const float4*)x_o, (const float4*)x_a, (uint4*)xo16, (uint4*)xa16, NN * FF / 8);
  k_wprep1<<<RR, 256, 0, stream>>>(W1, W1f);
  k_wprep2<<<RR, 256, 0, stream>>>(W2, W2f);

  k_hist<<<(NE + 255) / 256, 256, 0, stream>>>(ei, etA, etB, cntA, cntB, sm, cntD);
  k_prefix<<<1, 128, 0, stream>>>(sm);
  k_scatter<<<(NE + 255) / 256, 256, 0, stream>>>(etA, etB, sm, ordA, ordB);
  k_emeta<<<(NE + 255) / 256, 256, 0, stream>>>(ei, ordA, ordB, cntA, cntB,
                                                etA, etB, sdA, ivA, sdB, ivB);
  if (midT) {
    k_prefixD<<<1, 256, 0, stream>>>(cntD, startD, curA, curB);
    k_scatterD<<<(NE + 255) / 256, 256, 0, stream>>>(sdA, sdB, curA, curB, posA, posB);
  }

  // ---- layer 1 ----
  if (fullT) {
    k_root1<<<(NN * H1) / 256, 256, 0, stream>>>(x_o, x_a, rt1, b1,
                                                 rootO16, rootO16, rootA16);
    k_edge1s<2><<<RR * CPB1, 256, 0, stream>>>(sdA, ivA, sm, SM_START_A, SM_HIST_A,
                                               W1f, xo16, xa16, t0, t1);
    k_reduce1<2><<<(NN * 64) / 256, 256, 0, stream>>>(startD, posA, t0, t1,
                                                      rootO16, rootA16, x1o16, x1a16);
    k_edge1s<1><<<RR * CPB1, 256, 0, stream>>>(sdB, ivB, sm, SM_START_B, SM_HIST_B,
                                               W1f, xo16, nullptr, t0, nullptr);
    k_reduce1<1><<<(NN * 64) / 256, 256, 0, stream>>>(startD, posB, t0, nullptr,
                                                      rootO16, nullptr, x1aa16, nullptr);
  } else {
    k_root1<<<(NN * H1) / 256, 256, 0, stream>>>(x_o, x_a, rt1, b1,
                                                 x1o16, x1aa16, x1a16);
    k_edge1m<2><<<RR * CPB1, 256, 0, stream>>>(sdA, ivA, sm, SM_START_A, SM_HIST_A,
                                               W1f, xo16, xa16, x1o16, x1a16);
    k_edge1m<1><<<RR * CPB1, 256, 0, stream>>>(sdB, ivB, sm, SM_START_B, SM_HIST_B,
                                               W1f, xo16, nullptr, x1aa16, nullptr);
    k_relu16<<<(3 * NN * H1 / 8 + 255) / 256, 256, 0, stream>>>((uint4*)x1o16,
                                                                3 * NN * H1 / 8);
  }

  // ---- layer 2 ----
  if (midT) {
    k_root2x3<<<(NN * H2 + 255) / 256, 256, 0, stream>>>(x1o16, x1a16, x1aa16, rt2, b2,
                                                         r2o16, r2a16, r2aa16);
    k_edge2s<2><<<RR * CPB2, 256, 0, stream>>>(sdA, ivA, sm, SM_START_A, SM_HIST_A,
                                               W2f, x1o16, x1a16, t0, tc1);
    k_reduce2<2><<<(NN * 32) / 256, 256, 0, stream>>>(startD, posA, t0, tc1,
                                                      r2o16, r2a16, x2ob, x2oab, o_x2o);
    k_edge2s<1><<<RR * CPB2, 256, 0, stream>>>(sdB, ivB, sm, SM_START_B, SM_HIST_B,
                                               W2f, x1aa16, nullptr, t0, nullptr);
    k_reduce2<1><<<(NN * 32) / 256, 256, 0, stream>>>(startD, posB, t0, nullptr,
                                                      r2aa16, nullptr, x2oaab, nullptr,
                                                      nullptr);
  } else {
    k_root2x3<<<(NN * H2 + 255) / 256, 256, 0, stream>>>(x1o16, x1a16, x1aa16, rt2, b2,
                                                         x2ob, x2oab, x2oaab);
    k_edge2m<2><<<RR * CPB2, 256, 0, stream>>>(sdA, ivA, sm, SM_START_A, SM_HIST_A,
                                               W2f, x1o16, x1a16, x2ob, x2oab);
    k_edge2m<1><<<RR * CPB2, 256, 0, stream>>>(sdB, ivB, sm, SM_START_B, SM_HIST_B,
                                               W2f, x1aa16, nullptr, x2oaab, nullptr);
    k_fin<<<(NN * H2 / 8 + 255) / 256, 256, 0, stream>>>((const uint4*)x2ob,
                                                         (float4*)o_x2o, NN * H2 / 8);
  }

  k_colsum<<<128, 256, 0, stream>>>(o_x2o, hacc);
  k_disc<<<1, 64, 0, stream>>>(hacc, dw, vbuf);
  k_ret<<<(NN + 255) / 256, 256, 0, stream>>>(x2ob, x2oab, x2oaab, vbuf, db, o_ros, o_rosa);
  k_cls<<<BQ, 128, 0, stream>>>(idx, x1o16, o_x2o, attt, cw, cb, o_log);
}

// Round 16
// 828.110 us; speedup vs baseline: 2.8477x; 1.0469x over previous
//
#include <hip/hip_runtime.h>

// ---- problem dims ----
#define NN 20000
#define NE 640000
#define FF 128
#define H1 64
#define H2 32
#define RR 65
#define BQ 4096
#define NDPAD 20480

// ---- small scratch block offsets (ints within sm[1024]) ----
#define SM_HIST_A 0
#define SM_START_A 128
#define SM_CUR_A 256
#define SM_HIST_B 384
#define SM_START_B 512
#define SM_CUR_B 640
#define SM_HACC 768   // 32 floats
#define SM_V 832      // 32 floats

#define CPB1 32
#define CPB2 32

typedef __attribute__((ext_vector_type(8))) short bhalf8;   // 8 bf16 (4 VGPRs)
typedef __attribute__((ext_vector_type(4))) float f32x4;
#define MFMA16(a, b, c) __builtin_amdgcn_mfma_f32_16x16x32_bf16(a, b, c, 0, 0, 0)

__device__ __forceinline__ unsigned short f2bf(float f) {
  unsigned int u = __float_as_uint(f);
  unsigned int r = (u + 0x7fffu + ((u >> 16) & 1u)) >> 16;   // RNE
  return (unsigned short)r;
}
__device__ __forceinline__ float bf2f(unsigned short u) {
  return __uint_as_float((unsigned)u << 16);
}
__device__ __forceinline__ void atomPK(unsigned short* p, unsigned v) {
  asm volatile("global_atomic_pk_add_bf16 %0, %1, off"
               :: "v"((unsigned long long)p), "v"(v) : "memory");
}

// ===================== histogram: per-dst counts (L2-resident) + per-rel (LDS) =====
// r16: the two NR=1.3M-bin (dst,rel) histograms are GONE (were 127us of random
// line-allocate traffic). inv is now computed segment-locally in k_invD.
__global__ __launch_bounds__(256) void k_hist(
    const int* __restrict__ ei, const int* __restrict__ etA, const int* __restrict__ etB,
    int* __restrict__ sm, int* __restrict__ cntD) {
  __shared__ int lh[2 * RR];
  int tid = threadIdx.x;
  for (int i = tid; i < 2 * RR; i += blockDim.x) lh[i] = 0;
  __syncthreads();
  int e = blockIdx.x * blockDim.x + tid;
  if (e < NE) {
    int dst = ei[NE + e];
    atomicAdd(&cntD[dst], 1);
    atomicAdd(&lh[etA[e]], 1);
    atomicAdd(&lh[RR + etB[e]], 1);
  }
  __syncthreads();
  for (int i = tid; i < 2 * RR; i += blockDim.x) {
    int c = lh[i];
    if (c) atomicAdd(&sm[(i < RR) ? (SM_HIST_A + i) : (SM_HIST_B + (i - RR))], c);
  }
}

// ===================== exclusive prefix over 65 bins =====================
__global__ __launch_bounds__(128) void k_prefix(int* __restrict__ sm) {
  int w = threadIdx.x >> 6;
  if ((threadIdx.x & 63) == 0 && w < 2) {
    int hb = w ? SM_HIST_B : SM_HIST_A;
    int sb = w ? SM_START_B : SM_START_A;
    int cb = w ? SM_CUR_B : SM_CUR_A;
    int h[RR];
#pragma unroll
    for (int r = 0; r < RR; ++r) h[r] = sm[hb + r];
    int s = 0;
#pragma unroll
    for (int r = 0; r < RR; ++r) { sm[sb + r] = s; sm[cb + r] = s; s += h[r]; }
  }
}

// ===================== exclusive prefix over 20000 dst bins (1 block) ==============
__global__ __launch_bounds__(256) void k_prefixD(
    const int* __restrict__ cntD, int* __restrict__ startD,
    int* __restrict__ curA, int* __restrict__ curB) {
  __shared__ int psum[256];
  __shared__ int pbase[257];
  int t = threadIdx.x;
  int c0 = t * 80;
  int c1 = (c0 + 80 < NN) ? (c0 + 80) : NN;
  int s = 0;
  for (int i = c0; i < c1; ++i) s += cntD[i];
  psum[t] = s;
  __syncthreads();
  if (t == 0) {
    int a = 0;
    for (int i = 0; i < 256; ++i) { pbase[i] = a; a += psum[i]; }
    pbase[256] = a;
  }
  __syncthreads();
  int run = pbase[t];
  for (int i = c0; i < c1; ++i) {
    startD[i] = run; curA[i] = run; curB[i] = run;
    run += cntD[i];
  }
  if (t == 255) startD[NN] = pbase[256];
}

// ===================== counting-sort scatter (rel-major) =====================
__global__ __launch_bounds__(256) void k_scatter(
    const int* __restrict__ etA, const int* __restrict__ etB,
    int* __restrict__ sm, int* __restrict__ ordA, int* __restrict__ ordB) {
  __shared__ int lhA[RR], lbA[RR], lhB[RR], lbB[RR];
  int tid = threadIdx.x;
  for (int i = tid; i < RR; i += blockDim.x) { lhA[i] = 0; lhB[i] = 0; }
  __syncthreads();
  int e = blockIdx.x * blockDim.x + tid;
  int ta = 0, tb = 0, ra = 0, rb = 0;
  bool valid = (e < NE);
  if (valid) {
    ta = etA[e]; tb = etB[e];
    ra = atomicAdd(&lhA[ta], 1);
    rb = atomicAdd(&lhB[tb], 1);
  }
  __syncthreads();
  for (int i = tid; i < RR; i += blockDim.x) {
    if (lhA[i]) lbA[i] = atomicAdd(&sm[SM_CUR_A + i], lhA[i]);
    if (lhB[i]) lbB[i] = atomicAdd(&sm[SM_CUR_B + i], lhB[i]);
  }
  __syncthreads();
  if (valid) { ordA[lbA[ta] + ra] = e; ordB[lbB[tb] + rb] = e; }
}

// ===================== flatten meta: sd = (src | rel<<20, dst) =====================
__global__ __launch_bounds__(256) void k_emeta(
    const int* __restrict__ ei, const int* __restrict__ ordA, const int* __restrict__ ordB,
    const int* __restrict__ etA, const int* __restrict__ etB,
    int2* __restrict__ sdA, int2* __restrict__ sdB) {
  int p = blockIdx.x * blockDim.x + threadIdx.x;
  if (p >= NE) return;
  {
    int e = ordA[p];
    sdA[p] = make_int2(ei[e] | (etA[e] << 20), ei[NE + e]);
  }
  {
    int e = ordB[p];
    sdB[p] = make_int2(ei[e] | (etB[e] << 20), ei[NE + e]);
  }
}

// ===================== dst-major position lists =====================
__global__ __launch_bounds__(256) void k_scatterD(
    const int2* __restrict__ sdA, const int2* __restrict__ sdB,
    int* __restrict__ curA, int* __restrict__ curB,
    int* __restrict__ posA, int* __restrict__ posB) {
  int p = blockIdx.x * blockDim.x + threadIdx.x;
  if (p >= NE) return;
  posA[atomicAdd(&curA[sdA[p].y], 1)] = p;
  posB[atomicAdd(&curB[sdB[p].y], 1)] = p;
}

// ===================== inv = 1/cnt(dst,rel) via per-segment wave ballot-count ======
// One wave per dst segment; lane j holds edge j's rel; cnt = #matching rels in the
// segment (64-step shfl broadcast). Plain stores to iv[relpos]. Replaces the 1.3M-bin
// histograms (zero NR-sized arrays, zero random atomics).
__global__ __launch_bounds__(256) void k_invD(
    const int* __restrict__ startD, const int* __restrict__ pos,
    const int2* __restrict__ sd, float* __restrict__ iv) {
  int lane = threadIdx.x & 63;
  int d = (blockIdx.x * blockDim.x + threadIdx.x) >> 6;
  if (d >= NN) return;
  int e0 = startD[d], e1 = startD[d + 1];
  int len = e1 - e0;
  for (int c0 = 0; c0 < len; c0 += 64) {
    int myj = c0 + lane;
    int myp = 0, myrel = -1;
    if (myj < len) { myp = pos[e0 + myj]; myrel = ((unsigned)sd[myp].x) >> 20; }
    int cnt = 0;
    for (int c1 = 0; c1 < len; c1 += 64) {
      int oj = c1 + lane;
      int orel = (oj < len) ? (int)(((unsigned)sd[pos[e0 + oj]].x) >> 20) : -2;
      int kmax = (len - c1 < 64) ? (len - c1) : 64;
      for (int k = 0; k < kmax; ++k)
        cnt += (__shfl(orel, k) == myrel);
    }
    if (myj < len) iv[myp] = 1.0f / (float)cnt;
  }
}

// ===================== fp32 -> bf16 conversion for x_o and x_a =====================
__global__ __launch_bounds__(256) void k_cvt2(const float4* __restrict__ inA,
                                              const float4* __restrict__ inB,
                                              uint4* __restrict__ outA,
                                              uint4* __restrict__ outB, int n8) {
  int i = blockIdx.x * blockDim.x + threadIdx.x;
  if (i >= 2 * n8) return;
  const float4* in = (i < n8) ? inA : inB;
  uint4* out = (i < n8) ? outA : outB;
  int j = (i < n8) ? i : i - n8;
  float4 a = in[2 * j], b = in[2 * j + 1];
  uint4 o;
  o.x = (unsigned)f2bf(a.x) | ((unsigned)f2bf(a.y) << 16);
  o.y = (unsigned)f2bf(a.z) | ((unsigned)f2bf(a.w) << 16);
  o.z = (unsigned)f2bf(b.x) | ((unsigned)f2bf(b.y) << 16);
  o.w = (unsigned)f2bf(b.z) | ((unsigned)f2bf(b.w) << 16);
  out[j] = o;
}

// ===================== in-place bf16 relu (atomic tier only) =====================
__global__ __launch_bounds__(256) void k_relu16(uint4* __restrict__ a, int n4) {
  int i = blockIdx.x * blockDim.x + threadIdx.x;
  if (i >= n4) return;
  uint4 u = a[i];
  unsigned* w = (unsigned*)&u;
#pragma unroll
  for (int t = 0; t < 4; ++t) {
    unsigned lo = (w[t] & 0x8000u) ? 0u : (w[t] & 0xFFFFu);
    unsigned hi = (w[t] & 0x80000000u) ? 0u : (w[t] & 0xFFFF0000u);
    w[t] = lo | hi;
  }
  a[i] = u;
}

// ===================== W1 -> bf16 B-fragments =====================
__global__ __launch_bounds__(256) void k_wprep1(const float* __restrict__ W,
                                                unsigned short* __restrict__ Wf) {
  int r = blockIdx.x;
  int lane = threadIdx.x & 63, w = threadIdx.x >> 6;
#pragma unroll
  for (int s4 = 0; s4 < 4; ++s4) {
    int slot = w * 4 + s4;
    int ks = slot >> 2, n = slot & 3;
    int krow = ks * 32 + ((lane >> 4) << 3);
    int colo = n * 16 + (lane & 15);
    unsigned short* o = Wf + (((size_t)r * 16 + slot) * 64 + lane) * 8;
#pragma unroll
    for (int j = 0; j < 8; ++j)
      o[j] = f2bf(W[((size_t)r * FF + krow + j) * H1 + colo]);
  }
}

// ===================== W2 -> bf16 B-fragments =====================
__global__ __launch_bounds__(256) void k_wprep2(const float* __restrict__ W,
                                                unsigned short* __restrict__ Wf) {
  int r = blockIdx.x;
  int lane = threadIdx.x & 63, slot = threadIdx.x >> 6;
  int ks = slot >> 1, n = slot & 1;
  int krow = ks * 32 + ((lane >> 4) << 3);
  int colo = n * 16 + (lane & 15);
  unsigned short* o = Wf + (((size_t)r * 4 + slot) * 64 + lane) * 8;
#pragma unroll
  for (int j = 0; j < 8; ++j)
    o[j] = f2bf(W[((size_t)r * H1 + krow + j) * H2 + colo]);
}

// ===================== layer-1 root term -> bf16 =====================
__global__ __launch_bounds__(256) void k_root1(
    const float* __restrict__ xo, const float* __restrict__ xa,
    const float* __restrict__ rt, const float* __restrict__ b,
    unsigned short* __restrict__ yo, unsigned short* __restrict__ yaa,
    unsigned short* __restrict__ ya) {
  int lane = threadIdx.x & 63;
  int n = (blockIdx.x * blockDim.x + threadIdx.x) >> 6;
  if (n >= NN) return;
  const float4* xo4 = (const float4*)(xo + (size_t)n * FF);
  const float4* xa4 = (const float4*)(xa + (size_t)n * FF);
  float so = b[lane], sa = so;
#pragma unroll
  for (int j = 0; j < FF / 4; ++j) {
    float vo[4], va[4];
    *(float4*)vo = xo4[j];
    *(float4*)va = xa4[j];
#pragma unroll
    for (int t = 0; t < 4; ++t) {
      float wv = rt[(4 * j + t) * H1 + lane];
      so = fmaf(vo[t], wv, so);
      sa = fmaf(va[t], wv, sa);
    }
  }
  yo[(size_t)n * H1 + lane] = f2bf(so);
  yaa[(size_t)n * H1 + lane] = f2bf(so);
  ya[(size_t)n * H1 + lane] = f2bf(sa);
}

// ---- meta loader ----
#define LM(G, SD, IV)                                       \
  {                                                         \
    const int base_ = s0 + ((G) << 4);                      \
    const int lim_ = cnt - ((G) << 4);                      \
    const int off_ = base_ + ((col < lim_) ? col : 0);      \
    SD = sdp[off_];                                         \
    IV = (col < lim_) ? invp[off_] : 0.f;                   \
  }

// ===================== MFMA body (layer 1) =====================
#define MFMA_BODY1(A0, A1, A2, A3)                                  \
  f32x4 c0 = {0.f,0.f,0.f,0.f}, c1 = c0, c2 = c0, c3 = c0;          \
  c0 = MFMA16(A0, wb[0], c0);  c1 = MFMA16(A0, wb[1], c1);          \
  c2 = MFMA16(A0, wb[2], c2);  c3 = MFMA16(A0, wb[3], c3);          \
  c0 = MFMA16(A1, wb[4], c0);  c1 = MFMA16(A1, wb[5], c1);          \
  c2 = MFMA16(A1, wb[6], c2);  c3 = MFMA16(A1, wb[7], c3);          \
  c0 = MFMA16(A2, wb[8], c0);  c1 = MFMA16(A2, wb[9], c1);          \
  c2 = MFMA16(A2, wb[10], c2); c3 = MFMA16(A2, wb[11], c3);         \
  c0 = MFMA16(A3, wb[12], c0); c1 = MFMA16(A3, wb[13], c1);         \
  c2 = MFMA16(A3, wb[14], c2); c3 = MFMA16(A3, wb[15], c3);

// ===================== layer-1 edge GEMM, ATOMIC scatter (fallback tier) ===========
template <int NIN>
__global__ __launch_bounds__(256, 2) void k_edge1m(
    const int2* __restrict__ sdp, const float* __restrict__ invp,
    const int* __restrict__ sm, int startOff, int histOff,
    const unsigned short* __restrict__ Wf,
    const unsigned short* __restrict__ x16A, const unsigned short* __restrict__ x16B,
    unsigned short* __restrict__ yA, unsigned short* __restrict__ yB) {
  const int r = blockIdx.x / CPB1;
  const int lane = threadIdx.x & 63;
  bhalf8 wb[16];
  {
    const bhalf8* wf = (const bhalf8*)Wf + ((size_t)r * 16) * 64 + lane;
#pragma unroll
    for (int s = 0; s < 16; ++s) wb[s] = wf[(size_t)s * 64];
  }
  const int wvid = (blockIdx.x - r * CPB1) * 4 + (threadIdx.x >> 6);
  const int stride = CPB1 * 4;
  const int s0 = sm[startOff + r];
  const int cnt = sm[histOff + r];
  const int ngroups = (cnt + 15) >> 4;
  if (wvid >= ngroups) return;
  const int cg = lane >> 4;
  const int col = lane & 15;
  const int row0 = cg << 2;

  int2 sdC; float ivC;
  LM(wvid, sdC, ivC);
  for (int G = wvid; G < ngroups; G += stride) {
    int2 sdN = sdC; float ivN = ivC;
    if (G + stride < ngroups) LM(G + stride, sdN, ivN);
    const int src = sdC.x & 0xFFFFF;
    const int dstv = sdC.y;
    const int d0 = __shfl(dstv, row0),     d1 = __shfl(dstv, row0 + 1),
              d2 = __shfl(dstv, row0 + 2), d3 = __shfl(dstv, row0 + 3);
    const float i0 = __shfl(ivC, row0),     i1 = __shfl(ivC, row0 + 1),
                i2 = __shfl(ivC, row0 + 2), i3 = __shfl(ivC, row0 + 3);
#define SCAT1(Y, CCN, NOFF)                                                     \
    {                                                                           \
      float v0 = (CCN)[0] * i0, v1 = (CCN)[1] * i1,                             \
            v2 = (CCN)[2] * i2, v3 = (CCN)[3] * i3;                             \
      float p0 = __shfl_xor(v0, 1), p1 = __shfl_xor(v1, 1),                     \
            p2 = __shfl_xor(v2, 1), p3 = __shfl_xor(v3, 1);                     \
      if (!(lane & 1)) {                                                        \
        atomPK(Y + (size_t)d0 * H1 + (NOFF) + col, (unsigned)f2bf(v0) | ((unsigned)f2bf(p0) << 16)); \
        atomPK(Y + (size_t)d1 * H1 + (NOFF) + col, (unsigned)f2bf(v1) | ((unsigned)f2bf(p1) << 16)); \
        atomPK(Y + (size_t)d2 * H1 + (NOFF) + col, (unsigned)f2bf(v2) | ((unsigned)f2bf(p2) << 16)); \
        atomPK(Y + (size_t)d3 * H1 + (NOFF) + col, (unsigned)f2bf(v3) | ((unsigned)f2bf(p3) << 16)); \
      }                                                                         \
    }
    {
      const bhalf8* xr = (const bhalf8*)x16A + ((size_t)src << 4);
      bhalf8 a0 = xr[cg], a1 = xr[4 + cg], a2 = xr[8 + cg], a3 = xr[12 + cg];
      MFMA_BODY1(a0, a1, a2, a3)
      SCAT1(yA, c0, 0); SCAT1(yA, c1, 16); SCAT1(yA, c2, 32); SCAT1(yA, c3, 48);
    }
    if constexpr (NIN == 2) {
      const bhalf8* xr = (const bhalf8*)x16B + ((size_t)src << 4);
      bhalf8 a0 = xr[cg], a1 = xr[4 + cg], a2 = xr[8 + cg], a3 = xr[12 + cg];
      MFMA_BODY1(a0, a1, a2, a3)
      SCAT1(yB, c0, 0); SCAT1(yB, c1, 16); SCAT1(yB, c2, 32); SCAT1(yB, c3, 48);
    }
#undef SCAT1
    sdC = sdN; ivC = ivN;
  }
}

// ===================== layer-1 edge GEMM, per-edge row STORES (reduce tier) ========
template <int NIN>
__global__ __launch_bounds__(256, 2) void k_edge1s(
    const int2* __restrict__ sdp, const float* __restrict__ invp,
    const int* __restrict__ sm, int startOff, int histOff,
    const unsigned short* __restrict__ Wf,
    const unsigned short* __restrict__ x16A, const unsigned short* __restrict__ x16B,
    unsigned short* __restrict__ tA, unsigned short* __restrict__ tB) {
  const int r = blockIdx.x / CPB1;
  const int lane = threadIdx.x & 63;
  bhalf8 wb[16];
  {
    const bhalf8* wf = (const bhalf8*)Wf + ((size_t)r * 16) * 64 + lane;
#pragma unroll
    for (int s = 0; s < 16; ++s) wb[s] = wf[(size_t)s * 64];
  }
  const int wvid = (blockIdx.x - r * CPB1) * 4 + (threadIdx.x >> 6);
  const int stride = CPB1 * 4;
  const int s0 = sm[startOff + r];
  const int cnt = sm[histOff + r];
  const int ngroups = (cnt + 15) >> 4;
  if (wvid >= ngroups) return;
  const int cg = lane >> 4;
  const int col = lane & 15;
  const int row0 = cg << 2;

  int2 sdC; float ivC;
  LM(wvid, sdC, ivC);
  for (int G = wvid; G < ngroups; G += stride) {
    int2 sdN = sdC; float ivN = ivC;
    if (G + stride < ngroups) LM(G + stride, sdN, ivN);
    const int src = sdC.x & 0xFFFFF;
    const int base = s0 + (G << 4);
    const int lim = cnt - (G << 4);
    const float i0 = __shfl(ivC, row0),     i1 = __shfl(ivC, row0 + 1),
                i2 = __shfl(ivC, row0 + 2), i3 = __shfl(ivC, row0 + 3);
#define STOR1(T, CCN, NOFF)                                                     \
    {                                                                           \
      float v0 = (CCN)[0] * i0, v1 = (CCN)[1] * i1,                             \
            v2 = (CCN)[2] * i2, v3 = (CCN)[3] * i3;                             \
      float p0 = __shfl_xor(v0, 1), p1 = __shfl_xor(v1, 1),                     \
            p2 = __shfl_xor(v2, 1), p3 = __shfl_xor(v3, 1);                     \
      if (!(lane & 1)) {                                                        \
        if (row0 + 0 < lim) *(unsigned*)(T + (size_t)(base + row0 + 0) * H1 + (NOFF) + col) = (unsigned)f2bf(v0) | ((unsigned)f2bf(p0) << 16); \
        if (row0 + 1 < lim) *(unsigned*)(T + (size_t)(base + row0 + 1) * H1 + (NOFF) + col) = (unsigned)f2bf(v1) | ((unsigned)f2bf(p1) << 16); \
        if (row0 + 2 < lim) *(unsigned*)(T + (size_t)(base + row0 + 2) * H1 + (NOFF) + col) = (unsigned)f2bf(v2) | ((unsigned)f2bf(p2) << 16); \
        if (row0 + 3 < lim) *(unsigned*)(T + (size_t)(base + row0 + 3) * H1 + (NOFF) + col) = (unsigned)f2bf(v3) | ((unsigned)f2bf(p3) << 16); \
      }                                                                         \
    }
    {
      const bhalf8* xr = (const bhalf8*)x16A + ((size_t)src << 4);
      bhalf8 a0 = xr[cg], a1 = xr[4 + cg], a2 = xr[8 + cg], a3 = xr[12 + cg];
      MFMA_BODY1(a0, a1, a2, a3)
      STOR1(tA, c0, 0); STOR1(tA, c1, 16); STOR1(tA, c2, 32); STOR1(tA, c3, 48);
    }
    if constexpr (NIN == 2) {
      const bhalf8* xr = (const bhalf8*)x16B + ((size_t)src << 4);
      bhalf8 a0 = xr[cg], a1 = xr[4 + cg], a2 = xr[8 + cg], a3 = xr[12 + cg];
      MFMA_BODY1(a0, a1, a2, a3)
      STOR1(tB, c0, 0); STOR1(tB, c1, 16); STOR1(tB, c2, 32); STOR1(tB, c3, 48);
    }
#undef STOR1
    sdC = sdN; ivC = ivN;
  }
}

// ===================== layer-1 segmented reduce + root + relu =====================
template <int NT>
__global__ __launch_bounds__(256) void k_reduce1(
    const int* __restrict__ startD, const int* __restrict__ pos,
    const unsigned short* __restrict__ t0, const unsigned short* __restrict__ t1,
    const unsigned short* __restrict__ r0, const unsigned short* __restrict__ r1,
    unsigned short* __restrict__ y0, unsigned short* __restrict__ y1) {
  int lane = threadIdx.x & 63;
  int d = (blockIdx.x * blockDim.x + threadIdx.x) >> 6;
  if (d >= NN) return;
  int e0 = startD[d], e1 = startD[d + 1];
  float a0 = 0.f, a1 = 0.f;
  int j = e0;
  for (; j + 4 <= e1; j += 4) {
    int p0 = pos[j], p1 = pos[j + 1], p2 = pos[j + 2], p3 = pos[j + 3];
    a0 += bf2f(t0[(size_t)p0 * H1 + lane]) + bf2f(t0[(size_t)p1 * H1 + lane])
        + bf2f(t0[(size_t)p2 * H1 + lane]) + bf2f(t0[(size_t)p3 * H1 + lane]);
    if constexpr (NT == 2)
      a1 += bf2f(t1[(size_t)p0 * H1 + lane]) + bf2f(t1[(size_t)p1 * H1 + lane])
          + bf2f(t1[(size_t)p2 * H1 + lane]) + bf2f(t1[(size_t)p3 * H1 + lane]);
  }
  for (; j < e1; ++j) {
    int p = pos[j];
    a0 += bf2f(t0[(size_t)p * H1 + lane]);
    if constexpr (NT == 2) a1 += bf2f(t1[(size_t)p * H1 + lane]);
  }
  size_t o = (size_t)d * H1 + lane;
  y0[o] = f2bf(fmaxf(bf2f(r0[o]) + a0, 0.f));
  if constexpr (NT == 2) y1[o] = f2bf(fmaxf(bf2f(r1[o]) + a1, 0.f));
}

// ===================== layer-2 root term, 3 fused (bf16 out) =====================
__global__ __launch_bounds__(256) void k_root2x3(
    const unsigned short* __restrict__ x1o, const unsigned short* __restrict__ x1a,
    const unsigned short* __restrict__ x1aa,
    const float* __restrict__ rt, const float* __restrict__ b,
    unsigned short* __restrict__ y0, unsigned short* __restrict__ y1,
    unsigned short* __restrict__ y2) {
  int i = blockIdx.x * blockDim.x + threadIdx.x;
  if (i >= NN * H2) return;
  int o = i & (H2 - 1);
  int n = i >> 5;
  const uint2* p0 = (const uint2*)(x1o + (size_t)n * H1);
  const uint2* p1 = (const uint2*)(x1a + (size_t)n * H1);
  const uint2* p2 = (const uint2*)(x1aa + (size_t)n * H1);
  float s0 = b[o], s1 = s0, s2 = s0;
#pragma unroll
  for (int j = 0; j < 16; ++j) {
    uint2 u0 = p0[j], u1 = p1[j], u2 = p2[j];
#pragma unroll
    for (int t = 0; t < 4; ++t) {
      unsigned w0 = (t < 2) ? u0.x : u0.y;
      unsigned w1 = (t < 2) ? u1.x : u1.y;
      unsigned w2 = (t < 2) ? u2.x : u2.y;
      int sh = (t & 1) * 16;
      float wv = rt[(4 * j + t) * H2 + o];
      s0 = fmaf(bf2f((unsigned short)(w0 >> sh)), wv, s0);
      s1 = fmaf(bf2f((unsigned short)(w1 >> sh)), wv, s1);
      s2 = fmaf(bf2f((unsigned short)(w2 >> sh)), wv, s2);
    }
  }
  y0[i] = f2bf(s0); y1[i] = f2bf(s1); y2[i] = f2bf(s2);
}

// ===================== layer-2 edge GEMM, ATOMIC (fallback) =====================
template <int NIN>
__global__ __launch_bounds__(256, 2) void k_edge2m(
    const int2* __restrict__ sdp, const float* __restrict__ invp,
    const int* __restrict__ sm, int startOff, int histOff,
    const unsigned short* __restrict__ Wf,
    const unsigned short* __restrict__ x16A, const unsigned short* __restrict__ x16B,
    unsigned short* __restrict__ yA, unsigned short* __restrict__ yB) {
  const int r = blockIdx.x / CPB2;
  const int lane = threadIdx.x & 63;
  bhalf8 wb[4];
  {
    const bhalf8* wf = (const bhalf8*)Wf + ((size_t)r * 4) * 64 + lane;
#pragma unroll
    for (int s = 0; s < 4; ++s) wb[s] = wf[(size_t)s * 64];
  }
  const int wvid = (blockIdx.x - r * CPB2) * 4 + (threadIdx.x >> 6);
  const int stride = CPB2 * 4;
  const int s0 = sm[startOff + r];
  const int cnt = sm[histOff + r];
  const int ngroups = (cnt + 15) >> 4;
  if (wvid >= ngroups) return;
  const int cg = lane >> 4;
  const int col = lane & 15;
  const int row0 = cg << 2;

  int2 sdC; float ivC;
  LM(wvid, sdC, ivC);
  for (int G = wvid; G < ngroups; G += stride) {
    int2 sdN = sdC; float ivN = ivC;
    if (G + stride < ngroups) LM(G + stride, sdN, ivN);
    const int src = sdC.x & 0xFFFFF;
    const int dstv = sdC.y;
    const int d0 = __shfl(dstv, row0),     d1 = __shfl(dstv, row0 + 1),
              d2 = __shfl(dstv, row0 + 2), d3 = __shfl(dstv, row0 + 3);
    const float i0 = __shfl(ivC, row0),     i1 = __shfl(ivC, row0 + 1),
                i2 = __shfl(ivC, row0 + 2), i3 = __shfl(ivC, row0 + 3);
#define SCAT2(Y, CCN, NOFF)                                                     \
    {                                                                           \
      float v0 = (CCN)[0] * i0, v1 = (CCN)[1] * i1,                             \
            v2 = (CCN)[2] * i2, v3 = (CCN)[3] * i3;                             \
      float p0 = __shfl_xor(v0, 1), p1 = __shfl_xor(v1, 1),                     \
            p2 = __shfl_xor(v2, 1), p3 = __shfl_xor(v3, 1);                     \
      if (!(lane & 1)) {                                                        \
        atomPK(Y + (size_t)d0 * H2 + (NOFF) + col, (unsigned)f2bf(v0) | ((unsigned)f2bf(p0) << 16)); \
        atomPK(Y + (size_t)d1 * H2 + (NOFF) + col, (unsigned)f2bf(v1) | ((unsigned)f2bf(p1) << 16)); \
        atomPK(Y + (size_t)d2 * H2 + (NOFF) + col, (unsigned)f2bf(v2) | ((unsigned)f2bf(p2) << 16)); \
        atomPK(Y + (size_t)d3 * H2 + (NOFF) + col, (unsigned)f2bf(v3) | ((unsigned)f2bf(p3) << 16)); \
      }                                                                         \
    }
    {
      const bhalf8* xr = (const bhalf8*)x16A + ((size_t)src << 3);
      bhalf8 a0 = xr[cg], a1 = xr[4 + cg];
      f32x4 c0 = {0.f,0.f,0.f,0.f}, c1 = c0;
      c0 = MFMA16(a0, wb[0], c0); c1 = MFMA16(a0, wb[1], c1);
      c0 = MFMA16(a1, wb[2], c0); c1 = MFMA16(a1, wb[3], c1);
      SCAT2(yA, c0, 0); SCAT2(yA, c1, 16);
    }
    if constexpr (NIN == 2) {
      const bhalf8* xr = (const bhalf8*)x16B + ((size_t)src << 3);
      bhalf8 a0 = xr[cg], a1 = xr[4 + cg];
      f32x4 c0 = {0.f,0.f,0.f,0.f}, c1 = c0;
      c0 = MFMA16(a0, wb[0], c0); c1 = MFMA16(a0, wb[1], c1);
      c0 = MFMA16(a1, wb[2], c0); c1 = MFMA16(a1, wb[3], c1);
      SCAT2(yB, c0, 0); SCAT2(yB, c1, 16);
    }
#undef SCAT2
    sdC = sdN; ivC = ivN;
  }
}

// ===================== layer-2 edge GEMM, STORES (reduce tier) =====================
template <int NIN>
__global__ __launch_bounds__(256, 2) void k_edge2s(
    const int2* __restrict__ sdp, const float* __restrict__ invp,
    const int* __restrict__ sm, int startOff, int histOff,
    const unsigned short* __restrict__ Wf,
    const unsigned short* __restrict__ x16A, const unsigned short* __restrict__ x16B,
    unsigned short* __restrict__ tA, unsigned short* __restrict__ tB) {
  const int r = blockIdx.x / CPB2;
  const int lane = threadIdx.x & 63;
  bhalf8 wb[4];
  {
    const bhalf8* wf = (const bhalf8*)Wf + ((size_t)r * 4) * 64 + lane;
#pragma unroll
    for (int s = 0; s < 4; ++s) wb[s] = wf[(size_t)s * 64];
  }
  const int wvid = (blockIdx.x - r * CPB2) * 4 + (threadIdx.x >> 6);
  const int stride = CPB2 * 4;
  const int s0 = sm[startOff + r];
  const int cnt = sm[histOff + r];
  const int ngroups = (cnt + 15) >> 4;
  if (wvid >= ngroups) return;
  const int cg = lane >> 4;
  const int col = lane & 15;
  const int row0 = cg << 2;

  int2 sdC; float ivC;
  LM(wvid, sdC, ivC);
  for (int G = wvid; G < ngroups; G += stride) {
    int2 sdN = sdC; float ivN = ivC;
    if (G + stride < ngroups) LM(G + stride, sdN, ivN);
    const int src = sdC.x & 0xFFFFF;
    const int base = s0 + (G << 4);
    const int lim = cnt - (G << 4);
    const float i0 = __shfl(ivC, row0),     i1 = __shfl(ivC, row0 + 1),
                i2 = __shfl(ivC, row0 + 2), i3 = __shfl(ivC, row0 + 3);
#define STOR2(T, CCN, NOFF)                                                     \
    {                                                                           \
      float v0 = (CCN)[0] * i0, v1 = (CCN)[1] * i1,                             \
            v2 = (CCN)[2] * i2, v3 = (CCN)[3] * i3;                             \
      float p0 = __shfl_xor(v0, 1), p1 = __shfl_xor(v1, 1),                     \
            p2 = __shfl_xor(v2, 1), p3 = __shfl_xor(v3, 1);                     \
      if (!(lane & 1)) {                                                        \
        if (row0 + 0 < lim) *(unsigned*)(T + (size_t)(base + row0 + 0) * H2 + (NOFF) + col) = (unsigned)f2bf(v0) | ((unsigned)f2bf(p0) << 16); \
        if (row0 + 1 < lim) *(unsigned*)(T + (size_t)(base + row0 + 1) * H2 + (NOFF) + col) = (unsigned)f2bf(v1) | ((unsigned)f2bf(p1) << 16); \
        if (row0 + 2 < lim) *(unsigned*)(T + (size_t)(base + row0 + 2) * H2 + (NOFF) + col) = (unsigned)f2bf(v2) | ((unsigned)f2bf(p2) << 16); \
        if (row0 + 3 < lim) *(unsigned*)(T + (size_t)(base + row0 + 3) * H2 + (NOFF) + col) = (unsigned)f2bf(v3) | ((unsigned)f2bf(p3) << 16); \
      }                                                                         \
    }
    {
      const bhalf8* xr = (const bhalf8*)x16A + ((size_t)src << 3);
      bhalf8 a0 = xr[cg], a1 = xr[4 + cg];
      f32x4 c0 = {0.f,0.f,0.f,0.f}, c1 = c0;
      c0 = MFMA16(a0, wb[0], c0); c1 = MFMA16(a0, wb[1], c1);
      c0 = MFMA16(a1, wb[2], c0); c1 = MFMA16(a1, wb[3], c1);
      STOR2(tA, c0, 0); STOR2(tA, c1, 16);
    }
    if constexpr (NIN == 2) {
      const bhalf8* xr = (const bhalf8*)x16B + ((size_t)src << 3);
      bhalf8 a0 = xr[cg], a1 = xr[4 + cg];
      f32x4 c0 = {0.f,0.f,0.f,0.f}, c1 = c0;
      c0 = MFMA16(a0, wb[0], c0); c1 = MFMA16(a0, wb[1], c1);
      c0 = MFMA16(a1, wb[2], c0); c1 = MFMA16(a1, wb[3], c1);
      STOR2(tB, c0, 0); STOR2(tB, c1, 16);
    }
#undef STOR2
    sdC = sdN; ivC = ivN;
  }
}

// ===================== layer-2 segmented reduce + root =====================
template <int NT>
__global__ __launch_bounds__(256) void k_reduce2(
    const int* __restrict__ startD, const int* __restrict__ pos,
    const unsigned short* __restrict__ t0, const unsigned short* __restrict__ t1,
    const unsigned short* __restrict__ r0, const unsigned short* __restrict__ r1,
    unsigned short* __restrict__ y0, unsigned short* __restrict__ y1,
    float* __restrict__ f32out) {
  int gt = blockIdx.x * blockDim.x + threadIdx.x;
  int d = gt >> 5;
  int colc = gt & 31;
  if (d >= NN) return;
  int e0 = startD[d], e1 = startD[d + 1];
  float a0 = 0.f, a1 = 0.f;
  int j = e0;
  for (; j + 4 <= e1; j += 4) {
    int p0 = pos[j], p1 = pos[j + 1], p2 = pos[j + 2], p3 = pos[j + 3];
    a0 += bf2f(t0[(size_t)p0 * H2 + colc]) + bf2f(t0[(size_t)p1 * H2 + colc])
        + bf2f(t0[(size_t)p2 * H2 + colc]) + bf2f(t0[(size_t)p3 * H2 + colc]);
    if constexpr (NT == 2)
      a1 += bf2f(t1[(size_t)p0 * H2 + colc]) + bf2f(t1[(size_t)p1 * H2 + colc])
          + bf2f(t1[(size_t)p2 * H2 + colc]) + bf2f(t1[(size_t)p3 * H2 + colc]);
  }
  for (; j < e1; ++j) {
    int p = pos[j];
    a0 += bf2f(t0[(size_t)p * H2 + colc]);
    if constexpr (NT == 2) a1 += bf2f(t1[(size_t)p * H2 + colc]);
  }
  size_t o = (size_t)d * H2 + colc;
  float v0 = bf2f(r0[o]) + a0;
  y0[o] = f2bf(v0);
  if (f32out) f32out[o] = v0;
  if constexpr (NT == 2) y1[o] = f2bf(bf2f(r1[o]) + a1);
}

// ===================== x2_o bf16 -> fp32 into d_out (atomic tier) ==================
__global__ __launch_bounds__(256) void k_fin(const uint4* __restrict__ xb,
                                             float4* __restrict__ out, int n8) {
  int i = blockIdx.x * blockDim.x + threadIdx.x;
  if (i >= n8) return;
  uint4 u = xb[i];
  float4 a, b;
  a.x = bf2f((unsigned short)u.x); a.y = bf2f((unsigned short)(u.x >> 16));
  a.z = bf2f((unsigned short)u.y); a.w = bf2f((unsigned short)(u.y >> 16));
  b.x = bf2f((unsigned short)u.z); b.y = bf2f((unsigned short)(u.z >> 16));
  b.z = bf2f((unsigned short)u.w); b.w = bf2f((unsigned short)(u.w >> 16));
  out[2 * i] = a; out[2 * i + 1] = b;
}

// ===================== column sum -> hacc[32] =====================
__global__ __launch_bounds__(256) void k_colsum(const float* __restrict__ x2o,
                                                float* __restrict__ hacc) {
  int tid = threadIdx.x;
  int col = tid & 31;
  int rgrp = blockIdx.x * (blockDim.x >> 5) + (tid >> 5);
  int nth = gridDim.x * (blockDim.x >> 5);
  float s = 0.f;
  for (int n = rgrp; n < NN; n += nth) s += x2o[(size_t)n * H2 + col];
  unsafeAtomicAdd(&hacc[col], s);
}

// ===================== h_os = sigmoid(mean); v = disc_w @ h_os =====================
__global__ __launch_bounds__(64) void k_disc(const float* __restrict__ hacc,
                                             const float* __restrict__ dw,
                                             float* __restrict__ vout) {
  __shared__ float hos[H2];
  int t = threadIdx.x;
  if (t < H2) hos[t] = 1.0f / (1.0f + expf(-hacc[t] / (float)NN));
  __syncthreads();
  if (t < H2) {
    float s = 0.f;
#pragma unroll
    for (int k = 0; k < H2; ++k) s = fmaf(dw[t * H2 + k], hos[k], s);
    vout[t] = s;
  }
}

// ===================== ret_os / ret_os_a =====================
__global__ __launch_bounds__(256) void k_ret(
    const unsigned short* __restrict__ x2o, const unsigned short* __restrict__ x2oa,
    const unsigned short* __restrict__ x2oaa,
    const float* __restrict__ v, const float* __restrict__ db,
    float* __restrict__ ros, float* __restrict__ rosa) {
  int n = blockIdx.x * blockDim.x + threadIdx.x;
  if (n >= NN) return;
  const uint2* a2 = (const uint2*)(x2o + (size_t)n * H2);
  const uint2* b2 = (const uint2*)(x2oa + (size_t)n * H2);
  const uint2* c2 = (const uint2*)(x2oaa + (size_t)n * H2);
  const float4* v4 = (const float4*)v;
  float r0 = 0.f, r1 = 0.f, r2 = 0.f;
#pragma unroll
  for (int j = 0; j < 8; ++j) {
    uint2 ua = a2[j], ub = b2[j], uc = c2[j];
    float4 vv = v4[j];
    r0 += bf2f((unsigned short)ua.x) * vv.x + bf2f((unsigned short)(ua.x >> 16)) * vv.y
        + bf2f((unsigned short)ua.y) * vv.z + bf2f((unsigned short)(ua.y >> 16)) * vv.w;
    r1 += bf2f((unsigned short)ub.x) * vv.x + bf2f((unsigned short)(ub.x >> 16)) * vv.y
        + bf2f((unsigned short)ub.y) * vv.z + bf2f((unsigned short)(ub.y >> 16)) * vv.w;
    r2 += bf2f((unsigned short)uc.x) * vv.x + bf2f((unsigned short)(uc.x >> 16)) * vv.y
        + bf2f((unsigned short)uc.y) * vv.z + bf2f((unsigned short)(uc.y >> 16)) * vv.w;
  }
  float bb = db[0];
  ros[n * 2] = r0 + bb;  ros[n * 2 + 1] = r1 + bb;
  rosa[n * 2] = r0 + bb; rosa[n * 2 + 1] = r2 + bb;
}

// ===================== classifier =====================
__global__ __launch_bounds__(128) void k_cls(
    const int* __restrict__ idx, const unsigned short* __restrict__ x1o,
    const float* __restrict__ x2o,
    const float* __restrict__ attt, const float* __restrict__ cw, const float* __restrict__ cb,
    float* __restrict__ lg) {
  int b = blockIdx.x;
  int r = threadIdx.x;
  if (r >= RR) return;
  int i1 = idx[b], i2 = idx[BQ + b];
  float a0 = attt[0], a1 = attt[1];
  float acc = cb[r];
  const uint2* q1 = (const uint2*)(x1o + (size_t)i1 * H1);
  const float4* q2 = (const float4*)(x2o + (size_t)i1 * H2);
  const uint2* q3 = (const uint2*)(x1o + (size_t)i2 * H1);
  const float4* q4 = (const float4*)(x2o + (size_t)i2 * H2);
#pragma unroll
  for (int j = 0; j < 16; ++j) {
    uint2 u = q1[j];
    float v0 = bf2f((unsigned short)u.x), v1 = bf2f((unsigned short)(u.x >> 16));
    float v2 = bf2f((unsigned short)u.y), v3 = bf2f((unsigned short)(u.y >> 16));
    acc = fmaf(a0 * v0, cw[(4 * j) * RR + r], acc);
    acc = fmaf(a0 * v1, cw[(4 * j + 1) * RR + r], acc);
    acc = fmaf(a0 * v2, cw[(4 * j + 2) * RR + r], acc);
    acc = fmaf(a0 * v3, cw[(4 * j + 3) * RR + r], acc);
  }
#pragma unroll
  for (int j = 0; j < H2 / 4; ++j) {
    float v[4]; *(float4*)v = q2[j];
#pragma unroll
    for (int t = 0; t < 4; ++t) acc = fmaf(a1 * v[t], cw[(H1 + 4 * j + t) * RR + r], acc);
  }
#pragma unroll
  for (int j = 0; j < 16; ++j) {
    uint2 u = q3[j];
    float v0 = bf2f((unsigned short)u.x), v1 = bf2f((unsigned short)(u.x >> 16));
    float v2 = bf2f((unsigned short)u.y), v3 = bf2f((unsigned short)(u.y >> 16));
    acc = fmaf(a0 * v0, cw[(96 + 4 * j) * RR + r], acc);
    acc = fmaf(a0 * v1, cw[(96 + 4 * j + 1) * RR + r], acc);
    acc = fmaf(a0 * v2, cw[(96 + 4 * j + 2) * RR + r], acc);
    acc = fmaf(a0 * v3, cw[(96 + 4 * j + 3) * RR + r], acc);
  }
#pragma unroll
  for (int j = 0; j < H2 / 4; ++j) {
    float v[4]; *(float4*)v = q4[j];
#pragma unroll
    for (int t = 0; t < 4; ++t) acc = fmaf(a1 * v[t], cw[(96 + H1 + 4 * j + t) * RR + r], acc);
  }
  lg[(size_t)b * RR + r] = acc;
}

// ===================== launch =====================
extern "C" void kernel_launch(void* const* d_in, const int* in_sizes, int n_in,
                              void* d_out, int out_size, void* d_ws, size_t ws_size,
                              hipStream_t stream) {
  const float* x_o  = (const float*)d_in[0];
  const float* x_a  = (const float*)d_in[1];
  const int*   ei   = (const int*)d_in[2];
  const int*   etA  = (const int*)d_in[3];
  const int*   etB  = (const int*)d_in[4];
  const int*   idx  = (const int*)d_in[5];
  const float* W1   = (const float*)d_in[6];
  const float* rt1  = (const float*)d_in[7];
  const float* b1   = (const float*)d_in[8];
  const float* W2   = (const float*)d_in[9];
  const float* rt2  = (const float*)d_in[10];
  const float* b2   = (const float*)d_in[11];
  const float* attt = (const float*)d_in[12];
  const float* dw   = (const float*)d_in[13];
  const float* db   = (const float*)d_in[14];
  const float* cw   = (const float*)d_in[15];
  const float* cb   = (const float*)d_in[16];

  int* wsI    = (int*)d_ws;
  int* sm     = wsI;                            // 1024 (memset'd)
  int* cntD   = sm + 1024;                      // NDPAD (memset'd)
  int* startD = cntD + NDPAD;                   // NDPAD
  int* curA   = startD + NDPAD;                 // NDPAD
  int* curB   = curA + NDPAD;                   // NDPAD
  int* ordA   = curB + NDPAD;                   // NE
  int* ordB   = ordA + NE;                      // NE
  int* posA   = ordB + NE;                      // NE
  int* posB   = posA + NE;                      // NE
  int2*  sdA  = (int2*)(posB + NE);             // NE int2
  int2*  sdB  = sdA + NE;                       // NE int2
  float* ivA  = (float*)(sdB + NE);             // NE
  float* ivB  = ivA + NE;                       // NE
  // bf16 region
  unsigned short* x1o16   = (unsigned short*)(ivB + NE);   // NN*H1 x3
  unsigned short* x1a16   = x1o16 + (size_t)NN * H1;
  unsigned short* x1aa16  = x1a16 + (size_t)NN * H1;
  unsigned short* x2ob    = x1aa16 + (size_t)NN * H1;      // NN*H2 x3
  unsigned short* x2oab   = x2ob + (size_t)NN * H2;
  unsigned short* x2oaab  = x2oab + (size_t)NN * H2;
  unsigned short* xo16    = x2oaab + (size_t)NN * H2;      // NN*FF x2
  unsigned short* xa16    = xo16 + (size_t)NN * FF;
  unsigned short* W1f     = xa16 + (size_t)NN * FF;        // RR*16*64*8
  unsigned short* W2f     = W1f + (size_t)RR * 16 * 64 * 8;
  unsigned short* rootO16 = W2f + (size_t)RR * 4 * 64 * 8; // NN*H1 x2
  unsigned short* rootA16 = rootO16 + (size_t)NN * H1;
  unsigned short* r2o16   = rootA16 + (size_t)NN * H1;     // NN*H2 x3
  unsigned short* r2a16   = r2o16 + (size_t)NN * H2;
  unsigned short* r2aa16  = r2a16 + (size_t)NN * H2;
  unsigned short* t0      = r2aa16 + (size_t)NN * H2;      // t region start
  unsigned short* t1      = t0 + (size_t)NE * H1;
  unsigned short* tc1     = t0 + (size_t)NE * H2;

  const size_t ofsT = (size_t)((char*)t0 - (char*)d_ws);
  const size_t needFull = ofsT + (size_t)2 * NE * H1 * 2 + 256;
  const size_t needMid  = ofsT + (size_t)2 * NE * H2 * 2 + 256;
  const bool fullT = ws_size >= needFull;
  const bool midT  = fullT || ws_size >= needMid;

  float* smF  = (float*)sm;
  float* hacc = smF + SM_HACC;
  float* vbuf = smF + SM_V;

  float* outF   = (float*)d_out;
  float* o_log  = outF;
  float* o_ros  = outF + (size_t)BQ * RR;
  float* o_rosa = o_ros + (size_t)NN * 2;
  float* o_x2o  = o_rosa + (size_t)NN * 2;

  hipMemsetAsync(wsI, 0, (1024 + NDPAD) * sizeof(int), stream);

  // prep
  k_cvt2<<<(2 * NN * FF / 8 + 255) / 256, 256, 0, stream>>>(
      (const float4*)x_o, (const float4*)x_a, (uint4*)xo16, (uint4*)xa16, NN * FF / 8);
  k_wprep1<<<RR, 256, 0, stream>>>(W1, W1f);
  k_wprep2<<<RR, 256, 0, stream>>>(W2, W2f);

  k_hist<<<(NE + 255) / 256, 256, 0, stream>>>(ei, etA, etB, sm, cntD);
  k_prefix<<<1, 128, 0, stream>>>(sm);
  k_prefixD<<<1, 256, 0, stream>>>(cntD, startD, curA, curB);
  k_scatter<<<(NE + 255) / 256, 256, 0, stream>>>(etA, etB, sm, ordA, ordB);
  k_emeta<<<(NE + 255) / 256, 256, 0, stream>>>(ei, ordA, ordB, etA, etB, sdA, sdB);
  k_scatterD<<<(NE + 255) / 256, 256, 0, stream>>>(sdA, sdB, curA, curB, posA, posB);
  k_invD<<<(NN * 64 + 255) / 256, 256, 0, stream>>>(startD, posA, sdA, ivA);
  k_invD<<<(NN * 64 + 255) / 256, 256, 0, stream>>>(startD, posB, sdB, ivB);

  // ---- layer 1 ----
  if (fullT) {
    k_root1<<<(NN * H1) / 256, 256, 0, stream>>>(x_o, x_a, rt1, b1,
                                                 rootO16, rootO16, rootA16);
    k_edge1s<2><<<RR * CPB1, 256, 0, stream>>>(sdA, ivA, sm, SM_START_A, SM_HIST_A,
                                               W1f, xo16, xa16, t0, t1);
    k_reduce1<2><<<(NN * 64) / 256, 256, 0, stream>>>(startD, posA, t0, t1,
                                                      rootO16, rootA16, x1o16, x1a16);
    k_edge1s<1><<<RR * CPB1, 256, 0, stream>>>(sdB, ivB, sm, SM_START_B, SM_HIST_B,
                                               W1f, xo16, nullptr, t0, nullptr);
    k_reduce1<1><<<(NN * 64) / 256, 256, 0, stream>>>(startD, posB, t0, nullptr,
                                                      rootO16, nullptr, x1aa16, nullptr);
  } else {
    k_root1<<<(NN * H1) / 256, 256, 0, stream>>>(x_o, x_a, rt1, b1,
                                                 x1o16, x1aa16, x1a16);
    k_edge1m<2><<<RR * CPB1, 256, 0, stream>>>(sdA, ivA, sm, SM_START_A, SM_HIST_A,
                                               W1f, xo16, xa16, x1o16, x1a16);
    k_edge1m<1><<<RR * CPB1, 256, 0, stream>>>(sdB, ivB, sm, SM_START_B, SM_HIST_B,
                                               W1f, xo16, nullptr, x1aa16, nullptr);
    k_relu16<<<(3 * NN * H1 / 8 + 255) / 256, 256, 0, stream>>>((uint4*)x1o16,
                                                                3 * NN * H1 / 8);
  }

  // ---- layer 2 ----
  if (midT) {
    k_root2x3<<<(NN * H2 + 255) / 256, 256, 0, stream>>>(x1o16, x1a16, x1aa16, rt2, b2,
                                                         r2o16, r2a16, r2aa16);
    k_edge2s<2><<<RR * CPB2, 256, 0, stream>>>(sdA, ivA, sm, SM_START_A, SM_HIST_A,
                                               W2f, x1o16, x1a16, t0, tc1);
    k_reduce2<2><<<(NN * 32) / 256, 256, 0, stream>>>(startD, posA, t0, tc1,
                                                      r2o16, r2a16, x2ob, x2oab, o_x2o);
    k_edge2s<1><<<RR * CPB2, 256, 0, stream>>>(sdB, ivB, sm, SM_START_B, SM_HIST_B,
                                               W2f, x1aa16, nullptr, t0, nullptr);
    k_reduce2<1><<<(NN * 32) / 256, 256, 0, stream>>>(startD, posB, t0, nullptr,
                                                      r2aa16, nullptr, x2oaab, nullptr,
                                                      nullptr);
  } else {
    k_root2x3<<<(NN * H2 + 255) / 256, 256, 0, stream>>>(x1o16, x1a16, x1aa16, rt2, b2,
                                                         x2ob, x2oab, x2oaab);
    k_edge2m<2><<<RR * CPB2, 256, 0, stream>>>(sdA, ivA, sm, SM_START_A, SM_HIST_A,
                                               W2f, x1o16, x1a16, x2ob, x2oab);
    k_edge2m<1><<<RR * CPB2, 256, 0, stream>>>(sdB, ivB, sm, SM_START_B, SM_HIST_B,
                                               W2f, x1aa16, nullptr, x2oaab, nullptr);
    k_fin<<<(NN * H2 / 8 + 255) / 256, 256, 0, stream>>>((const uint4*)x2ob,
                                                         (float4*)o_x2o, NN * H2 / 8);
  }

  k_colsum<<<128, 256, 0, stream>>>(o_x2o, hacc);
  k_disc<<<1, 64, 0, stream>>>(hacc, dw, vbuf);
  k_ret<<<(NN + 255) / 256, 256, 0, stream>>>(x2ob, x2oab, x2oaab, vbuf, db, o_ros, o_rosa);
  k_cls<<<BQ, 128, 0, stream>>>(idx, x1o16, o_x2o, attt, cw, cb, o_log);
}

// Round 17
// 739.177 us; speedup vs baseline: 3.1903x; 1.1203x over previous
//
#include <hip/hip_runtime.h>

// ---- problem dims ----
#define NN 20000
#define NE 640000
#define FF 128
#define H1 64
#define H2 32
#define RR 65
#define BQ 4096
#define NDPAD 20480

// ---- small scratch block offsets (ints within sm[1024]) ----
#define SM_HIST_A 0
#define SM_START_A 128
#define SM_CUR_A 256
#define SM_HIST_B 384
#define SM_START_B 512
#define SM_CUR_B 640
#define SM_HACC 768   // 32 floats
#define SM_V 832      // 32 floats

#define CPB1 32
#define CPB2 32

typedef __attribute__((ext_vector_type(8))) short bhalf8;   // 8 bf16 (4 VGPRs)
typedef __attribute__((ext_vector_type(4))) float f32x4;
#define MFMA16(a, b, c) __builtin_amdgcn_mfma_f32_16x16x32_bf16(a, b, c, 0, 0, 0)

__device__ __forceinline__ unsigned short f2bf(float f) {
  unsigned int u = __float_as_uint(f);
  unsigned int r = (u + 0x7fffu + ((u >> 16) & 1u)) >> 16;   // RNE
  return (unsigned short)r;
}
__device__ __forceinline__ float bf2f(unsigned short u) {
  return __uint_as_float((unsigned)u << 16);
}
__device__ __forceinline__ void atomPK(unsigned short* p, unsigned v) {
  asm volatile("global_atomic_pk_add_bf16 %0, %1, off"
               :: "v"((unsigned long long)p), "v"(v) : "memory");
}

// ===================== histogram: per-dst counts (L2) + per-rel (LDS) ==============
__global__ __launch_bounds__(256) void k_hist(
    const int* __restrict__ ei, const int* __restrict__ etA, const int* __restrict__ etB,
    int* __restrict__ sm, int* __restrict__ cntD) {
  __shared__ int lh[2 * RR];
  int tid = threadIdx.x;
  for (int i = tid; i < 2 * RR; i += blockDim.x) lh[i] = 0;
  __syncthreads();
  int e = blockIdx.x * blockDim.x + tid;
  if (e < NE) {
    atomicAdd(&cntD[ei[NE + e]], 1);
    atomicAdd(&lh[etA[e]], 1);
    atomicAdd(&lh[RR + etB[e]], 1);
  }
  __syncthreads();
  for (int i = tid; i < 2 * RR; i += blockDim.x) {
    int c = lh[i];
    if (c) atomicAdd(&sm[(i < RR) ? (SM_HIST_A + i) : (SM_HIST_B + (i - RR))], c);
  }
}

// ===================== exclusive prefix over 65 bins =====================
__global__ __launch_bounds__(128) void k_prefix(int* __restrict__ sm) {
  int w = threadIdx.x >> 6;
  if ((threadIdx.x & 63) == 0 && w < 2) {
    int hb = w ? SM_HIST_B : SM_HIST_A;
    int sb = w ? SM_START_B : SM_START_A;
    int cb = w ? SM_CUR_B : SM_CUR_A;
    int h[RR];
#pragma unroll
    for (int r = 0; r < RR; ++r) h[r] = sm[hb + r];
    int s = 0;
#pragma unroll
    for (int r = 0; r < RR; ++r) { sm[sb + r] = s; sm[cb + r] = s; s += h[r]; }
  }
}

// ===================== exclusive prefix over 20000 dst bins (1 block) ==============
__global__ __launch_bounds__(256) void k_prefixD(
    const int* __restrict__ cntD, int* __restrict__ startD, int* __restrict__ cur) {
  __shared__ int psum[256];
  __shared__ int pbase[257];
  int t = threadIdx.x;
  int c0 = t * 80;
  int c1 = (c0 + 80 < NN) ? (c0 + 80) : NN;
  int s = 0;
  for (int i = c0; i < c1; ++i) s += cntD[i];
  psum[t] = s;
  __syncthreads();
  if (t == 0) {
    int a = 0;
    for (int i = 0; i < 256; ++i) { pbase[i] = a; a += psum[i]; }
    pbase[256] = a;
  }
  __syncthreads();
  int run = pbase[t];
  for (int i = c0; i < c1; ++i) {
    startD[i] = run; cur[i] = run;
    run += cntD[i];
  }
  if (t == 255) startD[NN] = pbase[256];
}

// ===================== fused counting-sort scatter ================================
// r17: ONE kernel replaces scatter+emeta+scatterD. Sequential reads of ei/et;
// writes sd=(src|dst<<15, q) at rel-major p for each stream, and relQ[q]=relA|relB<<8
// at the shared dst-major slot q (both streams share dst per edge -> one slot pool).
// 3 random line-touches/edge vs the old 4 + a gather pass.
__global__ __launch_bounds__(256) void k_scatterF(
    const int* __restrict__ ei, const int* __restrict__ etA, const int* __restrict__ etB,
    int* __restrict__ sm, int* __restrict__ cur,
    int2* __restrict__ sdA, int2* __restrict__ sdB,
    unsigned short* __restrict__ relQ) {
  __shared__ int lhA[RR], lbA[RR], lhB[RR], lbB[RR];
  int tid = threadIdx.x;
  for (int i = tid; i < RR; i += blockDim.x) { lhA[i] = 0; lhB[i] = 0; }
  __syncthreads();
  int e = blockIdx.x * blockDim.x + tid;
  int ta = 0, tb = 0, ra = 0, rb = 0;
  bool valid = (e < NE);
  if (valid) {
    ta = etA[e]; tb = etB[e];
    ra = atomicAdd(&lhA[ta], 1);
    rb = atomicAdd(&lhB[tb], 1);
  }
  __syncthreads();
  for (int i = tid; i < RR; i += blockDim.x) {
    if (lhA[i]) lbA[i] = atomicAdd(&sm[SM_CUR_A + i], lhA[i]);
    if (lhB[i]) lbB[i] = atomicAdd(&sm[SM_CUR_B + i], lhB[i]);
  }
  __syncthreads();
  if (valid) {
    int src = ei[e], dst = ei[NE + e];
    int q = atomicAdd(&cur[dst], 1);
    int packed = src | (dst << 15);
    sdA[lbA[ta] + ra] = make_int2(packed, q);
    sdB[lbB[tb] + rb] = make_int2(packed, q);
    relQ[q] = (unsigned short)(ta | (tb << 8));
  }
}

// ===================== inv for both streams (contiguous relQ per dst segment) ======
__global__ __launch_bounds__(256) void k_invD2(
    const int* __restrict__ startD, const unsigned short* __restrict__ relQ,
    float* __restrict__ ivqA, float* __restrict__ ivqB) {
  int lane = threadIdx.x & 63;
  int d = (blockIdx.x * blockDim.x + threadIdx.x) >> 6;
  if (d >= NN) return;
  int e0 = startD[d], e1 = startD[d + 1];
  int len = e1 - e0;
  for (int c0 = 0; c0 < len; c0 += 64) {
    int myj = c0 + lane;
    int mr = (myj < len) ? (int)relQ[e0 + myj] : 0;
    int mA = mr & 0xFF, mB = mr >> 8;
    int cA = 0, cB = 0;
    for (int c1 = 0; c1 < len; c1 += 64) {
      int oj = c1 + lane;
      int orr = (oj < len) ? (int)relQ[e0 + oj] : 0;
      int kmax = (len - c1 < 64) ? (len - c1) : 64;
      for (int k = 0; k < kmax; ++k) {
        int o = __shfl(orr, k);
        cA += ((o & 0xFF) == mA);
        cB += ((o >> 8) == mB);
      }
    }
    if (myj < len) {
      ivqA[e0 + myj] = 1.0f / (float)cA;
      ivqB[e0 + myj] = 1.0f / (float)cB;
    }
  }
}

// ===================== fp32 -> bf16 conversion for x_o and x_a =====================
__global__ __launch_bounds__(256) void k_cvt2(const float4* __restrict__ inA,
                                              const float4* __restrict__ inB,
                                              uint4* __restrict__ outA,
                                              uint4* __restrict__ outB, int n8) {
  int i = blockIdx.x * blockDim.x + threadIdx.x;
  if (i >= 2 * n8) return;
  const float4* in = (i < n8) ? inA : inB;
  uint4* out = (i < n8) ? outA : outB;
  int j = (i < n8) ? i : i - n8;
  float4 a = in[2 * j], b = in[2 * j + 1];
  uint4 o;
  o.x = (unsigned)f2bf(a.x) | ((unsigned)f2bf(a.y) << 16);
  o.y = (unsigned)f2bf(a.z) | ((unsigned)f2bf(a.w) << 16);
  o.z = (unsigned)f2bf(b.x) | ((unsigned)f2bf(b.y) << 16);
  o.w = (unsigned)f2bf(b.z) | ((unsigned)f2bf(b.w) << 16);
  out[j] = o;
}

// ===================== in-place bf16 relu (atomic tier only) =====================
__global__ __launch_bounds__(256) void k_relu16(uint4* __restrict__ a, int n4) {
  int i = blockIdx.x * blockDim.x + threadIdx.x;
  if (i >= n4) return;
  uint4 u = a[i];
  unsigned* w = (unsigned*)&u;
#pragma unroll
  for (int t = 0; t < 4; ++t) {
    unsigned lo = (w[t] & 0x8000u) ? 0u : (w[t] & 0xFFFFu);
    unsigned hi = (w[t] & 0x80000000u) ? 0u : (w[t] & 0xFFFF0000u);
    w[t] = lo | hi;
  }
  a[i] = u;
}

// ===================== W1 -> bf16 B-fragments =====================
__global__ __launch_bounds__(256) void k_wprep1(const float* __restrict__ W,
                                                unsigned short* __restrict__ Wf) {
  int r = blockIdx.x;
  int lane = threadIdx.x & 63, w = threadIdx.x >> 6;
#pragma unroll
  for (int s4 = 0; s4 < 4; ++s4) {
    int slot = w * 4 + s4;
    int ks = slot >> 2, n = slot & 3;
    int krow = ks * 32 + ((lane >> 4) << 3);
    int colo = n * 16 + (lane & 15);
    unsigned short* o = Wf + (((size_t)r * 16 + slot) * 64 + lane) * 8;
#pragma unroll
    for (int j = 0; j < 8; ++j)
      o[j] = f2bf(W[((size_t)r * FF + krow + j) * H1 + colo]);
  }
}

// ===================== W2 -> bf16 B-fragments =====================
__global__ __launch_bounds__(256) void k_wprep2(const float* __restrict__ W,
                                                unsigned short* __restrict__ Wf) {
  int r = blockIdx.x;
  int lane = threadIdx.x & 63, slot = threadIdx.x >> 6;
  int ks = slot >> 1, n = slot & 1;
  int krow = ks * 32 + ((lane >> 4) << 3);
  int colo = n * 16 + (lane & 15);
  unsigned short* o = Wf + (((size_t)r * 4 + slot) * 64 + lane) * 8;
#pragma unroll
  for (int j = 0; j < 8; ++j)
    o[j] = f2bf(W[((size_t)r * H1 + krow + j) * H2 + colo]);
}

// ===================== layer-1 root term -> bf16 =====================
__global__ __launch_bounds__(256) void k_root1(
    const float* __restrict__ xo, const float* __restrict__ xa,
    const float* __restrict__ rt, const float* __restrict__ b,
    unsigned short* __restrict__ yo, unsigned short* __restrict__ yaa,
    unsigned short* __restrict__ ya) {
  int lane = threadIdx.x & 63;
  int n = (blockIdx.x * blockDim.x + threadIdx.x) >> 6;
  if (n >= NN) return;
  const float4* xo4 = (const float4*)(xo + (size_t)n * FF);
  const float4* xa4 = (const float4*)(xa + (size_t)n * FF);
  float so = b[lane], sa = so;
#pragma unroll
  for (int j = 0; j < FF / 4; ++j) {
    float vo[4], va[4];
    *(float4*)vo = xo4[j];
    *(float4*)va = xa4[j];
#pragma unroll
    for (int t = 0; t < 4; ++t) {
      float wv = rt[(4 * j + t) * H1 + lane];
      so = fmaf(vo[t], wv, so);
      sa = fmaf(va[t], wv, sa);
    }
  }
  yo[(size_t)n * H1 + lane] = f2bf(so);
  yaa[(size_t)n * H1 + lane] = f2bf(so);
  ya[(size_t)n * H1 + lane] = f2bf(sa);
}

// ---- meta loader: sd=(src|dst<<15, q); iv gathered from dst-major ivq by q ----
#define LM(G, SD, IV)                                       \
  {                                                         \
    const int base_ = s0 + ((G) << 4);                      \
    const int lim_ = cnt - ((G) << 4);                      \
    const int off_ = base_ + ((col < lim_) ? col : 0);      \
    SD = sdp[off_];                                         \
    IV = (col < lim_) ? ivq[SD.y] : 0.f;                    \
  }

// ===================== MFMA body (layer 1) =====================
#define MFMA_BODY1(A0, A1, A2, A3)                                  \
  f32x4 c0 = {0.f,0.f,0.f,0.f}, c1 = c0, c2 = c0, c3 = c0;          \
  c0 = MFMA16(A0, wb[0], c0);  c1 = MFMA16(A0, wb[1], c1);          \
  c2 = MFMA16(A0, wb[2], c2);  c3 = MFMA16(A0, wb[3], c3);          \
  c0 = MFMA16(A1, wb[4], c0);  c1 = MFMA16(A1, wb[5], c1);          \
  c2 = MFMA16(A1, wb[6], c2);  c3 = MFMA16(A1, wb[7], c3);          \
  c0 = MFMA16(A2, wb[8], c0);  c1 = MFMA16(A2, wb[9], c1);          \
  c2 = MFMA16(A2, wb[10], c2); c3 = MFMA16(A2, wb[11], c3);         \
  c0 = MFMA16(A3, wb[12], c0); c1 = MFMA16(A3, wb[13], c1);         \
  c2 = MFMA16(A3, wb[14], c2); c3 = MFMA16(A3, wb[15], c3);

// ===================== layer-1 edge GEMM, ATOMIC scatter (fallback tier) ===========
template <int NIN>
__global__ __launch_bounds__(256, 2) void k_edge1m(
    const int2* __restrict__ sdp, const float* __restrict__ ivq,
    const int* __restrict__ sm, int startOff, int histOff,
    const unsigned short* __restrict__ Wf,
    const unsigned short* __restrict__ x16A, const unsigned short* __restrict__ x16B,
    unsigned short* __restrict__ yA, unsigned short* __restrict__ yB) {
  const int r = blockIdx.x / CPB1;
  const int lane = threadIdx.x & 63;
  bhalf8 wb[16];
  {
    const bhalf8* wf = (const bhalf8*)Wf + ((size_t)r * 16) * 64 + lane;
#pragma unroll
    for (int s = 0; s < 16; ++s) wb[s] = wf[(size_t)s * 64];
  }
  const int wvid = (blockIdx.x - r * CPB1) * 4 + (threadIdx.x >> 6);
  const int stride = CPB1 * 4;
  const int s0 = sm[startOff + r];
  const int cnt = sm[histOff + r];
  const int ngroups = (cnt + 15) >> 4;
  if (wvid >= ngroups) return;
  const int cg = lane >> 4;
  const int col = lane & 15;
  const int row0 = cg << 2;

  int2 sdC; float ivC;
  LM(wvid, sdC, ivC);
  for (int G = wvid; G < ngroups; G += stride) {
    int2 sdN = sdC; float ivN = ivC;
    if (G + stride < ngroups) LM(G + stride, sdN, ivN);
    const int src = sdC.x & 0x7FFF;
    const int dstv = (sdC.x >> 15) & 0x7FFF;
    const int d0 = __shfl(dstv, row0),     d1 = __shfl(dstv, row0 + 1),
              d2 = __shfl(dstv, row0 + 2), d3 = __shfl(dstv, row0 + 3);
    const float i0 = __shfl(ivC, row0),     i1 = __shfl(ivC, row0 + 1),
                i2 = __shfl(ivC, row0 + 2), i3 = __shfl(ivC, row0 + 3);
#define SCAT1(Y, CCN, NOFF)                                                     \
    {                                                                           \
      float v0 = (CCN)[0] * i0, v1 = (CCN)[1] * i1,                             \
            v2 = (CCN)[2] * i2, v3 = (CCN)[3] * i3;                             \
      float p0 = __shfl_xor(v0, 1), p1 = __shfl_xor(v1, 1),                     \
            p2 = __shfl_xor(v2, 1), p3 = __shfl_xor(v3, 1);                     \
      if (!(lane & 1)) {                                                        \
        atomPK(Y + (size_t)d0 * H1 + (NOFF) + col, (unsigned)f2bf(v0) | ((unsigned)f2bf(p0) << 16)); \
        atomPK(Y + (size_t)d1 * H1 + (NOFF) + col, (unsigned)f2bf(v1) | ((unsigned)f2bf(p1) << 16)); \
        atomPK(Y + (size_t)d2 * H1 + (NOFF) + col, (unsigned)f2bf(v2) | ((unsigned)f2bf(p2) << 16)); \
        atomPK(Y + (size_t)d3 * H1 + (NOFF) + col, (unsigned)f2bf(v3) | ((unsigned)f2bf(p3) << 16)); \
      }                                                                         \
    }
    {
      const bhalf8* xr = (const bhalf8*)x16A + ((size_t)src << 4);
      bhalf8 a0 = xr[cg], a1 = xr[4 + cg], a2 = xr[8 + cg], a3 = xr[12 + cg];
      MFMA_BODY1(a0, a1, a2, a3)
      SCAT1(yA, c0, 0); SCAT1(yA, c1, 16); SCAT1(yA, c2, 32); SCAT1(yA, c3, 48);
    }
    if constexpr (NIN == 2) {
      const bhalf8* xr = (const bhalf8*)x16B + ((size_t)src << 4);
      bhalf8 a0 = xr[cg], a1 = xr[4 + cg], a2 = xr[8 + cg], a3 = xr[12 + cg];
      MFMA_BODY1(a0, a1, a2, a3)
      SCAT1(yB, c0, 0); SCAT1(yB, c1, 16); SCAT1(yB, c2, 32); SCAT1(yB, c3, 48);
    }
#undef SCAT1
    sdC = sdN; ivC = ivN;
  }
}

// ===================== layer-1 edge GEMM, row STORES at dst-major slot q ===========
template <int NIN>
__global__ __launch_bounds__(256, 2) void k_edge1s(
    const int2* __restrict__ sdp, const float* __restrict__ ivq,
    const int* __restrict__ sm, int startOff, int histOff,
    const unsigned short* __restrict__ Wf,
    const unsigned short* __restrict__ x16A, const unsigned short* __restrict__ x16B,
    unsigned short* __restrict__ tA, unsigned short* __restrict__ tB) {
  const int r = blockIdx.x / CPB1;
  const int lane = threadIdx.x & 63;
  bhalf8 wb[16];
  {
    const bhalf8* wf = (const bhalf8*)Wf + ((size_t)r * 16) * 64 + lane;
#pragma unroll
    for (int s = 0; s < 16; ++s) wb[s] = wf[(size_t)s * 64];
  }
  const int wvid = (blockIdx.x - r * CPB1) * 4 + (threadIdx.x >> 6);
  const int stride = CPB1 * 4;
  const int s0 = sm[startOff + r];
  const int cnt = sm[histOff + r];
  const int ngroups = (cnt + 15) >> 4;
  if (wvid >= ngroups) return;
  const int cg = lane >> 4;
  const int col = lane & 15;
  const int row0 = cg << 2;

  int2 sdC; float ivC;
  LM(wvid, sdC, ivC);
  for (int G = wvid; G < ngroups; G += stride) {
    int2 sdN = sdC; float ivN = ivC;
    if (G + stride < ngroups) LM(G + stride, sdN, ivN);
    const int src = sdC.x & 0x7FFF;
    const int qv = sdC.y;
    const int lim = cnt - (G << 4);
    const int q0 = __shfl(qv, row0),     q1 = __shfl(qv, row0 + 1),
              q2 = __shfl(qv, row0 + 2), q3 = __shfl(qv, row0 + 3);
    const float i0 = __shfl(ivC, row0),     i1 = __shfl(ivC, row0 + 1),
                i2 = __shfl(ivC, row0 + 2), i3 = __shfl(ivC, row0 + 3);
#define STOR1(T, CCN, NOFF)                                                     \
    {                                                                           \
      float v0 = (CCN)[0] * i0, v1 = (CCN)[1] * i1,                             \
            v2 = (CCN)[2] * i2, v3 = (CCN)[3] * i3;                             \
      float p0 = __shfl_xor(v0, 1), p1 = __shfl_xor(v1, 1),                     \
            p2 = __shfl_xor(v2, 1), p3 = __shfl_xor(v3, 1);                     \
      if (!(lane & 1)) {                                                        \
        if (row0 + 0 < lim) *(unsigned*)(T + (size_t)q0 * H1 + (NOFF) + col) = (unsigned)f2bf(v0) | ((unsigned)f2bf(p0) << 16); \
        if (row0 + 1 < lim) *(unsigned*)(T + (size_t)q1 * H1 + (NOFF) + col) = (unsigned)f2bf(v1) | ((unsigned)f2bf(p1) << 16); \
        if (row0 + 2 < lim) *(unsigned*)(T + (size_t)q2 * H1 + (NOFF) + col) = (unsigned)f2bf(v2) | ((unsigned)f2bf(p2) << 16); \
        if (row0 + 3 < lim) *(unsigned*)(T + (size_t)q3 * H1 + (NOFF) + col) = (unsigned)f2bf(v3) | ((unsigned)f2bf(p3) << 16); \
      }                                                                         \
    }
    {
      const bhalf8* xr = (const bhalf8*)x16A + ((size_t)src << 4);
      bhalf8 a0 = xr[cg], a1 = xr[4 + cg], a2 = xr[8 + cg], a3 = xr[12 + cg];
      MFMA_BODY1(a0, a1, a2, a3)
      STOR1(tA, c0, 0); STOR1(tA, c1, 16); STOR1(tA, c2, 32); STOR1(tA, c3, 48);
    }
    if constexpr (NIN == 2) {
      const bhalf8* xr = (const bhalf8*)x16B + ((size_t)src << 4);
      bhalf8 a0 = xr[cg], a1 = xr[4 + cg], a2 = xr[8 + cg], a3 = xr[12 + cg];
      MFMA_BODY1(a0, a1, a2, a3)
      STOR1(tB, c0, 0); STOR1(tB, c1, 16); STOR1(tB, c2, 32); STOR1(tB, c3, 48);
    }
#undef STOR1
    sdC = sdN; ivC = ivN;
  }
}

// ===================== layer-1 segmented reduce (CONTIGUOUS t rows) ================
template <int NT>
__global__ __launch_bounds__(256) void k_reduce1(
    const int* __restrict__ startD,
    const unsigned short* __restrict__ t0, const unsigned short* __restrict__ t1,
    const unsigned short* __restrict__ r0, const unsigned short* __restrict__ r1,
    unsigned short* __restrict__ y0, unsigned short* __restrict__ y1) {
  int lane = threadIdx.x & 63;
  int d = (blockIdx.x * blockDim.x + threadIdx.x) >> 6;
  if (d >= NN) return;
  int e0 = startD[d], e1 = startD[d + 1];
  float a0 = 0.f, a1 = 0.f;
  for (int j = e0; j < e1; ++j) {
    a0 += bf2f(t0[(size_t)j * H1 + lane]);
    if constexpr (NT == 2) a1 += bf2f(t1[(size_t)j * H1 + lane]);
  }
  size_t o = (size_t)d * H1 + lane;
  y0[o] = f2bf(fmaxf(bf2f(r0[o]) + a0, 0.f));
  if constexpr (NT == 2) y1[o] = f2bf(fmaxf(bf2f(r1[o]) + a1, 0.f));
}

// ===================== layer-2 root term, 3 fused (bf16 out) =====================
__global__ __launch_bounds__(256) void k_root2x3(
    const unsigned short* __restrict__ x1o, const unsigned short* __restrict__ x1a,
    const unsigned short* __restrict__ x1aa,
    const float* __restrict__ rt, const float* __restrict__ b,
    unsigned short* __restrict__ y0, unsigned short* __restrict__ y1,
    unsigned short* __restrict__ y2) {
  int i = blockIdx.x * blockDim.x + threadIdx.x;
  if (i >= NN * H2) return;
  int o = i & (H2 - 1);
  int n = i >> 5;
  const uint2* p0 = (const uint2*)(x1o + (size_t)n * H1);
  const uint2* p1 = (const uint2*)(x1a + (size_t)n * H1);
  const uint2* p2 = (const uint2*)(x1aa + (size_t)n * H1);
  float s0 = b[o], s1 = s0, s2 = s0;
#pragma unroll
  for (int j = 0; j < 16; ++j) {
    uint2 u0 = p0[j], u1 = p1[j], u2 = p2[j];
#pragma unroll
    for (int t = 0; t < 4; ++t) {
      unsigned w0 = (t < 2) ? u0.x : u0.y;
      unsigned w1 = (t < 2) ? u1.x : u1.y;
      unsigned w2 = (t < 2) ? u2.x : u2.y;
      int sh = (t & 1) * 16;
      float wv = rt[(4 * j + t) * H2 + o];
      s0 = fmaf(bf2f((unsigned short)(w0 >> sh)), wv, s0);
      s1 = fmaf(bf2f((unsigned short)(w1 >> sh)), wv, s1);
      s2 = fmaf(bf2f((unsigned short)(w2 >> sh)), wv, s2);
    }
  }
  y0[i] = f2bf(s0); y1[i] = f2bf(s1); y2[i] = f2bf(s2);
}

// ===================== layer-2 edge GEMM, ATOMIC (fallback) =====================
template <int NIN>
__global__ __launch_bounds__(256, 2) void k_edge2m(
    const int2* __restrict__ sdp, const float* __restrict__ ivq,
    const int* __restrict__ sm, int startOff, int histOff,
    const unsigned short* __restrict__ Wf,
    const unsigned short* __restrict__ x16A, const unsigned short* __restrict__ x16B,
    unsigned short* __restrict__ yA, unsigned short* __restrict__ yB) {
  const int r = blockIdx.x / CPB2;
  const int lane = threadIdx.x & 63;
  bhalf8 wb[4];
  {
    const bhalf8* wf = (const bhalf8*)Wf + ((size_t)r * 4) * 64 + lane;
#pragma unroll
    for (int s = 0; s < 4; ++s) wb[s] = wf[(size_t)s * 64];
  }
  const int wvid = (blockIdx.x - r * CPB2) * 4 + (threadIdx.x >> 6);
  const int stride = CPB2 * 4;
  const int s0 = sm[startOff + r];
  const int cnt = sm[histOff + r];
  const int ngroups = (cnt + 15) >> 4;
  if (wvid >= ngroups) return;
  const int cg = lane >> 4;
  const int col = lane & 15;
  const int row0 = cg << 2;

  int2 sdC; float ivC;
  LM(wvid, sdC, ivC);
  for (int G = wvid; G < ngroups; G += stride) {
    int2 sdN = sdC; float ivN = ivC;
    if (G + stride < ngroups) LM(G + stride, sdN, ivN);
    const int src = sdC.x & 0x7FFF;
    const int dstv = (sdC.x >> 15) & 0x7FFF;
    const int d0 = __shfl(dstv, row0),     d1 = __shfl(dstv, row0 + 1),
              d2 = __shfl(dstv, row0 + 2), d3 = __shfl(dstv, row0 + 3);
    const float i0 = __shfl(ivC, row0),     i1 = __shfl(ivC, row0 + 1),
                i2 = __shfl(ivC, row0 + 2), i3 = __shfl(ivC, row0 + 3);
#define SCAT2(Y, CCN, NOFF)                                                     \
    {                                                                           \
      float v0 = (CCN)[0] * i0, v1 = (CCN)[1] * i1,                             \
            v2 = (CCN)[2] * i2, v3 = (CCN)[3] * i3;                             \
      float p0 = __shfl_xor(v0, 1), p1 = __shfl_xor(v1, 1),                     \
            p2 = __shfl_xor(v2, 1), p3 = __shfl_xor(v3, 1);                     \
      if (!(lane & 1)) {                                                        \
        atomPK(Y + (size_t)d0 * H2 + (NOFF) + col, (unsigned)f2bf(v0) | ((unsigned)f2bf(p0) << 16)); \
        atomPK(Y + (size_t)d1 * H2 + (NOFF) + col, (unsigned)f2bf(v1) | ((unsigned)f2bf(p1) << 16)); \
        atomPK(Y + (size_t)d2 * H2 + (NOFF) + col, (unsigned)f2bf(v2) | ((unsigned)f2bf(p2) << 16)); \
        atomPK(Y + (size_t)d3 * H2 + (NOFF) + col, (unsigned)f2bf(v3) | ((unsigned)f2bf(p3) << 16)); \
      }                                                                         \
    }
    {
      const bhalf8* xr = (const bhalf8*)x16A + ((size_t)src << 3);
      bhalf8 a0 = xr[cg], a1 = xr[4 + cg];
      f32x4 c0 = {0.f,0.f,0.f,0.f}, c1 = c0;
      c0 = MFMA16(a0, wb[0], c0); c1 = MFMA16(a0, wb[1], c1);
      c0 = MFMA16(a1, wb[2], c0); c1 = MFMA16(a1, wb[3], c1);
      SCAT2(yA, c0, 0); SCAT2(yA, c1, 16);
    }
    if constexpr (NIN == 2) {
      const bhalf8* xr = (const bhalf8*)x16B + ((size_t)src << 3);
      bhalf8 a0 = xr[cg], a1 = xr[4 + cg];
      f32x4 c0 = {0.f,0.f,0.f,0.f}, c1 = c0;
      c0 = MFMA16(a0, wb[0], c0); c1 = MFMA16(a0, wb[1], c1);
      c0 = MFMA16(a1, wb[2], c0); c1 = MFMA16(a1, wb[3], c1);
      SCAT2(yB, c0, 0); SCAT2(yB, c1, 16);
    }
#undef SCAT2
    sdC = sdN; ivC = ivN;
  }
}

// ===================== layer-2 edge GEMM, STORES at slot q =====================
template <int NIN>
__global__ __launch_bounds__(256, 2) void k_edge2s(
    const int2* __restrict__ sdp, const float* __restrict__ ivq,
    const int* __restrict__ sm, int startOff, int histOff,
    const unsigned short* __restrict__ Wf,
    const unsigned short* __restrict__ x16A, const unsigned short* __restrict__ x16B,
    unsigned short* __restrict__ tA, unsigned short* __restrict__ tB) {
  const int r = blockIdx.x / CPB2;
  const int lane = threadIdx.x & 63;
  bhalf8 wb[4];
  {
    const bhalf8* wf = (const bhalf8*)Wf + ((size_t)r * 4) * 64 + lane;
#pragma unroll
    for (int s = 0; s < 4; ++s) wb[s] = wf[(size_t)s * 64];
  }
  const int wvid = (blockIdx.x - r * CPB2) * 4 + (threadIdx.x >> 6);
  const int stride = CPB2 * 4;
  const int s0 = sm[startOff + r];
  const int cnt = sm[histOff + r];
  const int ngroups = (cnt + 15) >> 4;
  if (wvid >= ngroups) return;
  const int cg = lane >> 4;
  const int col = lane & 15;
  const int row0 = cg << 2;

  int2 sdC; float ivC;
  LM(wvid, sdC, ivC);
  for (int G = wvid; G < ngroups; G += stride) {
    int2 sdN = sdC; float ivN = ivC;
    if (G + stride < ngroups) LM(G + stride, sdN, ivN);
    const int src = sdC.x & 0x7FFF;
    const int qv = sdC.y;
    const int lim = cnt - (G << 4);
    const int q0 = __shfl(qv, row0),     q1 = __shfl(qv, row0 + 1),
              q2 = __shfl(qv, row0 + 2), q3 = __shfl(qv, row0 + 3);
    const float i0 = __shfl(ivC, row0),     i1 = __shfl(ivC, row0 + 1),
                i2 = __shfl(ivC, row0 + 2), i3 = __shfl(ivC, row0 + 3);
#define STOR2(T, CCN, NOFF)                                                     \
    {                                                                           \
      float v0 = (CCN)[0] * i0, v1 = (CCN)[1] * i1,                             \
            v2 = (CCN)[2] * i2, v3 = (CCN)[3] * i3;                             \
      float p0 = __shfl_xor(v0, 1), p1 = __shfl_xor(v1, 1),                     \
            p2 = __shfl_xor(v2, 1), p3 = __shfl_xor(v3, 1);                     \
      if (!(lane & 1)) {                                                        \
        if (row0 + 0 < lim) *(unsigned*)(T + (size_t)q0 * H2 + (NOFF) + col) = (unsigned)f2bf(v0) | ((unsigned)f2bf(p0) << 16); \
        if (row0 + 1 < lim) *(unsigned*)(T + (size_t)q1 * H2 + (NOFF) + col) = (unsigned)f2bf(v1) | ((unsigned)f2bf(p1) << 16); \
        if (row0 + 2 < lim) *(unsigned*)(T + (size_t)q2 * H2 + (NOFF) + col) = (unsigned)f2bf(v2) | ((unsigned)f2bf(p2) << 16); \
        if (row0 + 3 < lim) *(unsigned*)(T + (size_t)q3 * H2 + (NOFF) + col) = (unsigned)f2bf(v3) | ((unsigned)f2bf(p3) << 16); \
      }                                                                         \
    }
    {
      const bhalf8* xr = (const bhalf8*)x16A + ((size_t)src << 3);
      bhalf8 a0 = xr[cg], a1 = xr[4 + cg];
      f32x4 c0 = {0.f,0.f,0.f,0.f}, c1 = c0;
      c0 = MFMA16(a0, wb[0], c0); c1 = MFMA16(a0, wb[1], c1);
      c0 = MFMA16(a1, wb[2], c0); c1 = MFMA16(a1, wb[3], c1);
      STOR2(tA, c0, 0); STOR2(tA, c1, 16);
    }
    if constexpr (NIN == 2) {
      const bhalf8* xr = (const bhalf8*)x16B + ((size_t)src << 3);
      bhalf8 a0 = xr[cg], a1 = xr[4 + cg];
      f32x4 c0 = {0.f,0.f,0.f,0.f}, c1 = c0;
      c0 = MFMA16(a0, wb[0], c0); c1 = MFMA16(a0, wb[1], c1);
      c0 = MFMA16(a1, wb[2], c0); c1 = MFMA16(a1, wb[3], c1);
      STOR2(tB, c0, 0); STOR2(tB, c1, 16);
    }
#undef STOR2
    sdC = sdN; ivC = ivN;
  }
}

// ===================== layer-2 segmented reduce (contiguous) =====================
template <int NT>
__global__ __launch_bounds__(256) void k_reduce2(
    const int* __restrict__ startD,
    const unsigned short* __restrict__ t0, const unsigned short* __restrict__ t1,
    const unsigned short* __restrict__ r0, const unsigned short* __restrict__ r1,
    unsigned short* __restrict__ y0, unsigned short* __restrict__ y1,
    float* __restrict__ f32out) {
  int gt = blockIdx.x * blockDim.x + threadIdx.x;
  int d = gt >> 5;
  int colc = gt & 31;
  if (d >= NN) return;
  int e0 = startD[d], e1 = startD[d + 1];
  float a0 = 0.f, a1 = 0.f;
  for (int j = e0; j < e1; ++j) {
    a0 += bf2f(t0[(size_t)j * H2 + colc]);
    if constexpr (NT == 2) a1 += bf2f(t1[(size_t)j * H2 + colc]);
  }
  size_t o = (size_t)d * H2 + colc;
  float v0 = bf2f(r0[o]) + a0;
  y0[o] = f2bf(v0);
  if (f32out) f32out[o] = v0;
  if constexpr (NT == 2) y1[o] = f2bf(bf2f(r1[o]) + a1);
}

// ===================== x2_o bf16 -> fp32 into d_out (atomic tier) ==================
__global__ __launch_bounds__(256) void k_fin(const uint4* __restrict__ xb,
                                             float4* __restrict__ out, int n8) {
  int i = blockIdx.x * blockDim.x + threadIdx.x;
  if (i >= n8) return;
  uint4 u = xb[i];
  float4 a, b;
  a.x = bf2f((unsigned short)u.x); a.y = bf2f((unsigned short)(u.x >> 16));
  a.z = bf2f((unsigned short)u.y); a.w = bf2f((unsigned short)(u.y >> 16));
  b.x = bf2f((unsigned short)u.z); b.y = bf2f((unsigned short)(u.z >> 16));
  b.z = bf2f((unsigned short)u.w); b.w = bf2f((unsigned short)(u.w >> 16));
  out[2 * i] = a; out[2 * i + 1] = b;
}

// ===================== column sum -> hacc[32] =====================
__global__ __launch_bounds__(256) void k_colsum(const float* __restrict__ x2o,
                                                float* __restrict__ hacc) {
  int tid = threadIdx.x;
  int col = tid & 31;
  int rgrp = blockIdx.x * (blockDim.x >> 5) + (tid >> 5);
  int nth = gridDim.x * (blockDim.x >> 5);
  float s = 0.f;
  for (int n = rgrp; n < NN; n += nth) s += x2o[(size_t)n * H2 + col];
  unsafeAtomicAdd(&hacc[col], s);
}

// ===================== h_os = sigmoid(mean); v = disc_w @ h_os =====================
__global__ __launch_bounds__(64) void k_disc(const float* __restrict__ hacc,
                                             const float* __restrict__ dw,
                                             float* __restrict__ vout) {
  __shared__ float hos[H2];
  int t = threadIdx.x;
  if (t < H2) hos[t] = 1.0f / (1.0f + expf(-hacc[t] / (float)NN));
  __syncthreads();
  if (t < H2) {
    float s = 0.f;
#pragma unroll
    for (int k = 0; k < H2; ++k) s = fmaf(dw[t * H2 + k], hos[k], s);
    vout[t] = s;
  }
}

// ===================== ret_os / ret_os_a =====================
__global__ __launch_bounds__(256) void k_ret(
    const unsigned short* __restrict__ x2o, const unsigned short* __restrict__ x2oa,
    const unsigned short* __restrict__ x2oaa,
    const float* __restrict__ v, const float* __restrict__ db,
    float* __restrict__ ros, float* __restrict__ rosa) {
  int n = blockIdx.x * blockDim.x + threadIdx.x;
  if (n >= NN) return;
  const uint2* a2 = (const uint2*)(x2o + (size_t)n * H2);
  const uint2* b2 = (const uint2*)(x2oa + (size_t)n * H2);
  const uint2* c2 = (const uint2*)(x2oaa + (size_t)n * H2);
  const float4* v4 = (const float4*)v;
  float r0 = 0.f, r1 = 0.f, r2 = 0.f;
#pragma unroll
  for (int j = 0; j < 8; ++j) {
    uint2 ua = a2[j], ub = b2[j], uc = c2[j];
    float4 vv = v4[j];
    r0 += bf2f((unsigned short)ua.x) * vv.x + bf2f((unsigned short)(ua.x >> 16)) * vv.y
        + bf2f((unsigned short)ua.y) * vv.z + bf2f((unsigned short)(ua.y >> 16)) * vv.w;
    r1 += bf2f((unsigned short)ub.x) * vv.x + bf2f((unsigned short)(ub.x >> 16)) * vv.y
        + bf2f((unsigned short)ub.y) * vv.z + bf2f((unsigned short)(ub.y >> 16)) * vv.w;
    r2 += bf2f((unsigned short)uc.x) * vv.x + bf2f((unsigned short)(uc.x >> 16)) * vv.y
        + bf2f((unsigned short)uc.y) * vv.z + bf2f((unsigned short)(uc.y >> 16)) * vv.w;
  }
  float bb = db[0];
  ros[n * 2] = r0 + bb;  ros[n * 2 + 1] = r1 + bb;
  rosa[n * 2] = r0 + bb; rosa[n * 2 + 1] = r2 + bb;
}

// ===================== classifier =====================
__global__ __launch_bounds__(128) void k_cls(
    const int* __restrict__ idx, const unsigned short* __restrict__ x1o,
    const float* __restrict__ x2o,
    const float* __restrict__ attt, const float* __restrict__ cw, const float* __restrict__ cb,
    float* __restrict__ lg) {
  int b = blockIdx.x;
  int r = threadIdx.x;
  if (r >= RR) return;
  int i1 = idx[b], i2 = idx[BQ + b];
  float a0 = attt[0], a1 = attt[1];
  float acc = cb[r];
  const uint2* q1 = (const uint2*)(x1o + (size_t)i1 * H1);
  const float4* q2 = (const float4*)(x2o + (size_t)i1 * H2);
  const uint2* q3 = (const uint2*)(x1o + (size_t)i2 * H1);
  const float4* q4 = (const float4*)(x2o + (size_t)i2 * H2);
#pragma unroll
  for (int j = 0; j < 16; ++j) {
    uint2 u = q1[j];
    float v0 = bf2f((unsigned short)u.x), v1 = bf2f((unsigned short)(u.x >> 16));
    float v2 = bf2f((unsigned short)u.y), v3 = bf2f((unsigned short)(u.y >> 16));
    acc = fmaf(a0 * v0, cw[(4 * j) * RR + r], acc);
    acc = fmaf(a0 * v1, cw[(4 * j + 1) * RR + r], acc);
    acc = fmaf(a0 * v2, cw[(4 * j + 2) * RR + r], acc);
    acc = fmaf(a0 * v3, cw[(4 * j + 3) * RR + r], acc);
  }
#pragma unroll
  for (int j = 0; j < H2 / 4; ++j) {
    float v[4]; *(float4*)v = q2[j];
#pragma unroll
    for (int t = 0; t < 4; ++t) acc = fmaf(a1 * v[t], cw[(H1 + 4 * j + t) * RR + r], acc);
  }
#pragma unroll
  for (int j = 0; j < 16; ++j) {
    uint2 u = q3[j];
    float v0 = bf2f((unsigned short)u.x), v1 = bf2f((unsigned short)(u.x >> 16));
    float v2 = bf2f((unsigned short)u.y), v3 = bf2f((unsigned short)(u.y >> 16));
    acc = fmaf(a0 * v0, cw[(96 + 4 * j) * RR + r], acc);
    acc = fmaf(a0 * v1, cw[(96 + 4 * j + 1) * RR + r], acc);
    acc = fmaf(a0 * v2, cw[(96 + 4 * j + 2) * RR + r], acc);
    acc = fmaf(a0 * v3, cw[(96 + 4 * j + 3) * RR + r], acc);
  }
#pragma unroll
  for (int j = 0; j < H2 / 4; ++j) {
    float v[4]; *(float4*)v = q4[j];
#pragma unroll
    for (int t = 0; t < 4; ++t) acc = fmaf(a1 * v[t], cw[(96 + H1 + 4 * j + t) * RR + r], acc);
  }
  lg[(size_t)b * RR + r] = acc;
}

// ===================== launch =====================
extern "C" void kernel_launch(void* const* d_in, const int* in_sizes, int n_in,
                              void* d_out, int out_size, void* d_ws, size_t ws_size,
                              hipStream_t stream) {
  const float* x_o  = (const float*)d_in[0];
  const float* x_a  = (const float*)d_in[1];
  const int*   ei   = (const int*)d_in[2];
  const int*   etA  = (const int*)d_in[3];
  const int*   etB  = (const int*)d_in[4];
  const int*   idx  = (const int*)d_in[5];
  const float* W1   = (const float*)d_in[6];
  const float* rt1  = (const float*)d_in[7];
  const float* b1   = (const float*)d_in[8];
  const float* W2   = (const float*)d_in[9];
  const float* rt2  = (const float*)d_in[10];
  const float* b2   = (const float*)d_in[11];
  const float* attt = (const float*)d_in[12];
  const float* dw   = (const float*)d_in[13];
  const float* db   = (const float*)d_in[14];
  const float* cw   = (const float*)d_in[15];
  const float* cb   = (const float*)d_in[16];

  int* wsI    = (int*)d_ws;
  int* sm     = wsI;                            // 1024 (memset'd)
  int* cntD   = sm + 1024;                      // NDPAD (memset'd)
  int* startD = cntD + NDPAD;                   // NDPAD
  int* cur    = startD + NDPAD;                 // NDPAD
  unsigned short* relQ = (unsigned short*)(cur + NDPAD);    // NE ushort
  int2*  sdA  = (int2*)((int*)(relQ + NE) + (NE & 1));      // NE int2 (align)
  int2*  sdB  = sdA + NE;                       // NE int2
  float* ivqA = (float*)(sdB + NE);             // NE
  float* ivqB = ivqA + NE;                      // NE
  // bf16 region
  unsigned short* x1o16   = (unsigned short*)(ivqB + NE);  // NN*H1 x3
  unsigned short* x1a16   = x1o16 + (size_t)NN * H1;
  unsigned short* x1aa16  = x1a16 + (size_t)NN * H1;
  unsigned short* x2ob    = x1aa16 + (size_t)NN * H1;      // NN*H2 x3
  unsigned short* x2oab   = x2ob + (size_t)NN * H2;
  unsigned short* x2oaab  = x2oab + (size_t)NN * H2;
  unsigned short* xo16    = x2oaab + (size_t)NN * H2;      // NN*FF x2
  unsigned short* xa16    = xo16 + (size_t)NN * FF;
  unsigned short* W1f     = xa16 + (size_t)NN * FF;        // RR*16*64*8
  unsigned short* W2f     = W1f + (size_t)RR * 16 * 64 * 8;
  unsigned short* rootO16 = W2f + (size_t)RR * 4 * 64 * 8; // NN*H1 x2
  unsigned short* rootA16 = rootO16 + (size_t)NN * H1;
  unsigned short* r2o16   = rootA16 + (size_t)NN * H1;     // NN*H2 x3
  unsigned short* r2a16   = r2o16 + (size_t)NN * H2;
  unsigned short* r2aa16  = r2a16 + (size_t)NN * H2;
  unsigned short* t0      = r2aa16 + (size_t)NN * H2;      // t region start
  unsigned short* t1      = t0 + (size_t)NE * H1;
  unsigned short* tc1     = t0 + (size_t)NE * H2;

  const size_t ofsT = (size_t)((char*)t0 - (char*)d_ws);
  const size_t needFull = ofsT + (size_t)2 * NE * H1 * 2 + 256;
  const size_t needMid  = ofsT + (size_t)2 * NE * H2 * 2 + 256;
  const bool fullT = ws_size >= needFull;
  const bool midT  = fullT || ws_size >= needMid;

  float* smF  = (float*)sm;
  float* hacc = smF + SM_HACC;
  float* vbuf = smF + SM_V;

  float* outF   = (float*)d_out;
  float* o_log  = outF;
  float* o_ros  = outF + (size_t)BQ * RR;
  float* o_rosa = o_ros + (size_t)NN * 2;
  float* o_x2o  = o_rosa + (size_t)NN * 2;

  hipMemsetAsync(wsI, 0, (1024 + NDPAD) * sizeof(int), stream);

  // prep
  k_cvt2<<<(2 * NN * FF / 8 + 255) / 256, 256, 0, stream>>>(
      (const float4*)x_o, (const float4*)x_a, (uint4*)xo16, (uint4*)xa16, NN * FF / 8);
  k_wprep1<<<RR, 256, 0, stream>>>(W1, W1f);
  k_wprep2<<<RR, 256, 0, stream>>>(W2, W2f);

  k_hist<<<(NE + 255) / 256, 256, 0, stream>>>(ei, etA, etB, sm, cntD);
  k_prefix<<<1, 128, 0, stream>>>(sm);
  k_prefixD<<<1, 256, 0, stream>>>(cntD, startD, cur);
  k_scatterF<<<(NE + 255) / 256, 256, 0, stream>>>(ei, etA, etB, sm, cur,
                                                   sdA, sdB, relQ);
  k_invD2<<<(NN * 64 + 255) / 256, 256, 0, stream>>>(startD, relQ, ivqA, ivqB);

  // ---- layer 1 ----
  if (fullT) {
    k_root1<<<(NN * H1) / 256, 256, 0, stream>>>(x_o, x_a, rt1, b1,
                                                 rootO16, rootO16, rootA16);
    k_edge1s<2><<<RR * CPB1, 256, 0, stream>>>(sdA, ivqA, sm, SM_START_A, SM_HIST_A,
                                               W1f, xo16, xa16, t0, t1);
    k_reduce1<2><<<(NN * 64) / 256, 256, 0, stream>>>(startD, t0, t1,
                                                      rootO16, rootA16, x1o16, x1a16);
    k_edge1s<1><<<RR * CPB1, 256, 0, stream>>>(sdB, ivqB, sm, SM_START_B, SM_HIST_B,
                                               W1f, xo16, nullptr, t0, nullptr);
    k_reduce1<1><<<(NN * 64) / 256, 256, 0, stream>>>(startD, t0, nullptr,
                                                      rootO16, nullptr, x1aa16, nullptr);
  } else {
    k_root1<<<(NN * H1) / 256, 256, 0, stream>>>(x_o, x_a, rt1, b1,
                                                 x1o16, x1aa16, x1a16);
    k_edge1m<2><<<RR * CPB1, 256, 0, stream>>>(sdA, ivqA, sm, SM_START_A, SM_HIST_A,
                                               W1f, xo16, xa16, x1o16, x1a16);
    k_edge1m<1><<<RR * CPB1, 256, 0, stream>>>(sdB, ivqB, sm, SM_START_B, SM_HIST_B,
                                               W1f, xo16, nullptr, x1aa16, nullptr);
    k_relu16<<<(3 * NN * H1 / 8 + 255) / 256, 256, 0, stream>>>((uint4*)x1o16,
                                                                3 * NN * H1 / 8);
  }

  // ---- layer 2 ----
  if (midT) {
    k_root2x3<<<(NN * H2 + 255) / 256, 256, 0, stream>>>(x1o16, x1a16, x1aa16, rt2, b2,
                                                         r2o16, r2a16, r2aa16);
    k_edge2s<2><<<RR * CPB2, 256, 0, stream>>>(sdA, ivqA, sm, SM_START_A, SM_HIST_A,
                                               W2f, x1o16, x1a16, t0, tc1);
    k_reduce2<2><<<(NN * 32) / 256, 256, 0, stream>>>(startD, t0, tc1,
                                                      r2o16, r2a16, x2ob, x2oab, o_x2o);
    k_edge2s<1><<<RR * CPB2, 256, 0, stream>>>(sdB, ivqB, sm, SM_START_B, SM_HIST_B,
                                               W2f, x1aa16, nullptr, t0, nullptr);
    k_reduce2<1><<<(NN * 32) / 256, 256, 0, stream>>>(startD, t0, nullptr,
                                                      r2aa16, nullptr, x2oaab, nullptr,
                                                      nullptr);
  } else {
    k_root2x3<<<(NN * H2 + 255) / 256, 256, 0, stream>>>(x1o16, x1a16, x1aa16, rt2, b2,
                                                         x2ob, x2oab, x2oaab);
    k_edge2m<2><<<RR * CPB2, 256, 0, stream>>>(sdA, ivqA, sm, SM_START_A, SM_HIST_A,
                                               W2f, x1o16, x1a16, x2ob, x2oab);
    k_edge2m<1><<<RR * CPB2, 256, 0, stream>>>(sdB, ivqB, sm, SM_START_B, SM_HIST_B,
                                               W2f, x1aa16, nullptr, x2oaab, nullptr);
    k_fin<<<(NN * H2 / 8 + 255) / 256, 256, 0, stream>>>((const uint4*)x2ob,
                                                         (float4*)o_x2o, NN * H2 / 8);
  }

  k_colsum<<<128, 256, 0, stream>>>(o_x2o, hacc);
  k_disc<<<1, 64, 0, stream>>>(hacc, dw, vbuf);
  k_ret<<<(NN + 255) / 256, 256, 0, stream>>>(x2ob, x2oab, x2oaab, vbuf, db, o_ros, o_rosa);
  k_cls<<<BQ, 128, 0, stream>>>(idx, x1o16, o_x2o, attt, cw, cb, o_log);
}